// Round 12
// baseline (428.988 us; speedup 1.0000x reference)
//
#include <hip/hip_runtime.h>
#include <hip/hip_bf16.h>
#include <math.h>

#define NB 4096
#define DC 256
#define PC 512

typedef unsigned short ushort_t;
typedef __attribute__((ext_vector_type(4))) unsigned short us4;
typedef __attribute__((ext_vector_type(8))) unsigned short us8;
typedef __attribute__((ext_vector_type(8))) short s8v;       // bf16x8 for MFMA
typedef __attribute__((ext_vector_type(4))) float f32x4;

__device__ __forceinline__ float bf16_to_f(ushort_t u) {
    union { unsigned int i; float f; } c;
    c.i = ((unsigned int)u) << 16;
    return c.f;
}
__device__ __forceinline__ ushort_t f2bf(float f) {          // RNE
    union { float f; unsigned int u; } c; c.f = f;
    unsigned int r = c.u + 0x7fffu + ((c.u >> 16) & 1u);
    return (ushort_t)(r >> 16);
}

// ---------------- K_pre: all small packing kernels merged (blockIdx-range dispatch) -------
// blocks: [0,512) prep | [512,1024) pack | [1024,1184) w3p | [1184,1190) w2p
//         [1190,1334) wd1p | [1334,7734) wupf
__global__ __launch_bounds__(256) void k_pre(
    const float* __restrict__ proto, float* __restrict__ p2,
    ushort_t* __restrict__ pfragHi, ushort_t* __restrict__ pfragLo,
    const float* __restrict__ w3, ushort_t* __restrict__ w3fH, ushort_t* __restrict__ w3fL,
    const float* __restrict__ w2, ushort_t* __restrict__ w2fH, ushort_t* __restrict__ w2fL,
    const float* __restrict__ wd1, ushort_t* __restrict__ wd1frag,
    const float* __restrict__ wup, ushort_t* __restrict__ wupfH, ushort_t* __restrict__ wupfL)
{
    int b = blockIdx.x, tid = threadIdx.x;
    __shared__ float red[256];
    if (b < 512) {
        int p = b, d = tid;
        float v = proto[p * DC + d];
        red[d] = v * v;
        __syncthreads();
        for (int s = 128; s > 0; s >>= 1) {
            if (d < s) red[d] += red[d + s];
            __syncthreads();
        }
        if (d == 0) p2[p] = red[0];
    } else if (b < 1024) {
        int idx = (b - 512) * 256 + tid;
        int j = idx & 7, l = (idx >> 3) & 63;
        int k0 = (idx >> 9) & 7, nt = idx >> 12;
        int n = nt * 16 + (l & 15);
        int k = k0 * 32 + (l >> 4) * 8 + j;
        float v = proto[n * DC + k];
        ushort_t hi = f2bf(v);
        pfragHi[idx] = hi;
        pfragLo[idx] = f2bf(v - bf16_to_f(hi));
    } else if (b < 1184) {
        int idx = (b - 1024) * 256 + tid;
        int j = idx & 7, l = (idx >> 3) & 63;
        int q = idx >> 9;
        int k0 = q % 5, nt = q / 5;
        int d = nt * 16 + (l & 15);
        int k = k0 * 32 + (l >> 4) * 8 + j;
        float v = (k < 144) ? w3[d * 144 + k] : 0.f;
        ushort_t hi = f2bf(v);
        w3fH[idx] = hi;
        w3fL[idx] = f2bf(v - bf16_to_f(hi));
    } else if (b < 1190) {
        int idx = (b - 1184) * 256 + tid;
        int j = idx & 7, l = (idx >> 3) & 63;
        int k0 = idx >> 9;
        int ch = l & 15;
        int k = k0 * 32 + (l >> 4) * 8 + j;
        float v = (k < 72) ? w2[ch * 72 + k] : 0.f;
        ushort_t hi = f2bf(v);
        w2fH[idx] = hi;
        w2fL[idx] = f2bf(v - bf16_to_f(hi));
    } else if (b < 1334) {
        int idx = (b - 1190) * 256 + tid;
        int j = idx & 7, l = (idx >> 3) & 63;
        int k0 = (idx >> 9) & 7, nt = idx >> 12;
        int n = nt * 16 + (l & 15);
        int k = k0 * 32 + (l >> 4) * 8 + j;
        wd1frag[idx] = f2bf(wd1[k * 144 + n]);
    } else {
        int idx = (b - 1334) * 256 + tid;
        int j = idx & 7, l = (idx >> 3) & 63;
        int k0 = (idx >> 9) & 7, nt = idx >> 12;
        int np = nt * 16 + (l & 15);
        int d = k0 * 32 + (l >> 4) * 8 + j;
        int pos = np >> 8, ch = np & 255;
        float v = wup[d * 6400 + ch * 25 + pos];
        ushort_t hi = f2bf(v);
        wupfH[idx] = hi;
        wupfL[idx] = f2bf(v - bf16_to_f(hi));
    }
}

// ---------------- K0f: PW = proto x wupT via MFMA (hi/lo), -> PWfrag [400][16][64][8] -----
__global__ __launch_bounds__(256) void k_pw2(
    const ushort_t* __restrict__ pfragHi, const ushort_t* __restrict__ pfragLo,
    const ushort_t* __restrict__ wupfH, const ushort_t* __restrict__ wupfL,
    ushort_t* __restrict__ PWfrag)
{
    int t = threadIdx.x;
    int w = t >> 6, l = t & 63, lr = l & 15, lg = l >> 4;
    int my = blockIdx.y;
    int ntb = blockIdx.x * 16 + w * 4;
    const s8v* AH = (const s8v*)pfragHi;
    const s8v* AL = (const s8v*)pfragLo;
    const s8v* BH = (const s8v*)wupfH;
    const s8v* BL = (const s8v*)wupfL;
    f32x4 acc[4];
#pragma unroll
    for (int q = 0; q < 4; q++) acc[q] = (f32x4){0.f, 0.f, 0.f, 0.f};
#pragma unroll
    for (int k0 = 0; k0 < 8; k0++) {
        s8v ah = AH[(my * 8 + k0) * 64 + l];
        s8v al = AL[(my * 8 + k0) * 64 + l];
#pragma unroll
        for (int q = 0; q < 4; q++) {
            s8v bh = BH[(size_t)((ntb + q) * 8 + k0) * 64 + l];
            s8v bl = BL[(size_t)((ntb + q) * 8 + k0) * 64 + l];
            acc[q] = __builtin_amdgcn_mfma_f32_16x16x32_bf16(ah, bh, acc[q], 0, 0, 0);
            acc[q] = __builtin_amdgcn_mfma_f32_16x16x32_bf16(al, bh, acc[q], 0, 0, 0);
            acc[q] = __builtin_amdgcn_mfma_f32_16x16x32_bf16(ah, bl, acc[q], 0, 0, 0);
        }
    }
#pragma unroll
    for (int q = 0; q < 4; q++) {
        int nt = ntb + q;
#pragma unroll
        for (int r = 0; r < 4; r++) {
            int p = my * 16 + lg * 4 + r;
            int k0p = p >> 5;
            int ll = ((p >> 3) & 3) * 16 + lr;
            int jj = p & 7;
            PWfrag[(((size_t)(nt * 16 + k0p) * 64) + ll) * 8 + jj] = f2bf(acc[q][r]);
        }
    }
}

// ---------------- E1: conv1(+scatter im2col2) + conv2 MFMA (+scatter im2col3) + conv3 -----
__global__ __launch_bounds__(512) void k_enc1(
    const float* __restrict__ x,
    const float* __restrict__ w1, const float* __restrict__ b1,
    const ushort_t* __restrict__ w2fH, const ushort_t* __restrict__ w2fL,
    const float* __restrict__ b2,
    const float* __restrict__ g2, const float* __restrict__ bt2,
    const ushort_t* __restrict__ w3fH, const ushort_t* __restrict__ w3fL,
    const float* __restrict__ b3,
    unsigned int* __restrict__ h3gP,   // [4096][25][256] u32 (hi | lo<<16)
    float* __restrict__ x2g)           // [4096][32]
{
    int b = blockIdx.x;
    int t = threadIdx.x;
    int w = t >> 6, l = t & 63, lr = l & 15, lg = l >> 4;

    __shared__ __align__(16) unsigned char buf[39168];
    __shared__ float x2s[32];
    float* xb = (float*)buf;
    ushort_t* im2Hi = (ushort_t*)(buf + 9408);
    ushort_t* im2Lo = (ushort_t*)(buf + 22720);
    float* h2 = (float*)(buf + 36032);
    ushort_t* imHi = (ushort_t*)buf;
    ushort_t* imLo = (ushort_t*)(buf + 9248);

    const float bnr = rsqrtf(1.0f + 1e-5f);

    const float* xg = x + (size_t)b * 784;
    for (int i = t; i < 784; i += 512) xb[i] = xg[i];
    for (int i = t; i < 1664; i += 512)
        ((float4*)(buf + 9408))[i] = (float4){0.f, 0.f, 0.f, 0.f};
    if (t < 32) x2s[t] = (t < 25) ? 0.f : 1e30f;
    __syncthreads();

    // phase 1: conv1 + scatter into im2col2
    for (int o = t; o < 1568; o += 512) {
        int c = o / 196, r = o % 196, y = r / 14, xc = r % 14;
        float acc = b1[c];
        for (int sy = 0; sy < 3; sy++) {
            int iy = 2 * y - 1 + sy;
            if ((unsigned)iy >= 28u) continue;
            for (int sx = 0; sx < 3; sx++) {
                int ix = 2 * xc - 1 + sx;
                if ((unsigned)ix >= 28u) continue;
                acc += w1[c * 9 + sy * 3 + sx] * xb[iy * 28 + ix];
            }
        }
        float v = fmaxf(acc, 0.f);
        ushort_t hi = f2bf(v), lo = f2bf(v - bf16_to_f(hi));
        int kb = c * 9;
        int yA, syA, xA, sxA, yB = 0, xB = 0;
        bool hasYB, hasXB;
        if (y & 1) { yA = y >> 1; syA = 2; yB = yA + 1; hasYB = (yB < 7); }
        else       { yA = y >> 1; syA = 1; hasYB = false; }
        if (xc & 1) { xA = xc >> 1; sxA = 2; xB = xA + 1; hasXB = (xB < 7); }
        else        { xA = xc >> 1; sxA = 1; hasXB = false; }
        int i0 = (yA * 7 + xA) * 104 + kb + syA * 3 + sxA;
        im2Hi[i0] = hi; im2Lo[i0] = lo;
        if (hasXB) {
            int i1 = (yA * 7 + xB) * 104 + kb + syA * 3;
            im2Hi[i1] = hi; im2Lo[i1] = lo;
        }
        if (hasYB) {
            int i2 = (yB * 7 + xA) * 104 + kb + sxA;
            im2Hi[i2] = hi; im2Lo[i2] = lo;
            if (hasXB) {
                int i3 = (yB * 7 + xB) * 104 + kb;
                im2Hi[i3] = hi; im2Lo[i3] = lo;
            }
        }
    }
    __syncthreads();

    // phase 2: conv2 as MFMA (waves 0-3)
    if (w < 4) {
        f32x4 cc = {0, 0, 0, 0};
        const s8v* WH = (const s8v*)w2fH;
        const s8v* WL = (const s8v*)w2fL;
#pragma unroll
        for (int k0 = 0; k0 < 3; k0++) {
            s8v a0 = *(const s8v*)&im2Hi[(w * 16 + lr) * 104 + k0 * 32 + lg * 8];
            s8v a1 = *(const s8v*)&im2Lo[(w * 16 + lr) * 104 + k0 * 32 + lg * 8];
            s8v bh = WH[k0 * 64 + l];
            s8v bl = WL[k0 * 64 + l];
            cc = __builtin_amdgcn_mfma_f32_16x16x32_bf16(a0, bh, cc, 0, 0, 0);
            cc = __builtin_amdgcn_mfma_f32_16x16x32_bf16(a1, bh, cc, 0, 0, 0);
            cc = __builtin_amdgcn_mfma_f32_16x16x32_bf16(a0, bl, cc, 0, 0, 0);
        }
        int ch = lr;
        float s = g2[ch] * bnr, bb = b2[ch], bt = bt2[ch];
#pragma unroll
        for (int r = 0; r < 4; r++) {
            int pos = w * 16 + lg * 4 + r;
            if (pos < 49)
                h2[ch * 49 + pos] = fmaxf((cc[r] + bb) * s + bt, 0.f);
        }
    }
    __syncthreads();

    // phase 3: scatter h2 -> im2col3
    if (t < 16) { imHi[3600 + t] = 0; imLo[3600 + t] = 0; }
    for (int o = t; o < 784; o += 512) {
        float v = h2[o];
        int ci = o / 49, rr = o % 49, iy = rr / 7, ixp = rr % 7;
        ushort_t hi = f2bf(v), lo = f2bf(v - bf16_to_f(hi));
        int kb = ci * 9;
#pragma unroll
        for (int sy = 0; sy < 3; sy++) {
            int py = iy - sy;
            if ((unsigned)py < 5u) {
#pragma unroll
                for (int sx = 0; sx < 3; sx++) {
                    int px = ixp - sx;
                    if ((unsigned)px < 5u) {
                        int idx = (py * 5 + px) * 144 + kb + sy * 3 + sx;
                        imHi[idx] = hi; imLo[idx] = lo;
                    }
                }
            }
        }
    }
    __syncthreads();

    // phase 4: conv3 as MFMA, bias+relu; packed u32 store + x2
    {
        int nt0 = 2 * w;
        f32x4 c00 = {0,0,0,0}, c01 = {0,0,0,0}, c10 = {0,0,0,0}, c11 = {0,0,0,0};
        const s8v* WH = (const s8v*)w3fH;
        const s8v* WL = (const s8v*)w3fL;
#pragma unroll
        for (int k0 = 0; k0 < 5; k0++) {
            s8v ah0 = *(const s8v*)&imHi[lr * 144 + k0 * 32 + lg * 8];
            s8v ah1 = *(const s8v*)&imHi[(16 + lr) * 144 + k0 * 32 + lg * 8];
            s8v al0 = *(const s8v*)&imLo[lr * 144 + k0 * 32 + lg * 8];
            s8v al1 = *(const s8v*)&imLo[(16 + lr) * 144 + k0 * 32 + lg * 8];
            s8v bh0 = WH[(nt0 * 5 + k0) * 64 + l];
            s8v bl0 = WL[(nt0 * 5 + k0) * 64 + l];
            s8v bh1 = WH[((nt0 + 1) * 5 + k0) * 64 + l];
            s8v bl1 = WL[((nt0 + 1) * 5 + k0) * 64 + l];
            c00 = __builtin_amdgcn_mfma_f32_16x16x32_bf16(ah0, bh0, c00, 0, 0, 0);
            c10 = __builtin_amdgcn_mfma_f32_16x16x32_bf16(ah1, bh0, c10, 0, 0, 0);
            c00 = __builtin_amdgcn_mfma_f32_16x16x32_bf16(al0, bh0, c00, 0, 0, 0);
            c10 = __builtin_amdgcn_mfma_f32_16x16x32_bf16(al1, bh0, c10, 0, 0, 0);
            c00 = __builtin_amdgcn_mfma_f32_16x16x32_bf16(ah0, bl0, c00, 0, 0, 0);
            c10 = __builtin_amdgcn_mfma_f32_16x16x32_bf16(ah1, bl0, c10, 0, 0, 0);
            c01 = __builtin_amdgcn_mfma_f32_16x16x32_bf16(ah0, bh1, c01, 0, 0, 0);
            c11 = __builtin_amdgcn_mfma_f32_16x16x32_bf16(ah1, bh1, c11, 0, 0, 0);
            c01 = __builtin_amdgcn_mfma_f32_16x16x32_bf16(al0, bh1, c01, 0, 0, 0);
            c11 = __builtin_amdgcn_mfma_f32_16x16x32_bf16(al1, bh1, c11, 0, 0, 0);
            c01 = __builtin_amdgcn_mfma_f32_16x16x32_bf16(ah0, bl1, c01, 0, 0, 0);
            c11 = __builtin_amdgcn_mfma_f32_16x16x32_bf16(ah1, bl1, c11, 0, 0, 0);
        }
        unsigned int* hg = h3gP + (size_t)b * 6400;
#pragma unroll
        for (int q = 0; q < 2; q++) {
            int d = (nt0 + q) * 16 + lr;
            float bb = b3[d];
            f32x4 cm0 = q ? c01 : c00;
            f32x4 cm1 = q ? c11 : c10;
#pragma unroll
            for (int mt = 0; mt < 2; mt++) {
                f32x4 cv = mt ? cm1 : cm0;
#pragma unroll
                for (int r = 0; r < 4; r++) {
                    int pos = mt * 16 + lg * 4 + r;
                    if (pos < 25) {
                        float h = fmaxf(cv[r] + bb, 0.f);
                        ushort_t hi = f2bf(h);
                        ushort_t lo = f2bf(h - bf16_to_f(hi));
                        hg[pos * 256 + d] = (unsigned int)hi | ((unsigned int)lo << 16);
                        float sq = h * h;
                        sq += __shfl_xor(sq, 1);
                        sq += __shfl_xor(sq, 2);
                        sq += __shfl_xor(sq, 4);
                        sq += __shfl_xor(sq, 8);
                        if (lr == 0) atomicAdd(&x2s[pos], sq);
                    }
                }
            }
        }
    }
    __syncthreads();
    if (t < 32) x2g[(size_t)b * 32 + t] = x2s[t];
}

// ---------------- E2: MFMA distances + softmax, 16 waves x 2 nt x 4 images ----------------
__global__ __launch_bounds__(1024) void k_enc2(
    const unsigned int* __restrict__ h3gP,   // [4096][25][256] u32
    const float* __restrict__ x2g,           // [4096][32]
    const ushort_t* __restrict__ pfragHi, const ushort_t* __restrict__ pfragLo,
    const float* __restrict__ p2,
    float* __restrict__ md_out,
    ushort_t* __restrict__ Wsm)
{
    int t = threadIdx.x;
    int b0 = blockIdx.x * 4;
    int w = t >> 6, l = t & 63, lr = l & 15, lg = l >> 4;

    __shared__ __align__(16) ushort_t h3s[4][2][32][264];   // 135168 B
    __shared__ float mds[4][512];
    __shared__ float x2sh[4][32];
    __shared__ float wred[4][8];

    // stage h3 with hi/lo unpack (rows >= 25 zeroed)
    for (int i = t; i < 8192; i += 1024) {   // 4img * 32pos * 64 chunks-of-4d
        int im = i >> 11, pos = (i >> 6) & 31, c4 = i & 63;
        us4 hi = {0, 0, 0, 0}, lo = {0, 0, 0, 0};
        if (pos < 25) {
            uint4 v = *(const uint4*)&h3gP[(size_t)(b0 + im) * 6400 + pos * 256 + c4 * 4];
            hi = (us4){(ushort_t)v.x, (ushort_t)v.y, (ushort_t)v.z, (ushort_t)v.w};
            lo = (us4){(ushort_t)(v.x >> 16), (ushort_t)(v.y >> 16),
                       (ushort_t)(v.z >> 16), (ushort_t)(v.w >> 16)};
        }
        *(us4*)&h3s[im][0][pos][c4 * 4] = hi;
        *(us4*)&h3s[im][1][pos][c4 * 4] = lo;
    }
    if (t < 128) x2sh[t >> 5][t & 31] = x2g[(size_t)(b0 + (t >> 5)) * 32 + (t & 31)];
    __syncthreads();

    // dist MFMA: wave w handles nt-pair {2w, 2w+1} for ALL 4 images (B reg reuse x4)
    {
        f32x4 acc[2][4][2];   // [ntq][img][mt]
#pragma unroll
        for (int i = 0; i < 2; i++)
#pragma unroll
            for (int jm = 0; jm < 4; jm++)
#pragma unroll
                for (int mt = 0; mt < 2; mt++) acc[i][jm][mt] = (f32x4){0.f, 0.f, 0.f, 0.f};
        const s8v* BH = (const s8v*)pfragHi;
        const s8v* BL = (const s8v*)pfragLo;
        for (int k0 = 0; k0 < 8; k0++) {
            s8v ah[4][2], al[4][2];
#pragma unroll
            for (int im = 0; im < 4; im++) {
                ah[im][0] = *(const s8v*)&h3s[im][0][lr][k0 * 32 + lg * 8];
                ah[im][1] = *(const s8v*)&h3s[im][0][16 + lr][k0 * 32 + lg * 8];
                al[im][0] = *(const s8v*)&h3s[im][1][lr][k0 * 32 + lg * 8];
                al[im][1] = *(const s8v*)&h3s[im][1][16 + lr][k0 * 32 + lg * 8];
            }
#pragma unroll
            for (int ntq = 0; ntq < 2; ntq++) {
                int nt = w * 2 + ntq;
                s8v bh = BH[(nt * 8 + k0) * 64 + l];
                s8v bl = BL[(nt * 8 + k0) * 64 + l];
#pragma unroll
                for (int im = 0; im < 4; im++) {
                    acc[ntq][im][0] = __builtin_amdgcn_mfma_f32_16x16x32_bf16(ah[im][0], bh, acc[ntq][im][0], 0, 0, 0);
                    acc[ntq][im][1] = __builtin_amdgcn_mfma_f32_16x16x32_bf16(ah[im][1], bh, acc[ntq][im][1], 0, 0, 0);
                    acc[ntq][im][0] = __builtin_amdgcn_mfma_f32_16x16x32_bf16(al[im][0], bh, acc[ntq][im][0], 0, 0, 0);
                    acc[ntq][im][1] = __builtin_amdgcn_mfma_f32_16x16x32_bf16(al[im][1], bh, acc[ntq][im][1], 0, 0, 0);
                    acc[ntq][im][0] = __builtin_amdgcn_mfma_f32_16x16x32_bf16(ah[im][0], bl, acc[ntq][im][0], 0, 0, 0);
                    acc[ntq][im][1] = __builtin_amdgcn_mfma_f32_16x16x32_bf16(ah[im][1], bl, acc[ntq][im][1], 0, 0, 0);
                }
            }
        }
        float x2r[4][8];
#pragma unroll
        for (int im = 0; im < 4; im++)
#pragma unroll
            for (int r = 0; r < 4; r++) {
                x2r[im][r]     = x2sh[im][lg * 4 + r];
                x2r[im][4 + r] = x2sh[im][16 + lg * 4 + r];
            }
#pragma unroll
        for (int ntq = 0; ntq < 2; ntq++) {
            int pcol = (w * 2 + ntq) * 16 + lr;
            float p2v = p2[pcol];
#pragma unroll
            for (int im = 0; im < 4; im++) {
                float mm = 1e30f;
#pragma unroll
                for (int r = 0; r < 4; r++) {
                    float d0 = fmaxf(x2r[im][r]     - 2.f * acc[ntq][im][0][r] + p2v, 0.f);
                    float d1 = fmaxf(x2r[im][4 + r] - 2.f * acc[ntq][im][1][r] + p2v, 0.f);
                    mm = fminf(mm, fminf(d0, d1));
                }
                mm = fminf(mm, __shfl_xor(mm, 16));
                mm = fminf(mm, __shfl_xor(mm, 32));
                if (lg == 0) mds[im][pcol] = mm;
            }
        }
    }
    __syncthreads();

    // softmax: wave group (w>>2) = image; each thread owns p = tt and tt+256
    int img = t >> 8, tt = t & 255;
    float mind0 = mds[img][tt], mind1 = mds[img][tt + 256];
    md_out[(size_t)(b0 + img) * PC + tt] = mind0;
    md_out[(size_t)(b0 + img) * PC + tt + 256] = mind1;
    float a0 = -mind0, a1 = -mind1;
    float mx = fmaxf(a0, a1);
#pragma unroll
    for (int off = 1; off < 64; off <<= 1) mx = fmaxf(mx, __shfl_xor(mx, off));
    if (l == 0) wred[img][w & 3] = mx;
    __syncthreads();
    float m = fmaxf(fmaxf(wred[img][0], wred[img][1]), fmaxf(wred[img][2], wred[img][3]));
    float e0 = expf(a0 - m), e1 = expf(a1 - m);
    float sm = e0 + e1;
#pragma unroll
    for (int off = 1; off < 64; off <<= 1) sm += __shfl_xor(sm, off);
    if (l == 0) wred[img][4 + (w & 3)] = sm;
    __syncthreads();
    float ssum = wred[img][4] + wred[img][5] + wred[img][6] + wred[img][7];
    Wsm[(size_t)(b0 + img) * PC + tt] = f2bf(e0 / ssum);
    Wsm[(size_t)(b0 + img) * PC + tt + 256] = f2bf(e1 / ssum);
}

// ---------------- K2: zupT = Wsm x PW (bf16 MFMA, 2-slab staging), bias+bn+relu ----------
__global__ __launch_bounds__(512) void k_zup2(
    const ushort_t* __restrict__ Wsm,      // [4096][512]
    const ushort_t* __restrict__ PWfrag,   // [400][16][64][8]
    const float* __restrict__ bup, const float* __restrict__ gup,
    const float* __restrict__ btup,
    ushort_t* __restrict__ zupT)           // [4096][6400]
{
    __shared__ __align__(16) ushort_t Bsh[2][8192];
    int t = threadIdx.x;
    int w = t >> 6, l = t & 63;
    int n0 = blockIdx.x * 128;             // 50
    int m0 = blockIdx.y * 128;             // 32
    int row = m0 + w * 16 + (l & 15);
    int krow = (l >> 4) * 8;
    f32x4 acc[8];
#pragma unroll
    for (int i = 0; i < 8; i++) acc[i] = (f32x4){0.f, 0.f, 0.f, 0.f};
    const s8v* B = (const s8v*)PWfrag;
    int base = blockIdx.x * 8 * 16;

    {
        s8v v0 = B[(size_t)(base + (t >> 6) * 16 + 0) * 64 + (t & 63)];
        s8v v1 = B[(size_t)(base + (t >> 6) * 16 + 1) * 64 + (t & 63)];
        *(s8v*)&Bsh[0][t * 8] = v0;
        *(s8v*)&Bsh[0][4096 + t * 8] = v1;
    }
    __syncthreads();
    for (int r = 0; r < 8; r++) {
        int cur = r & 1;
        if (r < 7) {
            s8v v0 = B[(size_t)(base + (t >> 6) * 16 + 2 * r + 2) * 64 + (t & 63)];
            s8v v1 = B[(size_t)(base + (t >> 6) * 16 + 2 * r + 3) * 64 + (t & 63)];
            *(s8v*)&Bsh[cur ^ 1][t * 8] = v0;
            *(s8v*)&Bsh[cur ^ 1][4096 + t * 8] = v1;
        }
#pragma unroll
        for (int kk = 0; kk < 2; kk++) {
            int k0 = 2 * r + kk;
            s8v a = *(const s8v*)&Wsm[(size_t)row * 512 + k0 * 32 + krow];
#pragma unroll
            for (int nt = 0; nt < 8; nt++) {
                s8v bb = *(const s8v*)&Bsh[cur][kk * 4096 + (nt * 64 + l) * 8];
                acc[nt] = __builtin_amdgcn_mfma_f32_16x16x32_bf16(a, bb, acc[nt], 0, 0, 0);
            }
        }
        __syncthreads();
    }

    const float bnr = rsqrtf(1.0f + 1e-5f);
    int rowbase = m0 + w * 16 + (l >> 4) * 4;
#pragma unroll
    for (int nt = 0; nt < 8; nt++) {
        int n = n0 + nt * 16 + (l & 15);
        int ch = n & 255;
        float sc = gup[ch] * bnr, bb = bup[ch], bt = btup[ch];
#pragma unroll
        for (int r = 0; r < 4; r++) {
            float v = (acc[nt][r] + bb) * sc + bt;
            zupT[(size_t)(rowbase + r) * 6400 + n] = f2bf(fmaxf(v, 0.f));
        }
    }
}

// ---------------- K3: fused decoder, 2 img/block, class-per-wave (uniform branches) -------
__global__ __launch_bounds__(512) void k_dtail(
    const ushort_t* __restrict__ zupT,     // [4096][6400]
    const ushort_t* __restrict__ wd1frag,  // [9][8][64][8]
    const float* __restrict__ bd1, const float* __restrict__ gd1, const float* __restrict__ btd1,
    const float* __restrict__ wd2, const float* __restrict__ bd2,
    const float* __restrict__ gd2, const float* __restrict__ btd2,
    const float* __restrict__ wd3, const float* __restrict__ bd3,
    float* __restrict__ out0)
{
    int b0 = blockIdx.x * 2, t = threadIdx.x;
    int w = t >> 6, l = t & 63, lr = l & 15, lg = l >> 4;
    int g = w >> 2, wv = w & 3, tg = t & 255;
    __shared__ __align__(16) unsigned char dbuf[33792];
    __shared__ float hd1p[2][16][64];
    __shared__ float w2sT[9 * 8 * 16];
    __shared__ float w3sT[9 * 8];
    ushort_t* zAb = (ushort_t*)dbuf;
    float* Psb = (float*)dbuf;

    const float bnr = rsqrtf(1.0f + 1e-5f);

    for (int c = t; c < 1600; c += 512) {
        int im = c / 800, cc = c % 800;
        *(us8*)&zAb[im * 8448 + (cc >> 5) * 264 + (cc & 31) * 8] =
            *(const us8*)&zupT[(size_t)(b0 + im) * 6400 + cc * 8];
    }
    for (int i = t; i < 2048; i += 512) ((float*)hd1p)[i] = 0.f;
    for (int i = t; i < 1152; i += 512) {
        int s = i >> 7, rest = i & 127;
        int co = rest >> 4, ci = rest & 15;
        w2sT[i] = wd2[(ci * 8 + co) * 9 + s];
    }
    if (t < 72) {
        int s = t >> 3, ci = t & 7;
        w3sT[t] = wd3[ci * 9 + s];
    }
    __syncthreads();

    {
        f32x4 acc[3][2];
#pragma unroll
        for (int i = 0; i < 3; i++)
#pragma unroll
            for (int mt = 0; mt < 2; mt++) acc[i][mt] = (f32x4){0.f, 0.f, 0.f, 0.f};
        const s8v* B = (const s8v*)wd1frag;
        for (int k0 = 0; k0 < 8; k0++) {
            s8v a0 = *(const s8v*)&zAb[g * 8448 + lr * 264 + k0 * 32 + lg * 8];
            s8v a1 = *(const s8v*)&zAb[g * 8448 + (16 + lr) * 264 + k0 * 32 + lg * 8];
#pragma unroll
            for (int i = 0; i < 3; i++) {
                int nt = wv + 4 * i;
                if (nt < 9) {
                    s8v bb = B[(nt * 8 + k0) * 64 + l];
                    acc[i][0] = __builtin_amdgcn_mfma_f32_16x16x32_bf16(a0, bb, acc[i][0], 0, 0, 0);
                    acc[i][1] = __builtin_amdgcn_mfma_f32_16x16x32_bf16(a1, bb, acc[i][1], 0, 0, 0);
                }
            }
        }
        __syncthreads();
#pragma unroll
        for (int i = 0; i < 3; i++) {
            int nt = wv + 4 * i;
            if (nt < 9) {
                int col = nt * 16 + lr;
#pragma unroll
                for (int mt = 0; mt < 2; mt++)
#pragma unroll
                    for (int r = 0; r < 4; r++) {
                        int pos = mt * 16 + lg * 4 + r;
                        if (pos < 25) Psb[g * 3700 + pos * 148 + col] = acc[i][mt][r];
                    }
            }
        }
    }
    __syncthreads();

    for (int o = tg; o < 784; o += 256) {
        int co = o / 49, rr = o % 49, y = rr / 7, xx = rr % 7;
        float a = bd1[co];
        int sy0 = y - 4 > 0 ? y - 4 : 0, sy1 = y < 2 ? y : 2;
        for (int sy = sy0; sy <= sy1; sy++) {
            int iy = y - sy;
            int sx0 = xx - 4 > 0 ? xx - 4 : 0, sx1 = xx < 2 ? xx : 2;
            for (int sx = sx0; sx <= sx1; sx++) {
                int ix = xx - sx;
                a += Psb[g * 3700 + (iy * 5 + ix) * 148 + co * 9 + sy * 3 + sx];
            }
        }
        float v = a * (gd1[co] * bnr) + btd1[co];
        hd1p[g][co][y * 8 + xx] = fmaxf(v, 0.f);
    }
    __syncthreads();

    {
        if (t < 464) {
            int im = t / 232, rest = t % 232;
            int co = rest / 29, s = rest % 29;
            int yy = (s < 15) ? 14 : (s - 15);
            int xx2 = (s < 15) ? s : 14;
            ((float*)dbuf)[im * 1808 + co * 225 + yy * 15 + xx2] = 0.f;
        }
        int cls = (wv + g) & 3;
        int cy = cls >> 1, cx = cls & 1;
        if (l < 56 && (l & 7) < 7) {
            int r = l >> 3, c = l & 7;
            float acc[8];
#pragma unroll
            for (int co = 0; co < 8; co++) acc[co] = 0.f;
            const float* hb = &hd1p[g][0][0];
            int niy = 1 + cy, nix = 1 + cx;
            for (int ty = 0; ty < niy; ty++) {
                int iy = r + ty;
                int sy = cy ? (ty ? 0 : 2) : 1;
                for (int tx = 0; tx < nix; tx++) {
                    int ix = c + tx;
                    int sx = cx ? (tx ? 0 : 2) : 1;
                    const float* wp = &w2sT[(sy * 3 + sx) * 128];
                    int hoff = iy * 8 + ix;
                    float h[16];
#pragma unroll
                    for (int ci = 0; ci < 16; ci++) h[ci] = hb[ci * 64 + hoff];
#pragma unroll
                    for (int co = 0; co < 8; co++) {
                        const float4* wp4 = (const float4*)&wp[co * 16];
                        float4 wa = wp4[0], wb4 = wp4[1], wc4 = wp4[2], wd4 = wp4[3];
                        float a = acc[co];
                        a = fmaf(h[0], wa.x, a);  a = fmaf(h[1], wa.y, a);
                        a = fmaf(h[2], wa.z, a);  a = fmaf(h[3], wa.w, a);
                        a = fmaf(h[4], wb4.x, a); a = fmaf(h[5], wb4.y, a);
                        a = fmaf(h[6], wb4.z, a); a = fmaf(h[7], wb4.w, a);
                        a = fmaf(h[8], wc4.x, a); a = fmaf(h[9], wc4.y, a);
                        a = fmaf(h[10], wc4.z, a); a = fmaf(h[11], wc4.w, a);
                        a = fmaf(h[12], wd4.x, a); a = fmaf(h[13], wd4.y, a);
                        a = fmaf(h[14], wd4.z, a); a = fmaf(h[15], wd4.w, a);
                        acc[co] = a;
                    }
                }
            }
            int y = 2 * r + cy, x = 2 * c + cx;
            float* hout = (float*)dbuf + g * 1808;
#pragma unroll
            for (int co = 0; co < 8; co++) {
                float v = (acc[co] + bd2[co]) * (gd2[co] * bnr) + btd2[co];
                hout[co * 225 + y * 15 + x] = fmaxf(v, 0.f);
            }
        }
    }
    __syncthreads();

    {
        int cls = (wv + g) & 3;
        int cy = cls >> 1, cx = cls & 1;
        const float* h2b = (const float*)dbuf + g * 1808;
        float* og = out0 + (size_t)(b0 + g) * 784;
        int niy = 1 + cy, nix = 1 + cx;
#pragma unroll
        for (int j = 0; j < 4; j++) {
            int idx = l + 64 * j;
            if (idx < 224) {
                int row = idx >> 4, col = idx & 15;
                if (col < 14) {
                    float a = bd3[0];
                    for (int ty = 0; ty < niy; ty++) {
                        int iy = row + ty;
                        int sy = cy ? (ty ? 0 : 2) : 1;
                        for (int tx = 0; tx < nix; tx++) {
                            int ix = col + tx;
                            int sx = cx ? (tx ? 0 : 2) : 1;
                            const float* wp = &w3sT[(sy * 3 + sx) * 8];
                            int hoff = iy * 15 + ix;
#pragma unroll
                            for (int ci = 0; ci < 8; ci++)
                                a = fmaf(h2b[ci * 225 + hoff], wp[ci], a);
                        }
                    }
                    int y = 2 * row + cy, x = 2 * col + cx;
                    og[y * 28 + x] = 1.f / (1.f + expf(-a));
                }
            }
        }
    }
}

extern "C" void kernel_launch(void* const* d_in, const int* in_sizes, int n_in,
                              void* d_out, int out_size, void* d_ws, size_t ws_size,
                              hipStream_t stream) {
    const float* x    = (const float*)d_in[0];
    const float* w1   = (const float*)d_in[1];
    const float* b1   = (const float*)d_in[2];
    const float* w2   = (const float*)d_in[3];
    const float* b2   = (const float*)d_in[4];
    const float* g2   = (const float*)d_in[5];
    const float* bt2  = (const float*)d_in[6];
    const float* w3   = (const float*)d_in[7];
    const float* b3   = (const float*)d_in[8];
    const float* proto= (const float*)d_in[9];
    const float* wup  = (const float*)d_in[10];
    const float* bup  = (const float*)d_in[11];
    const float* gup  = (const float*)d_in[12];
    const float* btup = (const float*)d_in[13];
    const float* wd1  = (const float*)d_in[14];
    const float* bd1  = (const float*)d_in[15];
    const float* gd1  = (const float*)d_in[16];
    const float* btd1 = (const float*)d_in[17];
    const float* wd2  = (const float*)d_in[18];
    const float* bd2  = (const float*)d_in[19];
    const float* gd2  = (const float*)d_in[20];
    const float* btd2 = (const float*)d_in[21];
    const float* wd3  = (const float*)d_in[22];
    const float* bd3  = (const float*)d_in[23];

    float* out0   = (float*)d_out;                 // [4096][784]
    float* out_md = out0 + (size_t)NB * 784;       // [4096][512]

    // ws layout
    float*    p2      = (float*)d_ws;                          // 512 f
    float*    x2g     = p2 + 512;                              // 131072 f
    ushort_t* pfragHi = (ushort_t*)(x2g + 131072);             // 131072
    ushort_t* pfragLo = pfragHi + 131072;                      // 131072
    ushort_t* w3fH    = pfragLo + 131072;                      // 40960
    ushort_t* w3fL    = w3fH + 40960;                          // 40960
    ushort_t* w2fH    = w3fL + 40960;                          // 1536
    ushort_t* w2fL    = w2fH + 1536;                           // 1536
    ushort_t* wd1frag = w2fL + 1536;                           // 36864
    ushort_t* wupfH   = wd1frag + 36864;                       // 1638400
    ushort_t* wupfL   = wupfH + 1638400;                       // 1638400
    ushort_t* PWfrag  = wupfL + 1638400;                       // 3276800
    ushort_t* Wsm     = PWfrag + 3276800;                      // 2097152
    ushort_t* BIG     = Wsm + 2097152;                         // 104.8 MB region
    unsigned int* h3gP = (unsigned int*)BIG;                   // [4096][25][256] u32
    ushort_t* zupT    = BIG;                                   // [4096][6400] (aliases dead h3gP)

    hipLaunchKernelGGL(k_pre, dim3(7734), dim3(256), 0, stream,
                       proto, p2, pfragHi, pfragLo, w3, w3fH, w3fL,
                       w2, w2fH, w2fL, wd1, wd1frag, wup, wupfH, wupfL);
    hipLaunchKernelGGL(k_pw2, dim3(25, 32), dim3(256), 0, stream,
                       pfragHi, pfragLo, wupfH, wupfL, PWfrag);
    hipLaunchKernelGGL(k_enc1, dim3(NB), dim3(512), 0, stream,
                       x, w1, b1, w2fH, w2fL, b2, g2, bt2, w3fH, w3fL, b3, h3gP, x2g);
    hipLaunchKernelGGL(k_enc2, dim3(NB / 4), dim3(1024), 0, stream,
                       h3gP, x2g, pfragHi, pfragLo, p2, out_md, Wsm);
    hipLaunchKernelGGL(k_zup2, dim3(50, 32), dim3(512), 0, stream,
                       Wsm, PWfrag, bup, gup, btup, zupT);
    hipLaunchKernelGGL(k_dtail, dim3(NB / 2), dim3(512), 0, stream,
                       zupT, wd1frag, bd1, gd1, btd1, wd2, bd2, gd2, btd2, wd3, bd3, out0);
}

// Round 13
// 317.453 us; speedup vs baseline: 1.3513x; 1.3513x over previous
//
#include <hip/hip_runtime.h>
#include <hip/hip_bf16.h>
#include <math.h>

#define NB 4096
#define DC 256
#define PC 512

typedef unsigned short ushort_t;
typedef __attribute__((ext_vector_type(4))) unsigned short us4;
typedef __attribute__((ext_vector_type(8))) unsigned short us8;
typedef __attribute__((ext_vector_type(8))) short s8v;       // bf16x8 for MFMA
typedef __attribute__((ext_vector_type(4))) float f32x4;

__device__ __forceinline__ float bf16_to_f(ushort_t u) {
    union { unsigned int i; float f; } c;
    c.i = ((unsigned int)u) << 16;
    return c.f;
}
__device__ __forceinline__ ushort_t f2bf(float f) {          // RNE
    union { float f; unsigned int u; } c; c.f = f;
    unsigned int r = c.u + 0x7fffu + ((c.u >> 16) & 1u);
    return (ushort_t)(r >> 16);
}

// ---------------- K_pre: all small packing kernels merged (blockIdx-range dispatch) -------
__global__ __launch_bounds__(256) void k_pre(
    const float* __restrict__ proto, float* __restrict__ p2,
    ushort_t* __restrict__ pfragHi, ushort_t* __restrict__ pfragLo,
    const float* __restrict__ w3, ushort_t* __restrict__ w3fH, ushort_t* __restrict__ w3fL,
    const float* __restrict__ w2, ushort_t* __restrict__ w2fH, ushort_t* __restrict__ w2fL,
    const float* __restrict__ wd1, ushort_t* __restrict__ wd1frag,
    const float* __restrict__ wup, ushort_t* __restrict__ wupfH, ushort_t* __restrict__ wupfL)
{
    int b = blockIdx.x, tid = threadIdx.x;
    __shared__ float red[256];
    if (b < 512) {
        int p = b, d = tid;
        float v = proto[p * DC + d];
        red[d] = v * v;
        __syncthreads();
        for (int s = 128; s > 0; s >>= 1) {
            if (d < s) red[d] += red[d + s];
            __syncthreads();
        }
        if (d == 0) p2[p] = red[0];
    } else if (b < 1024) {
        int idx = (b - 512) * 256 + tid;
        int j = idx & 7, l = (idx >> 3) & 63;
        int k0 = (idx >> 9) & 7, nt = idx >> 12;
        int n = nt * 16 + (l & 15);
        int k = k0 * 32 + (l >> 4) * 8 + j;
        float v = proto[n * DC + k];
        ushort_t hi = f2bf(v);
        pfragHi[idx] = hi;
        pfragLo[idx] = f2bf(v - bf16_to_f(hi));
    } else if (b < 1184) {
        int idx = (b - 1024) * 256 + tid;
        int j = idx & 7, l = (idx >> 3) & 63;
        int q = idx >> 9;
        int k0 = q % 5, nt = q / 5;
        int d = nt * 16 + (l & 15);
        int k = k0 * 32 + (l >> 4) * 8 + j;
        float v = (k < 144) ? w3[d * 144 + k] : 0.f;
        ushort_t hi = f2bf(v);
        w3fH[idx] = hi;
        w3fL[idx] = f2bf(v - bf16_to_f(hi));
    } else if (b < 1190) {
        int idx = (b - 1184) * 256 + tid;
        int j = idx & 7, l = (idx >> 3) & 63;
        int k0 = idx >> 9;
        int ch = l & 15;
        int k = k0 * 32 + (l >> 4) * 8 + j;
        float v = (k < 72) ? w2[ch * 72 + k] : 0.f;
        ushort_t hi = f2bf(v);
        w2fH[idx] = hi;
        w2fL[idx] = f2bf(v - bf16_to_f(hi));
    } else if (b < 1334) {
        int idx = (b - 1190) * 256 + tid;
        int j = idx & 7, l = (idx >> 3) & 63;
        int k0 = (idx >> 9) & 7, nt = idx >> 12;
        int n = nt * 16 + (l & 15);
        int k = k0 * 32 + (l >> 4) * 8 + j;
        wd1frag[idx] = f2bf(wd1[k * 144 + n]);
    } else {
        int idx = (b - 1334) * 256 + tid;
        int j = idx & 7, l = (idx >> 3) & 63;
        int k0 = (idx >> 9) & 7, nt = idx >> 12;
        int np = nt * 16 + (l & 15);
        int d = k0 * 32 + (l >> 4) * 8 + j;
        int pos = np >> 8, ch = np & 255;
        float v = wup[d * 6400 + ch * 25 + pos];
        ushort_t hi = f2bf(v);
        wupfH[idx] = hi;
        wupfL[idx] = f2bf(v - bf16_to_f(hi));
    }
}

// ---------------- K0f: PW = proto x wupT via MFMA (hi/lo), -> PWfrag [400][16][64][8] -----
__global__ __launch_bounds__(256) void k_pw2(
    const ushort_t* __restrict__ pfragHi, const ushort_t* __restrict__ pfragLo,
    const ushort_t* __restrict__ wupfH, const ushort_t* __restrict__ wupfL,
    ushort_t* __restrict__ PWfrag)
{
    int t = threadIdx.x;
    int w = t >> 6, l = t & 63, lr = l & 15, lg = l >> 4;
    int my = blockIdx.y;
    int ntb = blockIdx.x * 16 + w * 4;
    const s8v* AH = (const s8v*)pfragHi;
    const s8v* AL = (const s8v*)pfragLo;
    const s8v* BH = (const s8v*)wupfH;
    const s8v* BL = (const s8v*)wupfL;
    f32x4 acc[4];
#pragma unroll
    for (int q = 0; q < 4; q++) acc[q] = (f32x4){0.f, 0.f, 0.f, 0.f};
#pragma unroll
    for (int k0 = 0; k0 < 8; k0++) {
        s8v ah = AH[(my * 8 + k0) * 64 + l];
        s8v al = AL[(my * 8 + k0) * 64 + l];
#pragma unroll
        for (int q = 0; q < 4; q++) {
            s8v bh = BH[(size_t)((ntb + q) * 8 + k0) * 64 + l];
            s8v bl = BL[(size_t)((ntb + q) * 8 + k0) * 64 + l];
            acc[q] = __builtin_amdgcn_mfma_f32_16x16x32_bf16(ah, bh, acc[q], 0, 0, 0);
            acc[q] = __builtin_amdgcn_mfma_f32_16x16x32_bf16(al, bh, acc[q], 0, 0, 0);
            acc[q] = __builtin_amdgcn_mfma_f32_16x16x32_bf16(ah, bl, acc[q], 0, 0, 0);
        }
    }
#pragma unroll
    for (int q = 0; q < 4; q++) {
        int nt = ntb + q;
#pragma unroll
        for (int r = 0; r < 4; r++) {
            int p = my * 16 + lg * 4 + r;
            int k0p = p >> 5;
            int ll = ((p >> 3) & 3) * 16 + lr;
            int jj = p & 7;
            PWfrag[(((size_t)(nt * 16 + k0p) * 64) + ll) * 8 + jj] = f2bf(acc[q][r]);
        }
    }
}

// ---------------- E1: conv1(+scatter im2col2) + conv2 MFMA (+scatter im2col3) + conv3 -----
__global__ __launch_bounds__(512) void k_enc1(
    const float* __restrict__ x,
    const float* __restrict__ w1, const float* __restrict__ b1,
    const ushort_t* __restrict__ w2fH, const ushort_t* __restrict__ w2fL,
    const float* __restrict__ b2,
    const float* __restrict__ g2, const float* __restrict__ bt2,
    const ushort_t* __restrict__ w3fH, const ushort_t* __restrict__ w3fL,
    const float* __restrict__ b3,
    unsigned int* __restrict__ h3gP,   // [4096][25][256] u32 (hi | lo<<16)
    float* __restrict__ x2g)           // [4096][32]
{
    int b = blockIdx.x;
    int t = threadIdx.x;
    int w = t >> 6, l = t & 63, lr = l & 15, lg = l >> 4;

    __shared__ __align__(16) unsigned char buf[39168];
    __shared__ float x2s[32];
    float* xb = (float*)buf;
    ushort_t* im2Hi = (ushort_t*)(buf + 9408);
    ushort_t* im2Lo = (ushort_t*)(buf + 22720);
    float* h2 = (float*)(buf + 36032);
    ushort_t* imHi = (ushort_t*)buf;
    ushort_t* imLo = (ushort_t*)(buf + 9248);

    const float bnr = rsqrtf(1.0f + 1e-5f);

    const float* xg = x + (size_t)b * 784;
    for (int i = t; i < 784; i += 512) xb[i] = xg[i];
    for (int i = t; i < 1664; i += 512)
        ((float4*)(buf + 9408))[i] = (float4){0.f, 0.f, 0.f, 0.f};
    if (t < 32) x2s[t] = (t < 25) ? 0.f : 1e30f;
    __syncthreads();

    // phase 1: conv1 + scatter into im2col2
    for (int o = t; o < 1568; o += 512) {
        int c = o / 196, r = o % 196, y = r / 14, xc = r % 14;
        float acc = b1[c];
        for (int sy = 0; sy < 3; sy++) {
            int iy = 2 * y - 1 + sy;
            if ((unsigned)iy >= 28u) continue;
            for (int sx = 0; sx < 3; sx++) {
                int ix = 2 * xc - 1 + sx;
                if ((unsigned)ix >= 28u) continue;
                acc += w1[c * 9 + sy * 3 + sx] * xb[iy * 28 + ix];
            }
        }
        float v = fmaxf(acc, 0.f);
        ushort_t hi = f2bf(v), lo = f2bf(v - bf16_to_f(hi));
        int kb = c * 9;
        int yA, syA, xA, sxA, yB = 0, xB = 0;
        bool hasYB, hasXB;
        if (y & 1) { yA = y >> 1; syA = 2; yB = yA + 1; hasYB = (yB < 7); }
        else       { yA = y >> 1; syA = 1; hasYB = false; }
        if (xc & 1) { xA = xc >> 1; sxA = 2; xB = xA + 1; hasXB = (xB < 7); }
        else        { xA = xc >> 1; sxA = 1; hasXB = false; }
        int i0 = (yA * 7 + xA) * 104 + kb + syA * 3 + sxA;
        im2Hi[i0] = hi; im2Lo[i0] = lo;
        if (hasXB) {
            int i1 = (yA * 7 + xB) * 104 + kb + syA * 3;
            im2Hi[i1] = hi; im2Lo[i1] = lo;
        }
        if (hasYB) {
            int i2 = (yB * 7 + xA) * 104 + kb + sxA;
            im2Hi[i2] = hi; im2Lo[i2] = lo;
            if (hasXB) {
                int i3 = (yB * 7 + xB) * 104 + kb;
                im2Hi[i3] = hi; im2Lo[i3] = lo;
            }
        }
    }
    __syncthreads();

    // phase 2: conv2 as MFMA (waves 0-3)
    if (w < 4) {
        f32x4 cc = {0, 0, 0, 0};
        const s8v* WH = (const s8v*)w2fH;
        const s8v* WL = (const s8v*)w2fL;
#pragma unroll
        for (int k0 = 0; k0 < 3; k0++) {
            s8v a0 = *(const s8v*)&im2Hi[(w * 16 + lr) * 104 + k0 * 32 + lg * 8];
            s8v a1 = *(const s8v*)&im2Lo[(w * 16 + lr) * 104 + k0 * 32 + lg * 8];
            s8v bh = WH[k0 * 64 + l];
            s8v bl = WL[k0 * 64 + l];
            cc = __builtin_amdgcn_mfma_f32_16x16x32_bf16(a0, bh, cc, 0, 0, 0);
            cc = __builtin_amdgcn_mfma_f32_16x16x32_bf16(a1, bh, cc, 0, 0, 0);
            cc = __builtin_amdgcn_mfma_f32_16x16x32_bf16(a0, bl, cc, 0, 0, 0);
        }
        int ch = lr;
        float s = g2[ch] * bnr, bb = b2[ch], bt = bt2[ch];
#pragma unroll
        for (int r = 0; r < 4; r++) {
            int pos = w * 16 + lg * 4 + r;
            if (pos < 49)
                h2[ch * 49 + pos] = fmaxf((cc[r] + bb) * s + bt, 0.f);
        }
    }
    __syncthreads();

    // phase 3: scatter h2 -> im2col3
    if (t < 16) { imHi[3600 + t] = 0; imLo[3600 + t] = 0; }
    for (int o = t; o < 784; o += 512) {
        float v = h2[o];
        int ci = o / 49, rr = o % 49, iy = rr / 7, ixp = rr % 7;
        ushort_t hi = f2bf(v), lo = f2bf(v - bf16_to_f(hi));
        int kb = ci * 9;
#pragma unroll
        for (int sy = 0; sy < 3; sy++) {
            int py = iy - sy;
            if ((unsigned)py < 5u) {
#pragma unroll
                for (int sx = 0; sx < 3; sx++) {
                    int px = ixp - sx;
                    if ((unsigned)px < 5u) {
                        int idx = (py * 5 + px) * 144 + kb + sy * 3 + sx;
                        imHi[idx] = hi; imLo[idx] = lo;
                    }
                }
            }
        }
    }
    __syncthreads();

    // phase 4: conv3 as MFMA, bias+relu; packed u32 store + x2
    {
        int nt0 = 2 * w;
        f32x4 c00 = {0,0,0,0}, c01 = {0,0,0,0}, c10 = {0,0,0,0}, c11 = {0,0,0,0};
        const s8v* WH = (const s8v*)w3fH;
        const s8v* WL = (const s8v*)w3fL;
#pragma unroll
        for (int k0 = 0; k0 < 5; k0++) {
            s8v ah0 = *(const s8v*)&imHi[lr * 144 + k0 * 32 + lg * 8];
            s8v ah1 = *(const s8v*)&imHi[(16 + lr) * 144 + k0 * 32 + lg * 8];
            s8v al0 = *(const s8v*)&imLo[lr * 144 + k0 * 32 + lg * 8];
            s8v al1 = *(const s8v*)&imLo[(16 + lr) * 144 + k0 * 32 + lg * 8];
            s8v bh0 = WH[(nt0 * 5 + k0) * 64 + l];
            s8v bl0 = WL[(nt0 * 5 + k0) * 64 + l];
            s8v bh1 = WH[((nt0 + 1) * 5 + k0) * 64 + l];
            s8v bl1 = WL[((nt0 + 1) * 5 + k0) * 64 + l];
            c00 = __builtin_amdgcn_mfma_f32_16x16x32_bf16(ah0, bh0, c00, 0, 0, 0);
            c10 = __builtin_amdgcn_mfma_f32_16x16x32_bf16(ah1, bh0, c10, 0, 0, 0);
            c00 = __builtin_amdgcn_mfma_f32_16x16x32_bf16(al0, bh0, c00, 0, 0, 0);
            c10 = __builtin_amdgcn_mfma_f32_16x16x32_bf16(al1, bh0, c10, 0, 0, 0);
            c00 = __builtin_amdgcn_mfma_f32_16x16x32_bf16(ah0, bl0, c00, 0, 0, 0);
            c10 = __builtin_amdgcn_mfma_f32_16x16x32_bf16(ah1, bl0, c10, 0, 0, 0);
            c01 = __builtin_amdgcn_mfma_f32_16x16x32_bf16(ah0, bh1, c01, 0, 0, 0);
            c11 = __builtin_amdgcn_mfma_f32_16x16x32_bf16(ah1, bh1, c11, 0, 0, 0);
            c01 = __builtin_amdgcn_mfma_f32_16x16x32_bf16(al0, bh1, c01, 0, 0, 0);
            c11 = __builtin_amdgcn_mfma_f32_16x16x32_bf16(al1, bh1, c11, 0, 0, 0);
            c01 = __builtin_amdgcn_mfma_f32_16x16x32_bf16(ah0, bl1, c01, 0, 0, 0);
            c11 = __builtin_amdgcn_mfma_f32_16x16x32_bf16(ah1, bl1, c11, 0, 0, 0);
        }
        unsigned int* hg = h3gP + (size_t)b * 6400;
#pragma unroll
        for (int q = 0; q < 2; q++) {
            int d = (nt0 + q) * 16 + lr;
            float bb = b3[d];
            f32x4 cm0 = q ? c01 : c00;
            f32x4 cm1 = q ? c11 : c10;
#pragma unroll
            for (int mt = 0; mt < 2; mt++) {
                f32x4 cv = mt ? cm1 : cm0;
#pragma unroll
                for (int r = 0; r < 4; r++) {
                    int pos = mt * 16 + lg * 4 + r;
                    if (pos < 25) {
                        float h = fmaxf(cv[r] + bb, 0.f);
                        ushort_t hi = f2bf(h);
                        ushort_t lo = f2bf(h - bf16_to_f(hi));
                        hg[pos * 256 + d] = (unsigned int)hi | ((unsigned int)lo << 16);
                        float sq = h * h;
                        sq += __shfl_xor(sq, 1);
                        sq += __shfl_xor(sq, 2);
                        sq += __shfl_xor(sq, 4);
                        sq += __shfl_xor(sq, 8);
                        if (lr == 0) atomicAdd(&x2s[pos], sq);
                    }
                }
            }
        }
    }
    __syncthreads();
    if (t < 32) x2g[(size_t)b * 32 + t] = x2s[t];
}

// ---------------- E2: MFMA distances + softmax -> md_out, Wsm (2 img/block, R10 config) ---
__global__ __launch_bounds__(1024) void k_enc2(
    const unsigned int* __restrict__ h3gP,   // [4096][25][256] u32
    const float* __restrict__ x2g,           // [4096][32]
    const ushort_t* __restrict__ pfragHi, const ushort_t* __restrict__ pfragLo,
    const float* __restrict__ p2,
    float* __restrict__ md_out,
    ushort_t* __restrict__ Wsm)
{
    int t = threadIdx.x;
    int b0 = blockIdx.x * 2;
    int w = t >> 6, l = t & 63, lr = l & 15, lg = l >> 4;

    __shared__ __align__(16) ushort_t h3s[2][2][32][264];   // 67584 B
    __shared__ float mds[2][512];
    __shared__ float x2sh[2][32];
    __shared__ float wred[2][16];

    for (int i = t; i < 4096; i += 1024) {
        int im = i >> 11, pos = (i >> 6) & 31, c4 = i & 63;
        us4 hi = {0, 0, 0, 0}, lo = {0, 0, 0, 0};
        if (pos < 25) {
            uint4 v = *(const uint4*)&h3gP[(size_t)(b0 + im) * 6400 + pos * 256 + c4 * 4];
            hi = (us4){(ushort_t)v.x, (ushort_t)v.y, (ushort_t)v.z, (ushort_t)v.w};
            lo = (us4){(ushort_t)(v.x >> 16), (ushort_t)(v.y >> 16),
                       (ushort_t)(v.z >> 16), (ushort_t)(v.w >> 16)};
        }
        *(us4*)&h3s[im][0][pos][c4 * 4] = hi;
        *(us4*)&h3s[im][1][pos][c4 * 4] = lo;
    }
    if (t < 64) x2sh[t >> 5][t & 31] = x2g[(size_t)(b0 + (t >> 5)) * 32 + (t & 31)];
    __syncthreads();

    {
        const ushort_t* h3hi0 = &h3s[0][0][0][0];
        const ushort_t* h3lo0 = &h3s[0][1][0][0];
        const ushort_t* h3hi1 = &h3s[1][0][0][0];
        const ushort_t* h3lo1 = &h3s[1][1][0][0];
        f32x4 acc[2][2][2];
#pragma unroll
        for (int i = 0; i < 2; i++)
#pragma unroll
            for (int jm = 0; jm < 2; jm++)
#pragma unroll
                for (int mt = 0; mt < 2; mt++) acc[i][jm][mt] = (f32x4){0.f, 0.f, 0.f, 0.f};
        const s8v* BH = (const s8v*)pfragHi;
        const s8v* BL = (const s8v*)pfragLo;
        for (int k0 = 0; k0 < 8; k0++) {
            s8v ah[2][2], al[2][2];
            ah[0][0] = *(const s8v*)&h3hi0[lr * 264 + k0 * 32 + lg * 8];
            ah[0][1] = *(const s8v*)&h3hi0[(16 + lr) * 264 + k0 * 32 + lg * 8];
            al[0][0] = *(const s8v*)&h3lo0[lr * 264 + k0 * 32 + lg * 8];
            al[0][1] = *(const s8v*)&h3lo0[(16 + lr) * 264 + k0 * 32 + lg * 8];
            ah[1][0] = *(const s8v*)&h3hi1[lr * 264 + k0 * 32 + lg * 8];
            ah[1][1] = *(const s8v*)&h3hi1[(16 + lr) * 264 + k0 * 32 + lg * 8];
            al[1][0] = *(const s8v*)&h3lo1[lr * 264 + k0 * 32 + lg * 8];
            al[1][1] = *(const s8v*)&h3lo1[(16 + lr) * 264 + k0 * 32 + lg * 8];
#pragma unroll
            for (int ntq = 0; ntq < 2; ntq++) {
                int nt = w * 2 + ntq;
                s8v bh = BH[(nt * 8 + k0) * 64 + l];
                s8v bl = BL[(nt * 8 + k0) * 64 + l];
#pragma unroll
                for (int im = 0; im < 2; im++) {
                    acc[ntq][im][0] = __builtin_amdgcn_mfma_f32_16x16x32_bf16(ah[im][0], bh, acc[ntq][im][0], 0, 0, 0);
                    acc[ntq][im][1] = __builtin_amdgcn_mfma_f32_16x16x32_bf16(ah[im][1], bh, acc[ntq][im][1], 0, 0, 0);
                    acc[ntq][im][0] = __builtin_amdgcn_mfma_f32_16x16x32_bf16(al[im][0], bh, acc[ntq][im][0], 0, 0, 0);
                    acc[ntq][im][1] = __builtin_amdgcn_mfma_f32_16x16x32_bf16(al[im][1], bh, acc[ntq][im][1], 0, 0, 0);
                    acc[ntq][im][0] = __builtin_amdgcn_mfma_f32_16x16x32_bf16(ah[im][0], bl, acc[ntq][im][0], 0, 0, 0);
                    acc[ntq][im][1] = __builtin_amdgcn_mfma_f32_16x16x32_bf16(ah[im][1], bl, acc[ntq][im][1], 0, 0, 0);
                }
            }
        }
        float x2r[2][8];
#pragma unroll
        for (int im = 0; im < 2; im++)
#pragma unroll
            for (int r = 0; r < 4; r++) {
                x2r[im][r]     = x2sh[im][lg * 4 + r];
                x2r[im][4 + r] = x2sh[im][16 + lg * 4 + r];
            }
#pragma unroll
        for (int ntq = 0; ntq < 2; ntq++) {
            int pcol = (w * 2 + ntq) * 16 + lr;
            float p2v = p2[pcol];
#pragma unroll
            for (int im = 0; im < 2; im++) {
                float mm = 1e30f;
#pragma unroll
                for (int r = 0; r < 4; r++) {
                    float d0 = fmaxf(x2r[im][r]     - 2.f * acc[ntq][im][0][r] + p2v, 0.f);
                    float d1 = fmaxf(x2r[im][4 + r] - 2.f * acc[ntq][im][1][r] + p2v, 0.f);
                    mm = fminf(mm, fminf(d0, d1));
                }
                mm = fminf(mm, __shfl_xor(mm, 16));
                mm = fminf(mm, __shfl_xor(mm, 32));
                if (lg == 0) mds[im][pcol] = mm;
            }
        }
    }
    __syncthreads();

    int img = t >> 9, tt = t & 511;
    float mind = mds[img][tt];
    md_out[(size_t)(b0 + img) * PC + tt] = mind;
    float a = -mind;
    float mx = a;
#pragma unroll
    for (int off = 1; off < 64; off <<= 1) mx = fmaxf(mx, __shfl_xor(mx, off));
    int wv = w & 7;
    if (l == 0) wred[img][wv] = mx;
    __syncthreads();
    float m = wred[img][0];
#pragma unroll
    for (int i = 1; i < 8; i++) m = fmaxf(m, wred[img][i]);
    float e = expf(a - m);
    float sm = e;
#pragma unroll
    for (int off = 1; off < 64; off <<= 1) sm += __shfl_xor(sm, off);
    if (l == 0) wred[img][8 + wv] = sm;
    __syncthreads();
    float ssum = wred[img][8];
#pragma unroll
    for (int i = 9; i < 16; i++) ssum += wred[img][i];
    Wsm[(size_t)(b0 + img) * PC + tt] = f2bf(e / ssum);
}

// ---------------- K2: zupT = Wsm x PW (bf16 MFMA, 2-slab staging), bias+bn+relu ----------
__global__ __launch_bounds__(512) void k_zup2(
    const ushort_t* __restrict__ Wsm,      // [4096][512]
    const ushort_t* __restrict__ PWfrag,   // [400][16][64][8]
    const float* __restrict__ bup, const float* __restrict__ gup,
    const float* __restrict__ btup,
    ushort_t* __restrict__ zupT)           // [4096][6400]
{
    __shared__ __align__(16) ushort_t Bsh[2][8192];
    int t = threadIdx.x;
    int w = t >> 6, l = t & 63;
    int n0 = blockIdx.x * 128;             // 50
    int m0 = blockIdx.y * 128;             // 32
    int row = m0 + w * 16 + (l & 15);
    int krow = (l >> 4) * 8;
    f32x4 acc[8];
#pragma unroll
    for (int i = 0; i < 8; i++) acc[i] = (f32x4){0.f, 0.f, 0.f, 0.f};
    const s8v* B = (const s8v*)PWfrag;
    int base = blockIdx.x * 8 * 16;

    {
        s8v v0 = B[(size_t)(base + (t >> 6) * 16 + 0) * 64 + (t & 63)];
        s8v v1 = B[(size_t)(base + (t >> 6) * 16 + 1) * 64 + (t & 63)];
        *(s8v*)&Bsh[0][t * 8] = v0;
        *(s8v*)&Bsh[0][4096 + t * 8] = v1;
    }
    __syncthreads();
    for (int r = 0; r < 8; r++) {
        int cur = r & 1;
        if (r < 7) {
            s8v v0 = B[(size_t)(base + (t >> 6) * 16 + 2 * r + 2) * 64 + (t & 63)];
            s8v v1 = B[(size_t)(base + (t >> 6) * 16 + 2 * r + 3) * 64 + (t & 63)];
            *(s8v*)&Bsh[cur ^ 1][t * 8] = v0;
            *(s8v*)&Bsh[cur ^ 1][4096 + t * 8] = v1;
        }
#pragma unroll
        for (int kk = 0; kk < 2; kk++) {
            int k0 = 2 * r + kk;
            s8v a = *(const s8v*)&Wsm[(size_t)row * 512 + k0 * 32 + krow];
#pragma unroll
            for (int nt = 0; nt < 8; nt++) {
                s8v bb = *(const s8v*)&Bsh[cur][kk * 4096 + (nt * 64 + l) * 8];
                acc[nt] = __builtin_amdgcn_mfma_f32_16x16x32_bf16(a, bb, acc[nt], 0, 0, 0);
            }
        }
        __syncthreads();
    }

    const float bnr = rsqrtf(1.0f + 1e-5f);
    int rowbase = m0 + w * 16 + (l >> 4) * 4;
#pragma unroll
    for (int nt = 0; nt < 8; nt++) {
        int n = n0 + nt * 16 + (l & 15);
        int ch = n & 255;
        float sc = gup[ch] * bnr, bb = bup[ch], bt = btup[ch];
#pragma unroll
        for (int r = 0; r < 4; r++) {
            float v = (acc[nt][r] + bb) * sc + bt;
            zupT[(size_t)(rowbase + r) * 6400 + n] = f2bf(fmaxf(v, 0.f));
        }
    }
}

// ---------------- K3: fused decoder, 2 img/block, class-per-wave (uniform branches) -------
__global__ __launch_bounds__(512) void k_dtail(
    const ushort_t* __restrict__ zupT,     // [4096][6400]
    const ushort_t* __restrict__ wd1frag,  // [9][8][64][8]
    const float* __restrict__ bd1, const float* __restrict__ gd1, const float* __restrict__ btd1,
    const float* __restrict__ wd2, const float* __restrict__ bd2,
    const float* __restrict__ gd2, const float* __restrict__ btd2,
    const float* __restrict__ wd3, const float* __restrict__ bd3,
    float* __restrict__ out0)
{
    int b0 = blockIdx.x * 2, t = threadIdx.x;
    int w = t >> 6, l = t & 63, lr = l & 15, lg = l >> 4;
    int g = w >> 2, wv = w & 3, tg = t & 255;
    __shared__ __align__(16) unsigned char dbuf[33792];
    __shared__ float hd1p[2][16][64];
    __shared__ float w2sT[9 * 8 * 16];
    __shared__ float w3sT[9 * 8];
    ushort_t* zAb = (ushort_t*)dbuf;
    float* Psb = (float*)dbuf;

    const float bnr = rsqrtf(1.0f + 1e-5f);

    for (int c = t; c < 1600; c += 512) {
        int im = c / 800, cc = c % 800;
        *(us8*)&zAb[im * 8448 + (cc >> 5) * 264 + (cc & 31) * 8] =
            *(const us8*)&zupT[(size_t)(b0 + im) * 6400 + cc * 8];
    }
    for (int i = t; i < 2048; i += 512) ((float*)hd1p)[i] = 0.f;
    for (int i = t; i < 1152; i += 512) {
        int s = i >> 7, rest = i & 127;
        int co = rest >> 4, ci = rest & 15;
        w2sT[i] = wd2[(ci * 8 + co) * 9 + s];
    }
    if (t < 72) {
        int s = t >> 3, ci = t & 7;
        w3sT[t] = wd3[ci * 9 + s];
    }
    __syncthreads();

    {
        f32x4 acc[3][2];
#pragma unroll
        for (int i = 0; i < 3; i++)
#pragma unroll
            for (int mt = 0; mt < 2; mt++) acc[i][mt] = (f32x4){0.f, 0.f, 0.f, 0.f};
        const s8v* B = (const s8v*)wd1frag;
        for (int k0 = 0; k0 < 8; k0++) {
            s8v a0 = *(const s8v*)&zAb[g * 8448 + lr * 264 + k0 * 32 + lg * 8];
            s8v a1 = *(const s8v*)&zAb[g * 8448 + (16 + lr) * 264 + k0 * 32 + lg * 8];
#pragma unroll
            for (int i = 0; i < 3; i++) {
                int nt = wv + 4 * i;
                if (nt < 9) {
                    s8v bb = B[(nt * 8 + k0) * 64 + l];
                    acc[i][0] = __builtin_amdgcn_mfma_f32_16x16x32_bf16(a0, bb, acc[i][0], 0, 0, 0);
                    acc[i][1] = __builtin_amdgcn_mfma_f32_16x16x32_bf16(a1, bb, acc[i][1], 0, 0, 0);
                }
            }
        }
        __syncthreads();
#pragma unroll
        for (int i = 0; i < 3; i++) {
            int nt = wv + 4 * i;
            if (nt < 9) {
                int col = nt * 16 + lr;
#pragma unroll
                for (int mt = 0; mt < 2; mt++)
#pragma unroll
                    for (int r = 0; r < 4; r++) {
                        int pos = mt * 16 + lg * 4 + r;
                        if (pos < 25) Psb[g * 3700 + pos * 148 + col] = acc[i][mt][r];
                    }
            }
        }
    }
    __syncthreads();

    for (int o = tg; o < 784; o += 256) {
        int co = o / 49, rr = o % 49, y = rr / 7, xx = rr % 7;
        float a = bd1[co];
        int sy0 = y - 4 > 0 ? y - 4 : 0, sy1 = y < 2 ? y : 2;
        for (int sy = sy0; sy <= sy1; sy++) {
            int iy = y - sy;
            int sx0 = xx - 4 > 0 ? xx - 4 : 0, sx1 = xx < 2 ? xx : 2;
            for (int sx = sx0; sx <= sx1; sx++) {
                int ix = xx - sx;
                a += Psb[g * 3700 + (iy * 5 + ix) * 148 + co * 9 + sy * 3 + sx];
            }
        }
        float v = a * (gd1[co] * bnr) + btd1[co];
        hd1p[g][co][y * 8 + xx] = fmaxf(v, 0.f);
    }
    __syncthreads();

    {
        if (t < 464) {
            int im = t / 232, rest = t % 232;
            int co = rest / 29, s = rest % 29;
            int yy = (s < 15) ? 14 : (s - 15);
            int xx2 = (s < 15) ? s : 14;
            ((float*)dbuf)[im * 1808 + co * 225 + yy * 15 + xx2] = 0.f;
        }
        int cls = (wv + g) & 3;
        int cy = cls >> 1, cx = cls & 1;
        if (l < 56 && (l & 7) < 7) {
            int r = l >> 3, c = l & 7;
            float acc[8];
#pragma unroll
            for (int co = 0; co < 8; co++) acc[co] = 0.f;
            const float* hb = &hd1p[g][0][0];
            int niy = 1 + cy, nix = 1 + cx;
            for (int ty = 0; ty < niy; ty++) {
                int iy = r + ty;
                int sy = cy ? (ty ? 0 : 2) : 1;
                for (int tx = 0; tx < nix; tx++) {
                    int ix = c + tx;
                    int sx = cx ? (tx ? 0 : 2) : 1;
                    const float* wp = &w2sT[(sy * 3 + sx) * 128];
                    int hoff = iy * 8 + ix;
                    float h[16];
#pragma unroll
                    for (int ci = 0; ci < 16; ci++) h[ci] = hb[ci * 64 + hoff];
#pragma unroll
                    for (int co = 0; co < 8; co++) {
                        const float4* wp4 = (const float4*)&wp[co * 16];
                        float4 wa = wp4[0], wb4 = wp4[1], wc4 = wp4[2], wd4 = wp4[3];
                        float a = acc[co];
                        a = fmaf(h[0], wa.x, a);  a = fmaf(h[1], wa.y, a);
                        a = fmaf(h[2], wa.z, a);  a = fmaf(h[3], wa.w, a);
                        a = fmaf(h[4], wb4.x, a); a = fmaf(h[5], wb4.y, a);
                        a = fmaf(h[6], wb4.z, a); a = fmaf(h[7], wb4.w, a);
                        a = fmaf(h[8], wc4.x, a); a = fmaf(h[9], wc4.y, a);
                        a = fmaf(h[10], wc4.z, a); a = fmaf(h[11], wc4.w, a);
                        a = fmaf(h[12], wd4.x, a); a = fmaf(h[13], wd4.y, a);
                        a = fmaf(h[14], wd4.z, a); a = fmaf(h[15], wd4.w, a);
                        acc[co] = a;
                    }
                }
            }
            int y = 2 * r + cy, x = 2 * c + cx;
            float* hout = (float*)dbuf + g * 1808;
#pragma unroll
            for (int co = 0; co < 8; co++) {
                float v = (acc[co] + bd2[co]) * (gd2[co] * bnr) + btd2[co];
                hout[co * 225 + y * 15 + x] = fmaxf(v, 0.f);
            }
        }
    }
    __syncthreads();

    {
        int cls = (wv + g) & 3;
        int cy = cls >> 1, cx = cls & 1;
        const float* h2b = (const float*)dbuf + g * 1808;
        float* og = out0 + (size_t)(b0 + g) * 784;
        int niy = 1 + cy, nix = 1 + cx;
#pragma unroll
        for (int j = 0; j < 4; j++) {
            int idx = l + 64 * j;
            if (idx < 224) {
                int row = idx >> 4, col = idx & 15;
                if (col < 14) {
                    float a = bd3[0];
                    for (int ty = 0; ty < niy; ty++) {
                        int iy = row + ty;
                        int sy = cy ? (ty ? 0 : 2) : 1;
                        for (int tx = 0; tx < nix; tx++) {
                            int ix = col + tx;
                            int sx = cx ? (tx ? 0 : 2) : 1;
                            const float* wp = &w3sT[(sy * 3 + sx) * 8];
                            int hoff = iy * 15 + ix;
#pragma unroll
                            for (int ci = 0; ci < 8; ci++)
                                a = fmaf(h2b[ci * 225 + hoff], wp[ci], a);
                        }
                    }
                    int y = 2 * row + cy, x = 2 * col + cx;
                    og[y * 28 + x] = 1.f / (1.f + expf(-a));
                }
            }
        }
    }
}

extern "C" void kernel_launch(void* const* d_in, const int* in_sizes, int n_in,
                              void* d_out, int out_size, void* d_ws, size_t ws_size,
                              hipStream_t stream) {
    const float* x    = (const float*)d_in[0];
    const float* w1   = (const float*)d_in[1];
    const float* b1   = (const float*)d_in[2];
    const float* w2   = (const float*)d_in[3];
    const float* b2   = (const float*)d_in[4];
    const float* g2   = (const float*)d_in[5];
    const float* bt2  = (const float*)d_in[6];
    const float* w3   = (const float*)d_in[7];
    const float* b3   = (const float*)d_in[8];
    const float* proto= (const float*)d_in[9];
    const float* wup  = (const float*)d_in[10];
    const float* bup  = (const float*)d_in[11];
    const float* gup  = (const float*)d_in[12];
    const float* btup = (const float*)d_in[13];
    const float* wd1  = (const float*)d_in[14];
    const float* bd1  = (const float*)d_in[15];
    const float* gd1  = (const float*)d_in[16];
    const float* btd1 = (const float*)d_in[17];
    const float* wd2  = (const float*)d_in[18];
    const float* bd2  = (const float*)d_in[19];
    const float* gd2  = (const float*)d_in[20];
    const float* btd2 = (const float*)d_in[21];
    const float* wd3  = (const float*)d_in[22];
    const float* bd3  = (const float*)d_in[23];

    float* out0   = (float*)d_out;                 // [4096][784]
    float* out_md = out0 + (size_t)NB * 784;       // [4096][512]

    // ws layout
    float*    p2      = (float*)d_ws;                          // 512 f
    float*    x2g     = p2 + 512;                              // 131072 f
    ushort_t* pfragHi = (ushort_t*)(x2g + 131072);             // 131072
    ushort_t* pfragLo = pfragHi + 131072;                      // 131072
    ushort_t* w3fH    = pfragLo + 131072;                      // 40960
    ushort_t* w3fL    = w3fH + 40960;                          // 40960
    ushort_t* w2fH    = w3fL + 40960;                          // 1536
    ushort_t* w2fL    = w2fH + 1536;                           // 1536
    ushort_t* wd1frag = w2fL + 1536;                           // 36864
    ushort_t* wupfH   = wd1frag + 36864;                       // 1638400
    ushort_t* wupfL   = wupfH + 1638400;                       // 1638400
    ushort_t* PWfrag  = wupfL + 1638400;                       // 3276800
    ushort_t* Wsm     = PWfrag + 3276800;                      // 2097152
    ushort_t* BIG     = Wsm + 2097152;                         // 104.8 MB region
    unsigned int* h3gP = (unsigned int*)BIG;                   // [4096][25][256] u32
    ushort_t* zupT    = BIG;                                   // [4096][6400] (aliases dead h3gP)

    hipLaunchKernelGGL(k_pre, dim3(7734), dim3(256), 0, stream,
                       proto, p2, pfragHi, pfragLo, w3, w3fH, w3fL,
                       w2, w2fH, w2fL, wd1, wd1frag, wup, wupfH, wupfL);
    hipLaunchKernelGGL(k_pw2, dim3(25, 32), dim3(256), 0, stream,
                       pfragHi, pfragLo, wupfH, wupfL, PWfrag);
    hipLaunchKernelGGL(k_enc1, dim3(NB), dim3(512), 0, stream,
                       x, w1, b1, w2fH, w2fL, b2, g2, bt2, w3fH, w3fL, b3, h3gP, x2g);
    hipLaunchKernelGGL(k_enc2, dim3(NB / 2), dim3(1024), 0, stream,
                       h3gP, x2g, pfragHi, pfragLo, p2, out_md, Wsm);
    hipLaunchKernelGGL(k_zup2, dim3(50, 32), dim3(512), 0, stream,
                       Wsm, PWfrag, bup, gup, btup, zupT);
    hipLaunchKernelGGL(k_dtail, dim3(NB / 2), dim3(512), 0, stream,
                       zupT, wd1frag, bd1, gd1, btd1, wd2, bd2, gd2, btd2, wd3, bd3, out0);
}

// Round 14
// 314.350 us; speedup vs baseline: 1.3647x; 1.0099x over previous
//
#include <hip/hip_runtime.h>
#include <hip/hip_bf16.h>
#include <math.h>

#define NB 4096
#define DC 256
#define PC 512

typedef unsigned short ushort_t;
typedef __attribute__((ext_vector_type(4))) unsigned short us4;
typedef __attribute__((ext_vector_type(8))) unsigned short us8;
typedef __attribute__((ext_vector_type(8))) short s8v;       // bf16x8 for MFMA
typedef __attribute__((ext_vector_type(4))) float f32x4;

__device__ __forceinline__ float bf16_to_f(ushort_t u) {
    union { unsigned int i; float f; } c;
    c.i = ((unsigned int)u) << 16;
    return c.f;
}
__device__ __forceinline__ ushort_t f2bf(float f) {          // RNE
    union { float f; unsigned int u; } c; c.f = f;
    unsigned int r = c.u + 0x7fffu + ((c.u >> 16) & 1u);
    return (ushort_t)(r >> 16);
}

// ---------------- K_pre: all small packing kernels merged (blockIdx-range dispatch) -------
__global__ __launch_bounds__(256) void k_pre(
    const float* __restrict__ proto, float* __restrict__ p2,
    ushort_t* __restrict__ pfragHi, ushort_t* __restrict__ pfragLo,
    const float* __restrict__ w3, ushort_t* __restrict__ w3fH, ushort_t* __restrict__ w3fL,
    const float* __restrict__ w2, ushort_t* __restrict__ w2fH, ushort_t* __restrict__ w2fL,
    const float* __restrict__ wd1, ushort_t* __restrict__ wd1frag,
    const float* __restrict__ wup, ushort_t* __restrict__ wupfH, ushort_t* __restrict__ wupfL)
{
    int b = blockIdx.x, tid = threadIdx.x;
    __shared__ float red[256];
    if (b < 512) {
        int p = b, d = tid;
        float v = proto[p * DC + d];
        red[d] = v * v;
        __syncthreads();
        for (int s = 128; s > 0; s >>= 1) {
            if (d < s) red[d] += red[d + s];
            __syncthreads();
        }
        if (d == 0) p2[p] = red[0];
    } else if (b < 1024) {
        int idx = (b - 512) * 256 + tid;
        int j = idx & 7, l = (idx >> 3) & 63;
        int k0 = (idx >> 9) & 7, nt = idx >> 12;
        int n = nt * 16 + (l & 15);
        int k = k0 * 32 + (l >> 4) * 8 + j;
        float v = proto[n * DC + k];
        ushort_t hi = f2bf(v);
        pfragHi[idx] = hi;
        pfragLo[idx] = f2bf(v - bf16_to_f(hi));
    } else if (b < 1184) {
        int idx = (b - 1024) * 256 + tid;
        int j = idx & 7, l = (idx >> 3) & 63;
        int q = idx >> 9;
        int k0 = q % 5, nt = q / 5;
        int d = nt * 16 + (l & 15);
        int k = k0 * 32 + (l >> 4) * 8 + j;
        float v = (k < 144) ? w3[d * 144 + k] : 0.f;
        ushort_t hi = f2bf(v);
        w3fH[idx] = hi;
        w3fL[idx] = f2bf(v - bf16_to_f(hi));
    } else if (b < 1190) {
        int idx = (b - 1184) * 256 + tid;
        int j = idx & 7, l = (idx >> 3) & 63;
        int k0 = idx >> 9;
        int ch = l & 15;
        int k = k0 * 32 + (l >> 4) * 8 + j;
        float v = (k < 72) ? w2[ch * 72 + k] : 0.f;
        ushort_t hi = f2bf(v);
        w2fH[idx] = hi;
        w2fL[idx] = f2bf(v - bf16_to_f(hi));
    } else if (b < 1334) {
        int idx = (b - 1190) * 256 + tid;
        int j = idx & 7, l = (idx >> 3) & 63;
        int k0 = (idx >> 9) & 7, nt = idx >> 12;
        int n = nt * 16 + (l & 15);
        int k = k0 * 32 + (l >> 4) * 8 + j;
        wd1frag[idx] = f2bf(wd1[k * 144 + n]);
    } else {
        int idx = (b - 1334) * 256 + tid;
        int j = idx & 7, l = (idx >> 3) & 63;
        int k0 = (idx >> 9) & 7, nt = idx >> 12;
        int np = nt * 16 + (l & 15);
        int d = k0 * 32 + (l >> 4) * 8 + j;
        int pos = np >> 8, ch = np & 255;
        float v = wup[d * 6400 + ch * 25 + pos];
        ushort_t hi = f2bf(v);
        wupfH[idx] = hi;
        wupfL[idx] = f2bf(v - bf16_to_f(hi));
    }
}

// ---------------- K0f: PW = proto x wupT via MFMA (hi/lo), -> PWfrag [400][16][64][8] -----
__global__ __launch_bounds__(256) void k_pw2(
    const ushort_t* __restrict__ pfragHi, const ushort_t* __restrict__ pfragLo,
    const ushort_t* __restrict__ wupfH, const ushort_t* __restrict__ wupfL,
    ushort_t* __restrict__ PWfrag)
{
    int t = threadIdx.x;
    int w = t >> 6, l = t & 63, lr = l & 15, lg = l >> 4;
    int my = blockIdx.y;
    int ntb = blockIdx.x * 16 + w * 4;
    const s8v* AH = (const s8v*)pfragHi;
    const s8v* AL = (const s8v*)pfragLo;
    const s8v* BH = (const s8v*)wupfH;
    const s8v* BL = (const s8v*)wupfL;
    f32x4 acc[4];
#pragma unroll
    for (int q = 0; q < 4; q++) acc[q] = (f32x4){0.f, 0.f, 0.f, 0.f};
#pragma unroll
    for (int k0 = 0; k0 < 8; k0++) {
        s8v ah = AH[(my * 8 + k0) * 64 + l];
        s8v al = AL[(my * 8 + k0) * 64 + l];
#pragma unroll
        for (int q = 0; q < 4; q++) {
            s8v bh = BH[(size_t)((ntb + q) * 8 + k0) * 64 + l];
            s8v bl = BL[(size_t)((ntb + q) * 8 + k0) * 64 + l];
            acc[q] = __builtin_amdgcn_mfma_f32_16x16x32_bf16(ah, bh, acc[q], 0, 0, 0);
            acc[q] = __builtin_amdgcn_mfma_f32_16x16x32_bf16(al, bh, acc[q], 0, 0, 0);
            acc[q] = __builtin_amdgcn_mfma_f32_16x16x32_bf16(ah, bl, acc[q], 0, 0, 0);
        }
    }
#pragma unroll
    for (int q = 0; q < 4; q++) {
        int nt = ntb + q;
#pragma unroll
        for (int r = 0; r < 4; r++) {
            int p = my * 16 + lg * 4 + r;
            int k0p = p >> 5;
            int ll = ((p >> 3) & 3) * 16 + lr;
            int jj = p & 7;
            PWfrag[(((size_t)(nt * 16 + k0p) * 64) + ll) * 8 + jj] = f2bf(acc[q][r]);
        }
    }
}

// ---------------- E1: conv1(+scatter im2col2) + conv2 MFMA (+scatter im2col3) + conv3 -----
__global__ __launch_bounds__(512) void k_enc1(
    const float* __restrict__ x,
    const float* __restrict__ w1, const float* __restrict__ b1,
    const ushort_t* __restrict__ w2fH, const ushort_t* __restrict__ w2fL,
    const float* __restrict__ b2,
    const float* __restrict__ g2, const float* __restrict__ bt2,
    const ushort_t* __restrict__ w3fH, const ushort_t* __restrict__ w3fL,
    const float* __restrict__ b3,
    unsigned int* __restrict__ h3gP,   // [4096][25][256] u32 (hi | lo<<16)
    float* __restrict__ x2g)           // [4096][32]
{
    int b = blockIdx.x;
    int t = threadIdx.x;
    int w = t >> 6, l = t & 63, lr = l & 15, lg = l >> 4;

    __shared__ __align__(16) unsigned char buf[39168];
    __shared__ float x2s[32];
    float* xb = (float*)buf;
    ushort_t* im2Hi = (ushort_t*)(buf + 9408);
    ushort_t* im2Lo = (ushort_t*)(buf + 22720);
    float* h2 = (float*)(buf + 36032);
    ushort_t* imHi = (ushort_t*)buf;
    ushort_t* imLo = (ushort_t*)(buf + 9248);

    const float bnr = rsqrtf(1.0f + 1e-5f);

    const float* xg = x + (size_t)b * 784;
    for (int i = t; i < 784; i += 512) xb[i] = xg[i];
    for (int i = t; i < 1664; i += 512)
        ((float4*)(buf + 9408))[i] = (float4){0.f, 0.f, 0.f, 0.f};
    if (t < 32) x2s[t] = (t < 25) ? 0.f : 1e30f;
    __syncthreads();

    // phase 1: conv1 + scatter into im2col2
    for (int o = t; o < 1568; o += 512) {
        int c = o / 196, r = o % 196, y = r / 14, xc = r % 14;
        float acc = b1[c];
        for (int sy = 0; sy < 3; sy++) {
            int iy = 2 * y - 1 + sy;
            if ((unsigned)iy >= 28u) continue;
            for (int sx = 0; sx < 3; sx++) {
                int ix = 2 * xc - 1 + sx;
                if ((unsigned)ix >= 28u) continue;
                acc += w1[c * 9 + sy * 3 + sx] * xb[iy * 28 + ix];
            }
        }
        float v = fmaxf(acc, 0.f);
        ushort_t hi = f2bf(v), lo = f2bf(v - bf16_to_f(hi));
        int kb = c * 9;
        int yA, syA, xA, sxA, yB = 0, xB = 0;
        bool hasYB, hasXB;
        if (y & 1) { yA = y >> 1; syA = 2; yB = yA + 1; hasYB = (yB < 7); }
        else       { yA = y >> 1; syA = 1; hasYB = false; }
        if (xc & 1) { xA = xc >> 1; sxA = 2; xB = xA + 1; hasXB = (xB < 7); }
        else        { xA = xc >> 1; sxA = 1; hasXB = false; }
        int i0 = (yA * 7 + xA) * 104 + kb + syA * 3 + sxA;
        im2Hi[i0] = hi; im2Lo[i0] = lo;
        if (hasXB) {
            int i1 = (yA * 7 + xB) * 104 + kb + syA * 3;
            im2Hi[i1] = hi; im2Lo[i1] = lo;
        }
        if (hasYB) {
            int i2 = (yB * 7 + xA) * 104 + kb + sxA;
            im2Hi[i2] = hi; im2Lo[i2] = lo;
            if (hasXB) {
                int i3 = (yB * 7 + xB) * 104 + kb;
                im2Hi[i3] = hi; im2Lo[i3] = lo;
            }
        }
    }
    __syncthreads();

    // phase 2: conv2 as MFMA (waves 0-3)
    if (w < 4) {
        f32x4 cc = {0, 0, 0, 0};
        const s8v* WH = (const s8v*)w2fH;
        const s8v* WL = (const s8v*)w2fL;
#pragma unroll
        for (int k0 = 0; k0 < 3; k0++) {
            s8v a0 = *(const s8v*)&im2Hi[(w * 16 + lr) * 104 + k0 * 32 + lg * 8];
            s8v a1 = *(const s8v*)&im2Lo[(w * 16 + lr) * 104 + k0 * 32 + lg * 8];
            s8v bh = WH[k0 * 64 + l];
            s8v bl = WL[k0 * 64 + l];
            cc = __builtin_amdgcn_mfma_f32_16x16x32_bf16(a0, bh, cc, 0, 0, 0);
            cc = __builtin_amdgcn_mfma_f32_16x16x32_bf16(a1, bh, cc, 0, 0, 0);
            cc = __builtin_amdgcn_mfma_f32_16x16x32_bf16(a0, bl, cc, 0, 0, 0);
        }
        int ch = lr;
        float s = g2[ch] * bnr, bb = b2[ch], bt = bt2[ch];
#pragma unroll
        for (int r = 0; r < 4; r++) {
            int pos = w * 16 + lg * 4 + r;
            if (pos < 49)
                h2[ch * 49 + pos] = fmaxf((cc[r] + bb) * s + bt, 0.f);
        }
    }
    __syncthreads();

    // phase 3: scatter h2 -> im2col3
    if (t < 16) { imHi[3600 + t] = 0; imLo[3600 + t] = 0; }
    for (int o = t; o < 784; o += 512) {
        float v = h2[o];
        int ci = o / 49, rr = o % 49, iy = rr / 7, ixp = rr % 7;
        ushort_t hi = f2bf(v), lo = f2bf(v - bf16_to_f(hi));
        int kb = ci * 9;
#pragma unroll
        for (int sy = 0; sy < 3; sy++) {
            int py = iy - sy;
            if ((unsigned)py < 5u) {
#pragma unroll
                for (int sx = 0; sx < 3; sx++) {
                    int px = ixp - sx;
                    if ((unsigned)px < 5u) {
                        int idx = (py * 5 + px) * 144 + kb + sy * 3 + sx;
                        imHi[idx] = hi; imLo[idx] = lo;
                    }
                }
            }
        }
    }
    __syncthreads();

    // phase 4: conv3 as MFMA, bias+relu; packed u32 store + x2
    {
        int nt0 = 2 * w;
        f32x4 c00 = {0,0,0,0}, c01 = {0,0,0,0}, c10 = {0,0,0,0}, c11 = {0,0,0,0};
        const s8v* WH = (const s8v*)w3fH;
        const s8v* WL = (const s8v*)w3fL;
#pragma unroll
        for (int k0 = 0; k0 < 5; k0++) {
            s8v ah0 = *(const s8v*)&imHi[lr * 144 + k0 * 32 + lg * 8];
            s8v ah1 = *(const s8v*)&imHi[(16 + lr) * 144 + k0 * 32 + lg * 8];
            s8v al0 = *(const s8v*)&imLo[lr * 144 + k0 * 32 + lg * 8];
            s8v al1 = *(const s8v*)&imLo[(16 + lr) * 144 + k0 * 32 + lg * 8];
            s8v bh0 = WH[(nt0 * 5 + k0) * 64 + l];
            s8v bl0 = WL[(nt0 * 5 + k0) * 64 + l];
            s8v bh1 = WH[((nt0 + 1) * 5 + k0) * 64 + l];
            s8v bl1 = WL[((nt0 + 1) * 5 + k0) * 64 + l];
            c00 = __builtin_amdgcn_mfma_f32_16x16x32_bf16(ah0, bh0, c00, 0, 0, 0);
            c10 = __builtin_amdgcn_mfma_f32_16x16x32_bf16(ah1, bh0, c10, 0, 0, 0);
            c00 = __builtin_amdgcn_mfma_f32_16x16x32_bf16(al0, bh0, c00, 0, 0, 0);
            c10 = __builtin_amdgcn_mfma_f32_16x16x32_bf16(al1, bh0, c10, 0, 0, 0);
            c00 = __builtin_amdgcn_mfma_f32_16x16x32_bf16(ah0, bl0, c00, 0, 0, 0);
            c10 = __builtin_amdgcn_mfma_f32_16x16x32_bf16(ah1, bl0, c10, 0, 0, 0);
            c01 = __builtin_amdgcn_mfma_f32_16x16x32_bf16(ah0, bh1, c01, 0, 0, 0);
            c11 = __builtin_amdgcn_mfma_f32_16x16x32_bf16(ah1, bh1, c11, 0, 0, 0);
            c01 = __builtin_amdgcn_mfma_f32_16x16x32_bf16(al0, bh1, c01, 0, 0, 0);
            c11 = __builtin_amdgcn_mfma_f32_16x16x32_bf16(al1, bh1, c11, 0, 0, 0);
            c01 = __builtin_amdgcn_mfma_f32_16x16x32_bf16(ah0, bl1, c01, 0, 0, 0);
            c11 = __builtin_amdgcn_mfma_f32_16x16x32_bf16(ah1, bl1, c11, 0, 0, 0);
        }
        unsigned int* hg = h3gP + (size_t)b * 6400;
#pragma unroll
        for (int q = 0; q < 2; q++) {
            int d = (nt0 + q) * 16 + lr;
            float bb = b3[d];
            f32x4 cm0 = q ? c01 : c00;
            f32x4 cm1 = q ? c11 : c10;
#pragma unroll
            for (int mt = 0; mt < 2; mt++) {
                f32x4 cv = mt ? cm1 : cm0;
#pragma unroll
                for (int r = 0; r < 4; r++) {
                    int pos = mt * 16 + lg * 4 + r;
                    if (pos < 25) {
                        float h = fmaxf(cv[r] + bb, 0.f);
                        ushort_t hi = f2bf(h);
                        ushort_t lo = f2bf(h - bf16_to_f(hi));
                        hg[pos * 256 + d] = (unsigned int)hi | ((unsigned int)lo << 16);
                        float sq = h * h;
                        sq += __shfl_xor(sq, 1);
                        sq += __shfl_xor(sq, 2);
                        sq += __shfl_xor(sq, 4);
                        sq += __shfl_xor(sq, 8);
                        if (lr == 0) atomicAdd(&x2s[pos], sq);
                    }
                }
            }
        }
    }
    __syncthreads();
    if (t < 32) x2g[(size_t)b * 32 + t] = x2s[t];
}

// ---------------- E2: MFMA distances + softmax (2 img/block, B-prefetch pipelined) --------
__global__ __launch_bounds__(1024) void k_enc2(
    const unsigned int* __restrict__ h3gP,   // [4096][25][256] u32
    const float* __restrict__ x2g,           // [4096][32]
    const ushort_t* __restrict__ pfragHi, const ushort_t* __restrict__ pfragLo,
    const float* __restrict__ p2,
    float* __restrict__ md_out,
    ushort_t* __restrict__ Wsm)
{
    int t = threadIdx.x;
    int b0 = blockIdx.x * 2;
    int w = t >> 6, l = t & 63, lr = l & 15, lg = l >> 4;

    __shared__ __align__(16) ushort_t h3s[2][2][32][264];   // 67584 B
    __shared__ float mds[2][512];
    __shared__ float x2sh[2][32];
    __shared__ float wred[2][16];

    for (int i = t; i < 4096; i += 1024) {
        int im = i >> 11, pos = (i >> 6) & 31, c4 = i & 63;
        us4 hi = {0, 0, 0, 0}, lo = {0, 0, 0, 0};
        if (pos < 25) {
            uint4 v = *(const uint4*)&h3gP[(size_t)(b0 + im) * 6400 + pos * 256 + c4 * 4];
            hi = (us4){(ushort_t)v.x, (ushort_t)v.y, (ushort_t)v.z, (ushort_t)v.w};
            lo = (us4){(ushort_t)(v.x >> 16), (ushort_t)(v.y >> 16),
                       (ushort_t)(v.z >> 16), (ushort_t)(v.w >> 16)};
        }
        *(us4*)&h3s[im][0][pos][c4 * 4] = hi;
        *(us4*)&h3s[im][1][pos][c4 * 4] = lo;
    }
    if (t < 64) x2sh[t >> 5][t & 31] = x2g[(size_t)(b0 + (t >> 5)) * 32 + (t & 31)];
    __syncthreads();

    {
        const ushort_t* h3hi0 = &h3s[0][0][0][0];
        const ushort_t* h3lo0 = &h3s[0][1][0][0];
        const ushort_t* h3hi1 = &h3s[1][0][0][0];
        const ushort_t* h3lo1 = &h3s[1][1][0][0];
        f32x4 acc[2][2][2];
#pragma unroll
        for (int i = 0; i < 2; i++)
#pragma unroll
            for (int jm = 0; jm < 2; jm++)
#pragma unroll
                for (int mt = 0; mt < 2; mt++) acc[i][jm][mt] = (f32x4){0.f, 0.f, 0.f, 0.f};
        const s8v* BH = (const s8v*)pfragHi;
        const s8v* BL = (const s8v*)pfragLo;
        // software pipeline: prefetch B for k0+1 while doing MFMAs of k0
        s8v bhc[2], blc[2], bhn[2], bln[2];
#pragma unroll
        for (int ntq = 0; ntq < 2; ntq++) {
            int nt = w * 2 + ntq;
            bhc[ntq] = BH[(nt * 8 + 0) * 64 + l];
            blc[ntq] = BL[(nt * 8 + 0) * 64 + l];
        }
        for (int k0 = 0; k0 < 8; k0++) {
            if (k0 < 7) {
#pragma unroll
                for (int ntq = 0; ntq < 2; ntq++) {
                    int nt = w * 2 + ntq;
                    bhn[ntq] = BH[(nt * 8 + k0 + 1) * 64 + l];
                    bln[ntq] = BL[(nt * 8 + k0 + 1) * 64 + l];
                }
            }
            s8v ah[2][2], al[2][2];
            ah[0][0] = *(const s8v*)&h3hi0[lr * 264 + k0 * 32 + lg * 8];
            ah[0][1] = *(const s8v*)&h3hi0[(16 + lr) * 264 + k0 * 32 + lg * 8];
            al[0][0] = *(const s8v*)&h3lo0[lr * 264 + k0 * 32 + lg * 8];
            al[0][1] = *(const s8v*)&h3lo0[(16 + lr) * 264 + k0 * 32 + lg * 8];
            ah[1][0] = *(const s8v*)&h3hi1[lr * 264 + k0 * 32 + lg * 8];
            ah[1][1] = *(const s8v*)&h3hi1[(16 + lr) * 264 + k0 * 32 + lg * 8];
            al[1][0] = *(const s8v*)&h3lo1[lr * 264 + k0 * 32 + lg * 8];
            al[1][1] = *(const s8v*)&h3lo1[(16 + lr) * 264 + k0 * 32 + lg * 8];
#pragma unroll
            for (int ntq = 0; ntq < 2; ntq++) {
                s8v bh = bhc[ntq];
                s8v bl = blc[ntq];
#pragma unroll
                for (int im = 0; im < 2; im++) {
                    acc[ntq][im][0] = __builtin_amdgcn_mfma_f32_16x16x32_bf16(ah[im][0], bh, acc[ntq][im][0], 0, 0, 0);
                    acc[ntq][im][1] = __builtin_amdgcn_mfma_f32_16x16x32_bf16(ah[im][1], bh, acc[ntq][im][1], 0, 0, 0);
                    acc[ntq][im][0] = __builtin_amdgcn_mfma_f32_16x16x32_bf16(al[im][0], bh, acc[ntq][im][0], 0, 0, 0);
                    acc[ntq][im][1] = __builtin_amdgcn_mfma_f32_16x16x32_bf16(al[im][1], bh, acc[ntq][im][1], 0, 0, 0);
                    acc[ntq][im][0] = __builtin_amdgcn_mfma_f32_16x16x32_bf16(ah[im][0], bl, acc[ntq][im][0], 0, 0, 0);
                    acc[ntq][im][1] = __builtin_amdgcn_mfma_f32_16x16x32_bf16(ah[im][1], bl, acc[ntq][im][1], 0, 0, 0);
                }
            }
#pragma unroll
            for (int ntq = 0; ntq < 2; ntq++) {
                bhc[ntq] = bhn[ntq];
                blc[ntq] = bln[ntq];
            }
        }
        float x2r[2][8];
#pragma unroll
        for (int im = 0; im < 2; im++)
#pragma unroll
            for (int r = 0; r < 4; r++) {
                x2r[im][r]     = x2sh[im][lg * 4 + r];
                x2r[im][4 + r] = x2sh[im][16 + lg * 4 + r];
            }
#pragma unroll
        for (int ntq = 0; ntq < 2; ntq++) {
            int pcol = (w * 2 + ntq) * 16 + lr;
            float p2v = p2[pcol];
#pragma unroll
            for (int im = 0; im < 2; im++) {
                float mm = 1e30f;
#pragma unroll
                for (int r = 0; r < 4; r++) {
                    float d0 = fmaxf(x2r[im][r]     - 2.f * acc[ntq][im][0][r] + p2v, 0.f);
                    float d1 = fmaxf(x2r[im][4 + r] - 2.f * acc[ntq][im][1][r] + p2v, 0.f);
                    mm = fminf(mm, fminf(d0, d1));
                }
                mm = fminf(mm, __shfl_xor(mm, 16));
                mm = fminf(mm, __shfl_xor(mm, 32));
                if (lg == 0) mds[im][pcol] = mm;
            }
        }
    }
    __syncthreads();

    int img = t >> 9, tt = t & 511;
    float mind = mds[img][tt];
    md_out[(size_t)(b0 + img) * PC + tt] = mind;
    float a = -mind;
    float mx = a;
#pragma unroll
    for (int off = 1; off < 64; off <<= 1) mx = fmaxf(mx, __shfl_xor(mx, off));
    int wv = w & 7;
    if (l == 0) wred[img][wv] = mx;
    __syncthreads();
    float m = wred[img][0];
#pragma unroll
    for (int i = 1; i < 8; i++) m = fmaxf(m, wred[img][i]);
    float e = expf(a - m);
    float sm = e;
#pragma unroll
    for (int off = 1; off < 64; off <<= 1) sm += __shfl_xor(sm, off);
    if (l == 0) wred[img][8 + wv] = sm;
    __syncthreads();
    float ssum = wred[img][8];
#pragma unroll
    for (int i = 9; i < 16; i++) ssum += wred[img][i];
    Wsm[(size_t)(b0 + img) * PC + tt] = f2bf(e / ssum);
}

// ---------------- K2: zupT = Wsm x PW (bf16 MFMA, 2-slab staging), bias+bn+relu ----------
__global__ __launch_bounds__(512) void k_zup2(
    const ushort_t* __restrict__ Wsm,      // [4096][512]
    const ushort_t* __restrict__ PWfrag,   // [400][16][64][8]
    const float* __restrict__ bup, const float* __restrict__ gup,
    const float* __restrict__ btup,
    ushort_t* __restrict__ zupT)           // [4096][6400]
{
    __shared__ __align__(16) ushort_t Bsh[2][8192];
    int t = threadIdx.x;
    int w = t >> 6, l = t & 63;
    int n0 = blockIdx.x * 128;             // 50
    int m0 = blockIdx.y * 128;             // 32
    int row = m0 + w * 16 + (l & 15);
    int krow = (l >> 4) * 8;
    f32x4 acc[8];
#pragma unroll
    for (int i = 0; i < 8; i++) acc[i] = (f32x4){0.f, 0.f, 0.f, 0.f};
    const s8v* B = (const s8v*)PWfrag;
    int base = blockIdx.x * 8 * 16;

    {
        s8v v0 = B[(size_t)(base + (t >> 6) * 16 + 0) * 64 + (t & 63)];
        s8v v1 = B[(size_t)(base + (t >> 6) * 16 + 1) * 64 + (t & 63)];
        *(s8v*)&Bsh[0][t * 8] = v0;
        *(s8v*)&Bsh[0][4096 + t * 8] = v1;
    }
    __syncthreads();
    for (int r = 0; r < 8; r++) {
        int cur = r & 1;
        if (r < 7) {
            s8v v0 = B[(size_t)(base + (t >> 6) * 16 + 2 * r + 2) * 64 + (t & 63)];
            s8v v1 = B[(size_t)(base + (t >> 6) * 16 + 2 * r + 3) * 64 + (t & 63)];
            *(s8v*)&Bsh[cur ^ 1][t * 8] = v0;
            *(s8v*)&Bsh[cur ^ 1][4096 + t * 8] = v1;
        }
#pragma unroll
        for (int kk = 0; kk < 2; kk++) {
            int k0 = 2 * r + kk;
            s8v a = *(const s8v*)&Wsm[(size_t)row * 512 + k0 * 32 + krow];
#pragma unroll
            for (int nt = 0; nt < 8; nt++) {
                s8v bb = *(const s8v*)&Bsh[cur][kk * 4096 + (nt * 64 + l) * 8];
                acc[nt] = __builtin_amdgcn_mfma_f32_16x16x32_bf16(a, bb, acc[nt], 0, 0, 0);
            }
        }
        __syncthreads();
    }

    const float bnr = rsqrtf(1.0f + 1e-5f);
    int rowbase = m0 + w * 16 + (l >> 4) * 4;
#pragma unroll
    for (int nt = 0; nt < 8; nt++) {
        int n = n0 + nt * 16 + (l & 15);
        int ch = n & 255;
        float sc = gup[ch] * bnr, bb = bup[ch], bt = btup[ch];
#pragma unroll
        for (int r = 0; r < 4; r++) {
            float v = (acc[nt][r] + bb) * sc + bt;
            zupT[(size_t)(rowbase + r) * 6400 + n] = f2bf(fmaxf(v, 0.f));
        }
    }
}

// ---------------- K3: fused decoder, 2 img/block, class-per-wave (uniform branches) -------
__global__ __launch_bounds__(512) void k_dtail(
    const ushort_t* __restrict__ zupT,     // [4096][6400]
    const ushort_t* __restrict__ wd1frag,  // [9][8][64][8]
    const float* __restrict__ bd1, const float* __restrict__ gd1, const float* __restrict__ btd1,
    const float* __restrict__ wd2, const float* __restrict__ bd2,
    const float* __restrict__ gd2, const float* __restrict__ btd2,
    const float* __restrict__ wd3, const float* __restrict__ bd3,
    float* __restrict__ out0)
{
    int b0 = blockIdx.x * 2, t = threadIdx.x;
    int w = t >> 6, l = t & 63, lr = l & 15, lg = l >> 4;
    int g = w >> 2, wv = w & 3, tg = t & 255;
    __shared__ __align__(16) unsigned char dbuf[33792];
    __shared__ float hd1p[2][16][64];
    __shared__ float w2sT[9 * 8 * 16];
    __shared__ float w3sT[9 * 8];
    ushort_t* zAb = (ushort_t*)dbuf;
    float* Psb = (float*)dbuf;

    const float bnr = rsqrtf(1.0f + 1e-5f);

    for (int c = t; c < 1600; c += 512) {
        int im = c / 800, cc = c % 800;
        *(us8*)&zAb[im * 8448 + (cc >> 5) * 264 + (cc & 31) * 8] =
            *(const us8*)&zupT[(size_t)(b0 + im) * 6400 + cc * 8];
    }
    for (int i = t; i < 2048; i += 512) ((float*)hd1p)[i] = 0.f;
    for (int i = t; i < 1152; i += 512) {
        int s = i >> 7, rest = i & 127;
        int co = rest >> 4, ci = rest & 15;
        w2sT[i] = wd2[(ci * 8 + co) * 9 + s];
    }
    if (t < 72) {
        int s = t >> 3, ci = t & 7;
        w3sT[t] = wd3[ci * 9 + s];
    }
    __syncthreads();

    {
        f32x4 acc[3][2];
#pragma unroll
        for (int i = 0; i < 3; i++)
#pragma unroll
            for (int mt = 0; mt < 2; mt++) acc[i][mt] = (f32x4){0.f, 0.f, 0.f, 0.f};
        const s8v* B = (const s8v*)wd1frag;
        for (int k0 = 0; k0 < 8; k0++) {
            s8v a0 = *(const s8v*)&zAb[g * 8448 + lr * 264 + k0 * 32 + lg * 8];
            s8v a1 = *(const s8v*)&zAb[g * 8448 + (16 + lr) * 264 + k0 * 32 + lg * 8];
#pragma unroll
            for (int i = 0; i < 3; i++) {
                int nt = wv + 4 * i;
                if (nt < 9) {
                    s8v bb = B[(nt * 8 + k0) * 64 + l];
                    acc[i][0] = __builtin_amdgcn_mfma_f32_16x16x32_bf16(a0, bb, acc[i][0], 0, 0, 0);
                    acc[i][1] = __builtin_amdgcn_mfma_f32_16x16x32_bf16(a1, bb, acc[i][1], 0, 0, 0);
                }
            }
        }
        __syncthreads();
#pragma unroll
        for (int i = 0; i < 3; i++) {
            int nt = wv + 4 * i;
            if (nt < 9) {
                int col = nt * 16 + lr;
#pragma unroll
                for (int mt = 0; mt < 2; mt++)
#pragma unroll
                    for (int r = 0; r < 4; r++) {
                        int pos = mt * 16 + lg * 4 + r;
                        if (pos < 25) Psb[g * 3700 + pos * 148 + col] = acc[i][mt][r];
                    }
            }
        }
    }
    __syncthreads();

    for (int o = tg; o < 784; o += 256) {
        int co = o / 49, rr = o % 49, y = rr / 7, xx = rr % 7;
        float a = bd1[co];
        int sy0 = y - 4 > 0 ? y - 4 : 0, sy1 = y < 2 ? y : 2;
        for (int sy = sy0; sy <= sy1; sy++) {
            int iy = y - sy;
            int sx0 = xx - 4 > 0 ? xx - 4 : 0, sx1 = xx < 2 ? xx : 2;
            for (int sx = sx0; sx <= sx1; sx++) {
                int ix = xx - sx;
                a += Psb[g * 3700 + (iy * 5 + ix) * 148 + co * 9 + sy * 3 + sx];
            }
        }
        float v = a * (gd1[co] * bnr) + btd1[co];
        hd1p[g][co][y * 8 + xx] = fmaxf(v, 0.f);
    }
    __syncthreads();

    {
        if (t < 464) {
            int im = t / 232, rest = t % 232;
            int co = rest / 29, s = rest % 29;
            int yy = (s < 15) ? 14 : (s - 15);
            int xx2 = (s < 15) ? s : 14;
            ((float*)dbuf)[im * 1808 + co * 225 + yy * 15 + xx2] = 0.f;
        }
        int cls = (wv + g) & 3;
        int cy = cls >> 1, cx = cls & 1;
        if (l < 56 && (l & 7) < 7) {
            int r = l >> 3, c = l & 7;
            float acc[8];
#pragma unroll
            for (int co = 0; co < 8; co++) acc[co] = 0.f;
            const float* hb = &hd1p[g][0][0];
            int niy = 1 + cy, nix = 1 + cx;
            for (int ty = 0; ty < niy; ty++) {
                int iy = r + ty;
                int sy = cy ? (ty ? 0 : 2) : 1;
                for (int tx = 0; tx < nix; tx++) {
                    int ix = c + tx;
                    int sx = cx ? (tx ? 0 : 2) : 1;
                    const float* wp = &w2sT[(sy * 3 + sx) * 128];
                    int hoff = iy * 8 + ix;
                    float h[16];
#pragma unroll
                    for (int ci = 0; ci < 16; ci++) h[ci] = hb[ci * 64 + hoff];
#pragma unroll
                    for (int co = 0; co < 8; co++) {
                        const float4* wp4 = (const float4*)&wp[co * 16];
                        float4 wa = wp4[0], wb4 = wp4[1], wc4 = wp4[2], wd4 = wp4[3];
                        float a = acc[co];
                        a = fmaf(h[0], wa.x, a);  a = fmaf(h[1], wa.y, a);
                        a = fmaf(h[2], wa.z, a);  a = fmaf(h[3], wa.w, a);
                        a = fmaf(h[4], wb4.x, a); a = fmaf(h[5], wb4.y, a);
                        a = fmaf(h[6], wb4.z, a); a = fmaf(h[7], wb4.w, a);
                        a = fmaf(h[8], wc4.x, a); a = fmaf(h[9], wc4.y, a);
                        a = fmaf(h[10], wc4.z, a); a = fmaf(h[11], wc4.w, a);
                        a = fmaf(h[12], wd4.x, a); a = fmaf(h[13], wd4.y, a);
                        a = fmaf(h[14], wd4.z, a); a = fmaf(h[15], wd4.w, a);
                        acc[co] = a;
                    }
                }
            }
            int y = 2 * r + cy, x = 2 * c + cx;
            float* hout = (float*)dbuf + g * 1808;
#pragma unroll
            for (int co = 0; co < 8; co++) {
                float v = (acc[co] + bd2[co]) * (gd2[co] * bnr) + btd2[co];
                hout[co * 225 + y * 15 + x] = fmaxf(v, 0.f);
            }
        }
    }
    __syncthreads();

    {
        int cls = (wv + g) & 3;
        int cy = cls >> 1, cx = cls & 1;
        const float* h2b = (const float*)dbuf + g * 1808;
        float* og = out0 + (size_t)(b0 + g) * 784;
        int niy = 1 + cy, nix = 1 + cx;
#pragma unroll
        for (int j = 0; j < 4; j++) {
            int idx = l + 64 * j;
            if (idx < 224) {
                int row = idx >> 4, col = idx & 15;
                if (col < 14) {
                    float a = bd3[0];
                    for (int ty = 0; ty < niy; ty++) {
                        int iy = row + ty;
                        int sy = cy ? (ty ? 0 : 2) : 1;
                        for (int tx = 0; tx < nix; tx++) {
                            int ix = col + tx;
                            int sx = cx ? (tx ? 0 : 2) : 1;
                            const float* wp = &w3sT[(sy * 3 + sx) * 8];
                            int hoff = iy * 15 + ix;
#pragma unroll
                            for (int ci = 0; ci < 8; ci++)
                                a = fmaf(h2b[ci * 225 + hoff], wp[ci], a);
                        }
                    }
                    int y = 2 * row + cy, x = 2 * col + cx;
                    og[y * 28 + x] = 1.f / (1.f + expf(-a));
                }
            }
        }
    }
}

extern "C" void kernel_launch(void* const* d_in, const int* in_sizes, int n_in,
                              void* d_out, int out_size, void* d_ws, size_t ws_size,
                              hipStream_t stream) {
    const float* x    = (const float*)d_in[0];
    const float* w1   = (const float*)d_in[1];
    const float* b1   = (const float*)d_in[2];
    const float* w2   = (const float*)d_in[3];
    const float* b2   = (const float*)d_in[4];
    const float* g2   = (const float*)d_in[5];
    const float* bt2  = (const float*)d_in[6];
    const float* w3   = (const float*)d_in[7];
    const float* b3   = (const float*)d_in[8];
    const float* proto= (const float*)d_in[9];
    const float* wup  = (const float*)d_in[10];
    const float* bup  = (const float*)d_in[11];
    const float* gup  = (const float*)d_in[12];
    const float* btup = (const float*)d_in[13];
    const float* wd1  = (const float*)d_in[14];
    const float* bd1  = (const float*)d_in[15];
    const float* gd1  = (const float*)d_in[16];
    const float* btd1 = (const float*)d_in[17];
    const float* wd2  = (const float*)d_in[18];
    const float* bd2  = (const float*)d_in[19];
    const float* gd2  = (const float*)d_in[20];
    const float* btd2 = (const float*)d_in[21];
    const float* wd3  = (const float*)d_in[22];
    const float* bd3  = (const float*)d_in[23];

    float* out0   = (float*)d_out;                 // [4096][784]
    float* out_md = out0 + (size_t)NB * 784;       // [4096][512]

    // ws layout
    float*    p2      = (float*)d_ws;                          // 512 f
    float*    x2g     = p2 + 512;                              // 131072 f
    ushort_t* pfragHi = (ushort_t*)(x2g + 131072);             // 131072
    ushort_t* pfragLo = pfragHi + 131072;                      // 131072
    ushort_t* w3fH    = pfragLo + 131072;                      // 40960
    ushort_t* w3fL    = w3fH + 40960;                          // 40960
    ushort_t* w2fH    = w3fL + 40960;                          // 1536
    ushort_t* w2fL    = w2fH + 1536;                           // 1536
    ushort_t* wd1frag = w2fL + 1536;                           // 36864
    ushort_t* wupfH   = wd1frag + 36864;                       // 1638400
    ushort_t* wupfL   = wupfH + 1638400;                       // 1638400
    ushort_t* PWfrag  = wupfL + 1638400;                       // 3276800
    ushort_t* Wsm     = PWfrag + 3276800;                      // 2097152
    ushort_t* BIG     = Wsm + 2097152;                         // 104.8 MB region
    unsigned int* h3gP = (unsigned int*)BIG;                   // [4096][25][256] u32
    ushort_t* zupT    = BIG;                                   // [4096][6400] (aliases dead h3gP)

    hipLaunchKernelGGL(k_pre, dim3(7734), dim3(256), 0, stream,
                       proto, p2, pfragHi, pfragLo, w3, w3fH, w3fL,
                       w2, w2fH, w2fL, wd1, wd1frag, wup, wupfH, wupfL);
    hipLaunchKernelGGL(k_pw2, dim3(25, 32), dim3(256), 0, stream,
                       pfragHi, pfragLo, wupfH, wupfL, PWfrag);
    hipLaunchKernelGGL(k_enc1, dim3(NB), dim3(512), 0, stream,
                       x, w1, b1, w2fH, w2fL, b2, g2, bt2, w3fH, w3fL, b3, h3gP, x2g);
    hipLaunchKernelGGL(k_enc2, dim3(NB / 2), dim3(1024), 0, stream,
                       h3gP, x2g, pfragHi, pfragLo, p2, out_md, Wsm);
    hipLaunchKernelGGL(k_zup2, dim3(50, 32), dim3(512), 0, stream,
                       Wsm, PWfrag, bup, gup, btup, zupT);
    hipLaunchKernelGGL(k_dtail, dim3(NB / 2), dim3(512), 0, stream,
                       zupT, wd1frag, bd1, gd1, btd1, wd2, bd2, gd2, btd2, wd3, bd3, out0);
}

// Round 15
// 291.970 us; speedup vs baseline: 1.4693x; 1.0767x over previous
//
#include <hip/hip_runtime.h>
#include <hip/hip_bf16.h>
#include <math.h>

#define NB 4096
#define DC 256
#define PC 512

typedef unsigned short ushort_t;
typedef __attribute__((ext_vector_type(4))) unsigned short us4;
typedef __attribute__((ext_vector_type(8))) unsigned short us8;
typedef __attribute__((ext_vector_type(8))) short s8v;       // bf16x8 for MFMA
typedef __attribute__((ext_vector_type(4))) float f32x4;

__device__ __forceinline__ float bf16_to_f(ushort_t u) {
    union { unsigned int i; float f; } c;
    c.i = ((unsigned int)u) << 16;
    return c.f;
}
__device__ __forceinline__ ushort_t f2bf(float f) {          // RNE
    union { float f; unsigned int u; } c; c.f = f;
    unsigned int r = c.u + 0x7fffu + ((c.u >> 16) & 1u);
    return (ushort_t)(r >> 16);
}

// ---------------- K_pre: all small packing kernels merged (blockIdx-range dispatch) -------
__global__ __launch_bounds__(256) void k_pre(
    const float* __restrict__ proto, float* __restrict__ p2,
    ushort_t* __restrict__ pfragHi, ushort_t* __restrict__ pfragLo,
    const float* __restrict__ w3, ushort_t* __restrict__ w3fH, ushort_t* __restrict__ w3fL,
    const float* __restrict__ w2, ushort_t* __restrict__ w2fH, ushort_t* __restrict__ w2fL,
    const float* __restrict__ wd1, ushort_t* __restrict__ wd1frag,
    const float* __restrict__ wup, ushort_t* __restrict__ wupfH, ushort_t* __restrict__ wupfL)
{
    int b = blockIdx.x, tid = threadIdx.x;
    __shared__ float red[256];
    if (b < 512) {
        int p = b, d = tid;
        float v = proto[p * DC + d];
        red[d] = v * v;
        __syncthreads();
        for (int s = 128; s > 0; s >>= 1) {
            if (d < s) red[d] += red[d + s];
            __syncthreads();
        }
        if (d == 0) p2[p] = red[0];
    } else if (b < 1024) {
        int idx = (b - 512) * 256 + tid;
        int j = idx & 7, l = (idx >> 3) & 63;
        int k0 = (idx >> 9) & 7, nt = idx >> 12;
        int n = nt * 16 + (l & 15);
        int k = k0 * 32 + (l >> 4) * 8 + j;
        float v = proto[n * DC + k];
        ushort_t hi = f2bf(v);
        pfragHi[idx] = hi;
        pfragLo[idx] = f2bf(v - bf16_to_f(hi));
    } else if (b < 1184) {
        int idx = (b - 1024) * 256 + tid;
        int j = idx & 7, l = (idx >> 3) & 63;
        int q = idx >> 9;
        int k0 = q % 5, nt = q / 5;
        int d = nt * 16 + (l & 15);
        int k = k0 * 32 + (l >> 4) * 8 + j;
        float v = (k < 144) ? w3[d * 144 + k] : 0.f;
        ushort_t hi = f2bf(v);
        w3fH[idx] = hi;
        w3fL[idx] = f2bf(v - bf16_to_f(hi));
    } else if (b < 1190) {
        int idx = (b - 1184) * 256 + tid;
        int j = idx & 7, l = (idx >> 3) & 63;
        int k0 = idx >> 9;
        int ch = l & 15;
        int k = k0 * 32 + (l >> 4) * 8 + j;
        float v = (k < 72) ? w2[ch * 72 + k] : 0.f;
        ushort_t hi = f2bf(v);
        w2fH[idx] = hi;
        w2fL[idx] = f2bf(v - bf16_to_f(hi));
    } else if (b < 1334) {
        int idx = (b - 1190) * 256 + tid;
        int j = idx & 7, l = (idx >> 3) & 63;
        int k0 = (idx >> 9) & 7, nt = idx >> 12;
        int n = nt * 16 + (l & 15);
        int k = k0 * 32 + (l >> 4) * 8 + j;
        wd1frag[idx] = f2bf(wd1[k * 144 + n]);
    } else {
        int idx = (b - 1334) * 256 + tid;
        int j = idx & 7, l = (idx >> 3) & 63;
        int k0 = (idx >> 9) & 7, nt = idx >> 12;
        int np = nt * 16 + (l & 15);
        int d = k0 * 32 + (l >> 4) * 8 + j;
        int pos = np >> 8, ch = np & 255;
        float v = wup[d * 6400 + ch * 25 + pos];
        ushort_t hi = f2bf(v);
        wupfH[idx] = hi;
        wupfL[idx] = f2bf(v - bf16_to_f(hi));
    }
}

// ---------------- K0f: PW = proto x wupT via MFMA (hi/lo), -> PWfrag [400][16][64][8] -----
__global__ __launch_bounds__(256) void k_pw2(
    const ushort_t* __restrict__ pfragHi, const ushort_t* __restrict__ pfragLo,
    const ushort_t* __restrict__ wupfH, const ushort_t* __restrict__ wupfL,
    ushort_t* __restrict__ PWfrag)
{
    int t = threadIdx.x;
    int w = t >> 6, l = t & 63, lr = l & 15, lg = l >> 4;
    int my = blockIdx.y;
    int ntb = blockIdx.x * 16 + w * 4;
    const s8v* AH = (const s8v*)pfragHi;
    const s8v* AL = (const s8v*)pfragLo;
    const s8v* BH = (const s8v*)wupfH;
    const s8v* BL = (const s8v*)wupfL;
    f32x4 acc[4];
#pragma unroll
    for (int q = 0; q < 4; q++) acc[q] = (f32x4){0.f, 0.f, 0.f, 0.f};
#pragma unroll
    for (int k0 = 0; k0 < 8; k0++) {
        s8v ah = AH[(my * 8 + k0) * 64 + l];
        s8v al = AL[(my * 8 + k0) * 64 + l];
#pragma unroll
        for (int q = 0; q < 4; q++) {
            s8v bh = BH[(size_t)((ntb + q) * 8 + k0) * 64 + l];
            s8v bl = BL[(size_t)((ntb + q) * 8 + k0) * 64 + l];
            acc[q] = __builtin_amdgcn_mfma_f32_16x16x32_bf16(ah, bh, acc[q], 0, 0, 0);
            acc[q] = __builtin_amdgcn_mfma_f32_16x16x32_bf16(al, bh, acc[q], 0, 0, 0);
            acc[q] = __builtin_amdgcn_mfma_f32_16x16x32_bf16(ah, bl, acc[q], 0, 0, 0);
        }
    }
#pragma unroll
    for (int q = 0; q < 4; q++) {
        int nt = ntb + q;
#pragma unroll
        for (int r = 0; r < 4; r++) {
            int p = my * 16 + lg * 4 + r;
            int k0p = p >> 5;
            int ll = ((p >> 3) & 3) * 16 + lr;
            int jj = p & 7;
            PWfrag[(((size_t)(nt * 16 + k0p) * 64) + ll) * 8 + jj] = f2bf(acc[q][r]);
        }
    }
}

// ---------------- E1: conv1(+scatter im2col2) + conv2 MFMA (+scatter im2col3) + conv3 -----
__global__ __launch_bounds__(512) void k_enc1(
    const float* __restrict__ x,
    const float* __restrict__ w1, const float* __restrict__ b1,
    const ushort_t* __restrict__ w2fH, const ushort_t* __restrict__ w2fL,
    const float* __restrict__ b2,
    const float* __restrict__ g2, const float* __restrict__ bt2,
    const ushort_t* __restrict__ w3fH, const ushort_t* __restrict__ w3fL,
    const float* __restrict__ b3,
    ushort_t* __restrict__ h3g,        // [4096][25][256] bf16 (hi only)
    float* __restrict__ x2g)           // [4096][32]
{
    int b = blockIdx.x;
    int t = threadIdx.x;
    int w = t >> 6, l = t & 63, lr = l & 15, lg = l >> 4;

    __shared__ __align__(16) unsigned char buf[39168];
    __shared__ float x2s[32];
    float* xb = (float*)buf;
    ushort_t* im2Hi = (ushort_t*)(buf + 9408);
    ushort_t* im2Lo = (ushort_t*)(buf + 22720);
    float* h2 = (float*)(buf + 36032);
    ushort_t* imHi = (ushort_t*)buf;
    ushort_t* imLo = (ushort_t*)(buf + 9248);

    const float bnr = rsqrtf(1.0f + 1e-5f);

    const float* xg = x + (size_t)b * 784;
    for (int i = t; i < 784; i += 512) xb[i] = xg[i];
    for (int i = t; i < 1664; i += 512)
        ((float4*)(buf + 9408))[i] = (float4){0.f, 0.f, 0.f, 0.f};
    if (t < 32) x2s[t] = (t < 25) ? 0.f : 1e30f;
    __syncthreads();

    // phase 1: conv1 + scatter into im2col2
    for (int o = t; o < 1568; o += 512) {
        int c = o / 196, r = o % 196, y = r / 14, xc = r % 14;
        float acc = b1[c];
        for (int sy = 0; sy < 3; sy++) {
            int iy = 2 * y - 1 + sy;
            if ((unsigned)iy >= 28u) continue;
            for (int sx = 0; sx < 3; sx++) {
                int ix = 2 * xc - 1 + sx;
                if ((unsigned)ix >= 28u) continue;
                acc += w1[c * 9 + sy * 3 + sx] * xb[iy * 28 + ix];
            }
        }
        float v = fmaxf(acc, 0.f);
        ushort_t hi = f2bf(v), lo = f2bf(v - bf16_to_f(hi));
        int kb = c * 9;
        int yA, syA, xA, sxA, yB = 0, xB = 0;
        bool hasYB, hasXB;
        if (y & 1) { yA = y >> 1; syA = 2; yB = yA + 1; hasYB = (yB < 7); }
        else       { yA = y >> 1; syA = 1; hasYB = false; }
        if (xc & 1) { xA = xc >> 1; sxA = 2; xB = xA + 1; hasXB = (xB < 7); }
        else        { xA = xc >> 1; sxA = 1; hasXB = false; }
        int i0 = (yA * 7 + xA) * 104 + kb + syA * 3 + sxA;
        im2Hi[i0] = hi; im2Lo[i0] = lo;
        if (hasXB) {
            int i1 = (yA * 7 + xB) * 104 + kb + syA * 3;
            im2Hi[i1] = hi; im2Lo[i1] = lo;
        }
        if (hasYB) {
            int i2 = (yB * 7 + xA) * 104 + kb + sxA;
            im2Hi[i2] = hi; im2Lo[i2] = lo;
            if (hasXB) {
                int i3 = (yB * 7 + xB) * 104 + kb;
                im2Hi[i3] = hi; im2Lo[i3] = lo;
            }
        }
    }
    __syncthreads();

    // phase 2: conv2 as MFMA (waves 0-3)
    if (w < 4) {
        f32x4 cc = {0, 0, 0, 0};
        const s8v* WH = (const s8v*)w2fH;
        const s8v* WL = (const s8v*)w2fL;
#pragma unroll
        for (int k0 = 0; k0 < 3; k0++) {
            s8v a0 = *(const s8v*)&im2Hi[(w * 16 + lr) * 104 + k0 * 32 + lg * 8];
            s8v a1 = *(const s8v*)&im2Lo[(w * 16 + lr) * 104 + k0 * 32 + lg * 8];
            s8v bh = WH[k0 * 64 + l];
            s8v bl = WL[k0 * 64 + l];
            cc = __builtin_amdgcn_mfma_f32_16x16x32_bf16(a0, bh, cc, 0, 0, 0);
            cc = __builtin_amdgcn_mfma_f32_16x16x32_bf16(a1, bh, cc, 0, 0, 0);
            cc = __builtin_amdgcn_mfma_f32_16x16x32_bf16(a0, bl, cc, 0, 0, 0);
        }
        int ch = lr;
        float s = g2[ch] * bnr, bb = b2[ch], bt = bt2[ch];
#pragma unroll
        for (int r = 0; r < 4; r++) {
            int pos = w * 16 + lg * 4 + r;
            if (pos < 49)
                h2[ch * 49 + pos] = fmaxf((cc[r] + bb) * s + bt, 0.f);
        }
    }
    __syncthreads();

    // phase 3: scatter h2 -> im2col3
    if (t < 16) { imHi[3600 + t] = 0; imLo[3600 + t] = 0; }
    for (int o = t; o < 784; o += 512) {
        float v = h2[o];
        int ci = o / 49, rr = o % 49, iy = rr / 7, ixp = rr % 7;
        ushort_t hi = f2bf(v), lo = f2bf(v - bf16_to_f(hi));
        int kb = ci * 9;
#pragma unroll
        for (int sy = 0; sy < 3; sy++) {
            int py = iy - sy;
            if ((unsigned)py < 5u) {
#pragma unroll
                for (int sx = 0; sx < 3; sx++) {
                    int px = ixp - sx;
                    if ((unsigned)px < 5u) {
                        int idx = (py * 5 + px) * 144 + kb + sy * 3 + sx;
                        imHi[idx] = hi; imLo[idx] = lo;
                    }
                }
            }
        }
    }
    __syncthreads();

    // phase 4: conv3 as MFMA, bias+relu; bf16 store + x2 from rounded h
    {
        int nt0 = 2 * w;
        f32x4 c00 = {0,0,0,0}, c01 = {0,0,0,0}, c10 = {0,0,0,0}, c11 = {0,0,0,0};
        const s8v* WH = (const s8v*)w3fH;
        const s8v* WL = (const s8v*)w3fL;
#pragma unroll
        for (int k0 = 0; k0 < 5; k0++) {
            s8v ah0 = *(const s8v*)&imHi[lr * 144 + k0 * 32 + lg * 8];
            s8v ah1 = *(const s8v*)&imHi[(16 + lr) * 144 + k0 * 32 + lg * 8];
            s8v al0 = *(const s8v*)&imLo[lr * 144 + k0 * 32 + lg * 8];
            s8v al1 = *(const s8v*)&imLo[(16 + lr) * 144 + k0 * 32 + lg * 8];
            s8v bh0 = WH[(nt0 * 5 + k0) * 64 + l];
            s8v bl0 = WL[(nt0 * 5 + k0) * 64 + l];
            s8v bh1 = WH[((nt0 + 1) * 5 + k0) * 64 + l];
            s8v bl1 = WL[((nt0 + 1) * 5 + k0) * 64 + l];
            c00 = __builtin_amdgcn_mfma_f32_16x16x32_bf16(ah0, bh0, c00, 0, 0, 0);
            c10 = __builtin_amdgcn_mfma_f32_16x16x32_bf16(ah1, bh0, c10, 0, 0, 0);
            c00 = __builtin_amdgcn_mfma_f32_16x16x32_bf16(al0, bh0, c00, 0, 0, 0);
            c10 = __builtin_amdgcn_mfma_f32_16x16x32_bf16(al1, bh0, c10, 0, 0, 0);
            c00 = __builtin_amdgcn_mfma_f32_16x16x32_bf16(ah0, bl0, c00, 0, 0, 0);
            c10 = __builtin_amdgcn_mfma_f32_16x16x32_bf16(ah1, bl0, c10, 0, 0, 0);
            c01 = __builtin_amdgcn_mfma_f32_16x16x32_bf16(ah0, bh1, c01, 0, 0, 0);
            c11 = __builtin_amdgcn_mfma_f32_16x16x32_bf16(ah1, bh1, c11, 0, 0, 0);
            c01 = __builtin_amdgcn_mfma_f32_16x16x32_bf16(al0, bh1, c01, 0, 0, 0);
            c11 = __builtin_amdgcn_mfma_f32_16x16x32_bf16(al1, bh1, c11, 0, 0, 0);
            c01 = __builtin_amdgcn_mfma_f32_16x16x32_bf16(ah0, bl1, c01, 0, 0, 0);
            c11 = __builtin_amdgcn_mfma_f32_16x16x32_bf16(ah1, bl1, c11, 0, 0, 0);
        }
        ushort_t* hg = h3g + (size_t)b * 6400;
#pragma unroll
        for (int q = 0; q < 2; q++) {
            int d = (nt0 + q) * 16 + lr;
            float bb = b3[d];
            f32x4 cm0 = q ? c01 : c00;
            f32x4 cm1 = q ? c11 : c10;
#pragma unroll
            for (int mt = 0; mt < 2; mt++) {
                f32x4 cv = mt ? cm1 : cm0;
#pragma unroll
                for (int r = 0; r < 4; r++) {
                    int pos = mt * 16 + lg * 4 + r;
                    if (pos < 25) {
                        float h = fmaxf(cv[r] + bb, 0.f);
                        ushort_t hi = f2bf(h);
                        float hh = bf16_to_f(hi);
                        hg[pos * 256 + d] = hi;
                        float sq = hh * hh;
                        sq += __shfl_xor(sq, 1);
                        sq += __shfl_xor(sq, 2);
                        sq += __shfl_xor(sq, 4);
                        sq += __shfl_xor(sq, 8);
                        if (lr == 0) atomicAdd(&x2s[pos], sq);
                    }
                }
            }
        }
    }
    __syncthreads();
    if (t < 32) x2g[(size_t)b * 32 + t] = x2s[t];
}

// ---------------- E2: MFMA distances + softmax (2 img/block, single-bf16 A, 2-term) ------
__global__ __launch_bounds__(1024) void k_enc2(
    const ushort_t* __restrict__ h3g,        // [4096][25][256] bf16
    const float* __restrict__ x2g,           // [4096][32]
    const ushort_t* __restrict__ pfragHi, const ushort_t* __restrict__ pfragLo,
    const float* __restrict__ p2,
    float* __restrict__ md_out,
    ushort_t* __restrict__ Wsm)
{
    int t = threadIdx.x;
    int b0 = blockIdx.x * 2;
    int w = t >> 6, l = t & 63, lr = l & 15, lg = l >> 4;

    __shared__ __align__(16) ushort_t h3s[2][32][264];   // 33792 B
    __shared__ float mds[2][512];
    __shared__ float x2sh[2][32];
    __shared__ float wred[2][16];

    // stage h3 (rows >= 25 zeroed); us8 = 8 d's
    for (int i = t; i < 2048; i += 1024) {
        int im = i >> 10, pos = (i >> 5) & 31, c8 = i & 31;
        us8 v = {0, 0, 0, 0, 0, 0, 0, 0};
        if (pos < 25)
            v = *(const us8*)&h3g[(size_t)(b0 + im) * 6400 + pos * 256 + c8 * 8];
        *(us8*)&h3s[im][pos][c8 * 8] = v;
    }
    if (t < 64) x2sh[t >> 5][t & 31] = x2g[(size_t)(b0 + (t >> 5)) * 32 + (t & 31)];
    __syncthreads();

    {
        f32x4 acc[2][2][2];
#pragma unroll
        for (int i = 0; i < 2; i++)
#pragma unroll
            for (int jm = 0; jm < 2; jm++)
#pragma unroll
                for (int mt = 0; mt < 2; mt++) acc[i][jm][mt] = (f32x4){0.f, 0.f, 0.f, 0.f};
        const s8v* BH = (const s8v*)pfragHi;
        const s8v* BL = (const s8v*)pfragLo;
        // software pipeline: prefetch B for k0+1 while doing MFMAs of k0
        s8v bhc[2], blc[2], bhn[2], bln[2];
#pragma unroll
        for (int ntq = 0; ntq < 2; ntq++) {
            int nt = w * 2 + ntq;
            bhc[ntq] = BH[(nt * 8 + 0) * 64 + l];
            blc[ntq] = BL[(nt * 8 + 0) * 64 + l];
        }
        for (int k0 = 0; k0 < 8; k0++) {
            if (k0 < 7) {
#pragma unroll
                for (int ntq = 0; ntq < 2; ntq++) {
                    int nt = w * 2 + ntq;
                    bhn[ntq] = BH[(nt * 8 + k0 + 1) * 64 + l];
                    bln[ntq] = BL[(nt * 8 + k0 + 1) * 64 + l];
                }
            }
            s8v ah[2][2];
            ah[0][0] = *(const s8v*)&h3s[0][lr][k0 * 32 + lg * 8];
            ah[0][1] = *(const s8v*)&h3s[0][16 + lr][k0 * 32 + lg * 8];
            ah[1][0] = *(const s8v*)&h3s[1][lr][k0 * 32 + lg * 8];
            ah[1][1] = *(const s8v*)&h3s[1][16 + lr][k0 * 32 + lg * 8];
#pragma unroll
            for (int ntq = 0; ntq < 2; ntq++) {
                s8v bh = bhc[ntq];
                s8v bl = blc[ntq];
#pragma unroll
                for (int im = 0; im < 2; im++) {
                    acc[ntq][im][0] = __builtin_amdgcn_mfma_f32_16x16x32_bf16(ah[im][0], bh, acc[ntq][im][0], 0, 0, 0);
                    acc[ntq][im][1] = __builtin_amdgcn_mfma_f32_16x16x32_bf16(ah[im][1], bh, acc[ntq][im][1], 0, 0, 0);
                    acc[ntq][im][0] = __builtin_amdgcn_mfma_f32_16x16x32_bf16(ah[im][0], bl, acc[ntq][im][0], 0, 0, 0);
                    acc[ntq][im][1] = __builtin_amdgcn_mfma_f32_16x16x32_bf16(ah[im][1], bl, acc[ntq][im][1], 0, 0, 0);
                }
            }
#pragma unroll
            for (int ntq = 0; ntq < 2; ntq++) {
                bhc[ntq] = bhn[ntq];
                blc[ntq] = bln[ntq];
            }
        }
        float x2r[2][8];
#pragma unroll
        for (int im = 0; im < 2; im++)
#pragma unroll
            for (int r = 0; r < 4; r++) {
                x2r[im][r]     = x2sh[im][lg * 4 + r];
                x2r[im][4 + r] = x2sh[im][16 + lg * 4 + r];
            }
#pragma unroll
        for (int ntq = 0; ntq < 2; ntq++) {
            int pcol = (w * 2 + ntq) * 16 + lr;
            float p2v = p2[pcol];
#pragma unroll
            for (int im = 0; im < 2; im++) {
                float mm = 1e30f;
#pragma unroll
                for (int r = 0; r < 4; r++) {
                    float d0 = fmaxf(x2r[im][r]     - 2.f * acc[ntq][im][0][r] + p2v, 0.f);
                    float d1 = fmaxf(x2r[im][4 + r] - 2.f * acc[ntq][im][1][r] + p2v, 0.f);
                    mm = fminf(mm, fminf(d0, d1));
                }
                mm = fminf(mm, __shfl_xor(mm, 16));
                mm = fminf(mm, __shfl_xor(mm, 32));
                if (lg == 0) mds[im][pcol] = mm;
            }
        }
    }
    __syncthreads();

    int img = t >> 9, tt = t & 511;
    float mind = mds[img][tt];
    md_out[(size_t)(b0 + img) * PC + tt] = mind;
    float a = -mind;
    float mx = a;
#pragma unroll
    for (int off = 1; off < 64; off <<= 1) mx = fmaxf(mx, __shfl_xor(mx, off));
    int wv = w & 7;
    if (l == 0) wred[img][wv] = mx;
    __syncthreads();
    float m = wred[img][0];
#pragma unroll
    for (int i = 1; i < 8; i++) m = fmaxf(m, wred[img][i]);
    float e = expf(a - m);
    float sm = e;
#pragma unroll
    for (int off = 1; off < 64; off <<= 1) sm += __shfl_xor(sm, off);
    if (l == 0) wred[img][8 + wv] = sm;
    __syncthreads();
    float ssum = wred[img][8];
#pragma unroll
    for (int i = 9; i < 16; i++) ssum += wred[img][i];
    Wsm[(size_t)(b0 + img) * PC + tt] = f2bf(e / ssum);
}

// ---------------- K2: zupT = Wsm x PW (bf16 MFMA, 2-slab staging), bias+bn+relu ----------
__global__ __launch_bounds__(512) void k_zup2(
    const ushort_t* __restrict__ Wsm,      // [4096][512]
    const ushort_t* __restrict__ PWfrag,   // [400][16][64][8]
    const float* __restrict__ bup, const float* __restrict__ gup,
    const float* __restrict__ btup,
    ushort_t* __restrict__ zupT)           // [4096][6400]
{
    __shared__ __align__(16) ushort_t Bsh[2][8192];
    int t = threadIdx.x;
    int w = t >> 6, l = t & 63;
    int n0 = blockIdx.x * 128;             // 50
    int m0 = blockIdx.y * 128;             // 32
    int row = m0 + w * 16 + (l & 15);
    int krow = (l >> 4) * 8;
    f32x4 acc[8];
#pragma unroll
    for (int i = 0; i < 8; i++) acc[i] = (f32x4){0.f, 0.f, 0.f, 0.f};
    const s8v* B = (const s8v*)PWfrag;
    int base = blockIdx.x * 8 * 16;

    {
        s8v v0 = B[(size_t)(base + (t >> 6) * 16 + 0) * 64 + (t & 63)];
        s8v v1 = B[(size_t)(base + (t >> 6) * 16 + 1) * 64 + (t & 63)];
        *(s8v*)&Bsh[0][t * 8] = v0;
        *(s8v*)&Bsh[0][4096 + t * 8] = v1;
    }
    __syncthreads();
    for (int r = 0; r < 8; r++) {
        int cur = r & 1;
        if (r < 7) {
            s8v v0 = B[(size_t)(base + (t >> 6) * 16 + 2 * r + 2) * 64 + (t & 63)];
            s8v v1 = B[(size_t)(base + (t >> 6) * 16 + 2 * r + 3) * 64 + (t & 63)];
            *(s8v*)&Bsh[cur ^ 1][t * 8] = v0;
            *(s8v*)&Bsh[cur ^ 1][4096 + t * 8] = v1;
        }
#pragma unroll
        for (int kk = 0; kk < 2; kk++) {
            int k0 = 2 * r + kk;
            s8v a = *(const s8v*)&Wsm[(size_t)row * 512 + k0 * 32 + krow];
#pragma unroll
            for (int nt = 0; nt < 8; nt++) {
                s8v bb = *(const s8v*)&Bsh[cur][kk * 4096 + (nt * 64 + l) * 8];
                acc[nt] = __builtin_amdgcn_mfma_f32_16x16x32_bf16(a, bb, acc[nt], 0, 0, 0);
            }
        }
        __syncthreads();
    }

    const float bnr = rsqrtf(1.0f + 1e-5f);
    int rowbase = m0 + w * 16 + (l >> 4) * 4;
#pragma unroll
    for (int nt = 0; nt < 8; nt++) {
        int n = n0 + nt * 16 + (l & 15);
        int ch = n & 255;
        float sc = gup[ch] * bnr, bb = bup[ch], bt = btup[ch];
#pragma unroll
        for (int r = 0; r < 4; r++) {
            float v = (acc[nt][r] + bb) * sc + bt;
            zupT[(size_t)(rowbase + r) * 6400 + n] = f2bf(fmaxf(v, 0.f));
        }
    }
}

// ---------------- K3: fused decoder, 2 img/block, class-per-wave (uniform branches) -------
__global__ __launch_bounds__(512) void k_dtail(
    const ushort_t* __restrict__ zupT,     // [4096][6400]
    const ushort_t* __restrict__ wd1frag,  // [9][8][64][8]
    const float* __restrict__ bd1, const float* __restrict__ gd1, const float* __restrict__ btd1,
    const float* __restrict__ wd2, const float* __restrict__ bd2,
    const float* __restrict__ gd2, const float* __restrict__ btd2,
    const float* __restrict__ wd3, const float* __restrict__ bd3,
    float* __restrict__ out0)
{
    int b0 = blockIdx.x * 2, t = threadIdx.x;
    int w = t >> 6, l = t & 63, lr = l & 15, lg = l >> 4;
    int g = w >> 2, wv = w & 3, tg = t & 255;
    __shared__ __align__(16) unsigned char dbuf[33792];
    __shared__ float hd1p[2][16][64];
    __shared__ float w2sT[9 * 8 * 16];
    __shared__ float w3sT[9 * 8];
    ushort_t* zAb = (ushort_t*)dbuf;
    float* Psb = (float*)dbuf;

    const float bnr = rsqrtf(1.0f + 1e-5f);

    for (int c = t; c < 1600; c += 512) {
        int im = c / 800, cc = c % 800;
        *(us8*)&zAb[im * 8448 + (cc >> 5) * 264 + (cc & 31) * 8] =
            *(const us8*)&zupT[(size_t)(b0 + im) * 6400 + cc * 8];
    }
    for (int i = t; i < 2048; i += 512) ((float*)hd1p)[i] = 0.f;
    for (int i = t; i < 1152; i += 512) {
        int s = i >> 7, rest = i & 127;
        int co = rest >> 4, ci = rest & 15;
        w2sT[i] = wd2[(ci * 8 + co) * 9 + s];
    }
    if (t < 72) {
        int s = t >> 3, ci = t & 7;
        w3sT[t] = wd3[ci * 9 + s];
    }
    __syncthreads();

    {
        f32x4 acc[3][2];
#pragma unroll
        for (int i = 0; i < 3; i++)
#pragma unroll
            for (int mt = 0; mt < 2; mt++) acc[i][mt] = (f32x4){0.f, 0.f, 0.f, 0.f};
        const s8v* B = (const s8v*)wd1frag;
        for (int k0 = 0; k0 < 8; k0++) {
            s8v a0 = *(const s8v*)&zAb[g * 8448 + lr * 264 + k0 * 32 + lg * 8];
            s8v a1 = *(const s8v*)&zAb[g * 8448 + (16 + lr) * 264 + k0 * 32 + lg * 8];
#pragma unroll
            for (int i = 0; i < 3; i++) {
                int nt = wv + 4 * i;
                if (nt < 9) {
                    s8v bb = B[(nt * 8 + k0) * 64 + l];
                    acc[i][0] = __builtin_amdgcn_mfma_f32_16x16x32_bf16(a0, bb, acc[i][0], 0, 0, 0);
                    acc[i][1] = __builtin_amdgcn_mfma_f32_16x16x32_bf16(a1, bb, acc[i][1], 0, 0, 0);
                }
            }
        }
        __syncthreads();
#pragma unroll
        for (int i = 0; i < 3; i++) {
            int nt = wv + 4 * i;
            if (nt < 9) {
                int col = nt * 16 + lr;
#pragma unroll
                for (int mt = 0; mt < 2; mt++)
#pragma unroll
                    for (int r = 0; r < 4; r++) {
                        int pos = mt * 16 + lg * 4 + r;
                        if (pos < 25) Psb[g * 3700 + pos * 148 + col] = acc[i][mt][r];
                    }
            }
        }
    }
    __syncthreads();

    for (int o = tg; o < 784; o += 256) {
        int co = o / 49, rr = o % 49, y = rr / 7, xx = rr % 7;
        float a = bd1[co];
        int sy0 = y - 4 > 0 ? y - 4 : 0, sy1 = y < 2 ? y : 2;
        for (int sy = sy0; sy <= sy1; sy++) {
            int iy = y - sy;
            int sx0 = xx - 4 > 0 ? xx - 4 : 0, sx1 = xx < 2 ? xx : 2;
            for (int sx = sx0; sx <= sx1; sx++) {
                int ix = xx - sx;
                a += Psb[g * 3700 + (iy * 5 + ix) * 148 + co * 9 + sy * 3 + sx];
            }
        }
        float v = a * (gd1[co] * bnr) + btd1[co];
        hd1p[g][co][y * 8 + xx] = fmaxf(v, 0.f);
    }
    __syncthreads();

    {
        if (t < 464) {
            int im = t / 232, rest = t % 232;
            int co = rest / 29, s = rest % 29;
            int yy = (s < 15) ? 14 : (s - 15);
            int xx2 = (s < 15) ? s : 14;
            ((float*)dbuf)[im * 1808 + co * 225 + yy * 15 + xx2] = 0.f;
        }
        int cls = (wv + g) & 3;
        int cy = cls >> 1, cx = cls & 1;
        if (l < 56 && (l & 7) < 7) {
            int r = l >> 3, c = l & 7;
            float acc[8];
#pragma unroll
            for (int co = 0; co < 8; co++) acc[co] = 0.f;
            const float* hb = &hd1p[g][0][0];
            int niy = 1 + cy, nix = 1 + cx;
            for (int ty = 0; ty < niy; ty++) {
                int iy = r + ty;
                int sy = cy ? (ty ? 0 : 2) : 1;
                for (int tx = 0; tx < nix; tx++) {
                    int ix = c + tx;
                    int sx = cx ? (tx ? 0 : 2) : 1;
                    const float* wp = &w2sT[(sy * 3 + sx) * 128];
                    int hoff = iy * 8 + ix;
                    float h[16];
#pragma unroll
                    for (int ci = 0; ci < 16; ci++) h[ci] = hb[ci * 64 + hoff];
#pragma unroll
                    for (int co = 0; co < 8; co++) {
                        const float4* wp4 = (const float4*)&wp[co * 16];
                        float4 wa = wp4[0], wb4 = wp4[1], wc4 = wp4[2], wd4 = wp4[3];
                        float a = acc[co];
                        a = fmaf(h[0], wa.x, a);  a = fmaf(h[1], wa.y, a);
                        a = fmaf(h[2], wa.z, a);  a = fmaf(h[3], wa.w, a);
                        a = fmaf(h[4], wb4.x, a); a = fmaf(h[5], wb4.y, a);
                        a = fmaf(h[6], wb4.z, a); a = fmaf(h[7], wb4.w, a);
                        a = fmaf(h[8], wc4.x, a); a = fmaf(h[9], wc4.y, a);
                        a = fmaf(h[10], wc4.z, a); a = fmaf(h[11], wc4.w, a);
                        a = fmaf(h[12], wd4.x, a); a = fmaf(h[13], wd4.y, a);
                        a = fmaf(h[14], wd4.z, a); a = fmaf(h[15], wd4.w, a);
                        acc[co] = a;
                    }
                }
            }
            int y = 2 * r + cy, x = 2 * c + cx;
            float* hout = (float*)dbuf + g * 1808;
#pragma unroll
            for (int co = 0; co < 8; co++) {
                float v = (acc[co] + bd2[co]) * (gd2[co] * bnr) + btd2[co];
                hout[co * 225 + y * 15 + x] = fmaxf(v, 0.f);
            }
        }
    }
    __syncthreads();

    {
        int cls = (wv + g) & 3;
        int cy = cls >> 1, cx = cls & 1;
        const float* h2b = (const float*)dbuf + g * 1808;
        float* og = out0 + (size_t)(b0 + g) * 784;
        int niy = 1 + cy, nix = 1 + cx;
#pragma unroll
        for (int j = 0; j < 4; j++) {
            int idx = l + 64 * j;
            if (idx < 224) {
                int row = idx >> 4, col = idx & 15;
                if (col < 14) {
                    float a = bd3[0];
                    for (int ty = 0; ty < niy; ty++) {
                        int iy = row + ty;
                        int sy = cy ? (ty ? 0 : 2) : 1;
                        for (int tx = 0; tx < nix; tx++) {
                            int ix = col + tx;
                            int sx = cx ? (tx ? 0 : 2) : 1;
                            const float* wp = &w3sT[(sy * 3 + sx) * 8];
                            int hoff = iy * 15 + ix;
#pragma unroll
                            for (int ci = 0; ci < 8; ci++)
                                a = fmaf(h2b[ci * 225 + hoff], wp[ci], a);
                        }
                    }
                    int y = 2 * row + cy, x = 2 * col + cx;
                    og[y * 28 + x] = 1.f / (1.f + expf(-a));
                }
            }
        }
    }
}

extern "C" void kernel_launch(void* const* d_in, const int* in_sizes, int n_in,
                              void* d_out, int out_size, void* d_ws, size_t ws_size,
                              hipStream_t stream) {
    const float* x    = (const float*)d_in[0];
    const float* w1   = (const float*)d_in[1];
    const float* b1   = (const float*)d_in[2];
    const float* w2   = (const float*)d_in[3];
    const float* b2   = (const float*)d_in[4];
    const float* g2   = (const float*)d_in[5];
    const float* bt2  = (const float*)d_in[6];
    const float* w3   = (const float*)d_in[7];
    const float* b3   = (const float*)d_in[8];
    const float* proto= (const float*)d_in[9];
    const float* wup  = (const float*)d_in[10];
    const float* bup  = (const float*)d_in[11];
    const float* gup  = (const float*)d_in[12];
    const float* btup = (const float*)d_in[13];
    const float* wd1  = (const float*)d_in[14];
    const float* bd1  = (const float*)d_in[15];
    const float* gd1  = (const float*)d_in[16];
    const float* btd1 = (const float*)d_in[17];
    const float* wd2  = (const float*)d_in[18];
    const float* bd2  = (const float*)d_in[19];
    const float* gd2  = (const float*)d_in[20];
    const float* btd2 = (const float*)d_in[21];
    const float* wd3  = (const float*)d_in[22];
    const float* bd3  = (const float*)d_in[23];

    float* out0   = (float*)d_out;                 // [4096][784]
    float* out_md = out0 + (size_t)NB * 784;       // [4096][512]

    // ws layout
    float*    p2      = (float*)d_ws;                          // 512 f
    float*    x2g     = p2 + 512;                              // 131072 f
    ushort_t* pfragHi = (ushort_t*)(x2g + 131072);             // 131072
    ushort_t* pfragLo = pfragHi + 131072;                      // 131072
    ushort_t* w3fH    = pfragLo + 131072;                      // 40960
    ushort_t* w3fL    = w3fH + 40960;                          // 40960
    ushort_t* w2fH    = w3fL + 40960;                          // 1536
    ushort_t* w2fL    = w2fH + 1536;                           // 1536
    ushort_t* wd1frag = w2fL + 1536;                           // 36864
    ushort_t* wupfH   = wd1frag + 36864;                       // 1638400
    ushort_t* wupfL   = wupfH + 1638400;                       // 1638400
    ushort_t* PWfrag  = wupfL + 1638400;                       // 3276800
    ushort_t* Wsm     = PWfrag + 3276800;                      // 2097152
    ushort_t* BIG     = Wsm + 2097152;                         // 52.4 MB region
    ushort_t* h3g     = BIG;                                   // [4096][25][256] bf16
    ushort_t* zupT    = BIG;                                   // [4096][6400] (aliases dead h3g)

    hipLaunchKernelGGL(k_pre, dim3(7734), dim3(256), 0, stream,
                       proto, p2, pfragHi, pfragLo, w3, w3fH, w3fL,
                       w2, w2fH, w2fL, wd1, wd1frag, wup, wupfH, wupfL);
    hipLaunchKernelGGL(k_pw2, dim3(25, 32), dim3(256), 0, stream,
                       pfragHi, pfragLo, wupfH, wupfL, PWfrag);
    hipLaunchKernelGGL(k_enc1, dim3(NB), dim3(512), 0, stream,
                       x, w1, b1, w2fH, w2fL, b2, g2, bt2, w3fH, w3fL, b3, h3g, x2g);
    hipLaunchKernelGGL(k_enc2, dim3(NB / 2), dim3(1024), 0, stream,
                       h3g, x2g, pfragHi, pfragLo, p2, out_md, Wsm);
    hipLaunchKernelGGL(k_zup2, dim3(50, 32), dim3(512), 0, stream,
                       Wsm, PWfrag, bup, gup, btup, zupT);
    hipLaunchKernelGGL(k_dtail, dim3(NB / 2), dim3(512), 0, stream,
                       zupT, wd1frag, bd1, gd1, btd1, wd2, bd2, gd2, btd2, wd3, bd3, out0);
}

// Round 16
// 289.626 us; speedup vs baseline: 1.4812x; 1.0081x over previous
//
#include <hip/hip_runtime.h>
#include <hip/hip_bf16.h>
#include <math.h>

#define NB 4096
#define DC 256
#define PC 512

typedef unsigned short ushort_t;
typedef __attribute__((ext_vector_type(4))) unsigned short us4;
typedef __attribute__((ext_vector_type(8))) unsigned short us8;
typedef __attribute__((ext_vector_type(8))) short s8v;       // bf16x8 for MFMA
typedef __attribute__((ext_vector_type(4))) float f32x4;

__device__ __forceinline__ float bf16_to_f(ushort_t u) {
    union { unsigned int i; float f; } c;
    c.i = ((unsigned int)u) << 16;
    return c.f;
}
__device__ __forceinline__ ushort_t f2bf(float f) {          // RNE
    union { float f; unsigned int u; } c; c.f = f;
    unsigned int r = c.u + 0x7fffu + ((c.u >> 16) & 1u);
    return (ushort_t)(r >> 16);
}

// ---------------- K_pre: all small packing kernels merged (blockIdx-range dispatch) -------
__global__ __launch_bounds__(256) void k_pre(
    const float* __restrict__ proto, float* __restrict__ p2,
    ushort_t* __restrict__ pfragHi, ushort_t* __restrict__ pfragLo,
    const float* __restrict__ w3, ushort_t* __restrict__ w3fH, ushort_t* __restrict__ w3fL,
    const float* __restrict__ w2, ushort_t* __restrict__ w2fH, ushort_t* __restrict__ w2fL,
    const float* __restrict__ wd1, ushort_t* __restrict__ wd1frag,
    const float* __restrict__ wup, ushort_t* __restrict__ wupfH, ushort_t* __restrict__ wupfL)
{
    int b = blockIdx.x, tid = threadIdx.x;
    __shared__ float red[256];
    if (b < 512) {
        int p = b, d = tid;
        float v = proto[p * DC + d];
        red[d] = v * v;
        __syncthreads();
        for (int s = 128; s > 0; s >>= 1) {
            if (d < s) red[d] += red[d + s];
            __syncthreads();
        }
        if (d == 0) p2[p] = red[0];
    } else if (b < 1024) {
        int idx = (b - 512) * 256 + tid;
        int j = idx & 7, l = (idx >> 3) & 63;
        int k0 = (idx >> 9) & 7, nt = idx >> 12;
        int n = nt * 16 + (l & 15);
        int k = k0 * 32 + (l >> 4) * 8 + j;
        float v = proto[n * DC + k];
        ushort_t hi = f2bf(v);
        pfragHi[idx] = hi;
        pfragLo[idx] = f2bf(v - bf16_to_f(hi));
    } else if (b < 1184) {
        int idx = (b - 1024) * 256 + tid;
        int j = idx & 7, l = (idx >> 3) & 63;
        int q = idx >> 9;
        int k0 = q % 5, nt = q / 5;
        int d = nt * 16 + (l & 15);
        int k = k0 * 32 + (l >> 4) * 8 + j;
        float v = (k < 144) ? w3[d * 144 + k] : 0.f;
        ushort_t hi = f2bf(v);
        w3fH[idx] = hi;
        w3fL[idx] = f2bf(v - bf16_to_f(hi));
    } else if (b < 1190) {
        int idx = (b - 1184) * 256 + tid;
        int j = idx & 7, l = (idx >> 3) & 63;
        int k0 = idx >> 9;
        int ch = l & 15;
        int k = k0 * 32 + (l >> 4) * 8 + j;
        float v = (k < 72) ? w2[ch * 72 + k] : 0.f;
        ushort_t hi = f2bf(v);
        w2fH[idx] = hi;
        w2fL[idx] = f2bf(v - bf16_to_f(hi));
    } else if (b < 1334) {
        int idx = (b - 1190) * 256 + tid;
        int j = idx & 7, l = (idx >> 3) & 63;
        int k0 = (idx >> 9) & 7, nt = idx >> 12;
        int n = nt * 16 + (l & 15);
        int k = k0 * 32 + (l >> 4) * 8 + j;
        wd1frag[idx] = f2bf(wd1[k * 144 + n]);
    } else {
        int idx = (b - 1334) * 256 + tid;
        int j = idx & 7, l = (idx >> 3) & 63;
        int k0 = (idx >> 9) & 7, nt = idx >> 12;
        int np = nt * 16 + (l & 15);
        int d = k0 * 32 + (l >> 4) * 8 + j;
        int pos = np >> 8, ch = np & 255;
        float v = wup[d * 6400 + ch * 25 + pos];
        ushort_t hi = f2bf(v);
        wupfH[idx] = hi;
        wupfL[idx] = f2bf(v - bf16_to_f(hi));
    }
}

// ---------------- K0f: PW = proto x wupT via MFMA (hi/lo), -> PWfrag [400][16][64][8] -----
__global__ __launch_bounds__(256) void k_pw2(
    const ushort_t* __restrict__ pfragHi, const ushort_t* __restrict__ pfragLo,
    const ushort_t* __restrict__ wupfH, const ushort_t* __restrict__ wupfL,
    ushort_t* __restrict__ PWfrag)
{
    int t = threadIdx.x;
    int w = t >> 6, l = t & 63, lr = l & 15, lg = l >> 4;
    int my = blockIdx.y;
    int ntb = blockIdx.x * 16 + w * 4;
    const s8v* AH = (const s8v*)pfragHi;
    const s8v* AL = (const s8v*)pfragLo;
    const s8v* BH = (const s8v*)wupfH;
    const s8v* BL = (const s8v*)wupfL;
    f32x4 acc[4];
#pragma unroll
    for (int q = 0; q < 4; q++) acc[q] = (f32x4){0.f, 0.f, 0.f, 0.f};
#pragma unroll
    for (int k0 = 0; k0 < 8; k0++) {
        s8v ah = AH[(my * 8 + k0) * 64 + l];
        s8v al = AL[(my * 8 + k0) * 64 + l];
#pragma unroll
        for (int q = 0; q < 4; q++) {
            s8v bh = BH[(size_t)((ntb + q) * 8 + k0) * 64 + l];
            s8v bl = BL[(size_t)((ntb + q) * 8 + k0) * 64 + l];
            acc[q] = __builtin_amdgcn_mfma_f32_16x16x32_bf16(ah, bh, acc[q], 0, 0, 0);
            acc[q] = __builtin_amdgcn_mfma_f32_16x16x32_bf16(al, bh, acc[q], 0, 0, 0);
            acc[q] = __builtin_amdgcn_mfma_f32_16x16x32_bf16(ah, bl, acc[q], 0, 0, 0);
        }
    }
#pragma unroll
    for (int q = 0; q < 4; q++) {
        int nt = ntb + q;
#pragma unroll
        for (int r = 0; r < 4; r++) {
            int p = my * 16 + lg * 4 + r;
            int k0p = p >> 5;
            int ll = ((p >> 3) & 3) * 16 + lr;
            int jj = p & 7;
            PWfrag[(((size_t)(nt * 16 + k0p) * 64) + ll) * 8 + jj] = f2bf(acc[q][r]);
        }
    }
}

// ---------------- E1: conv1(+scatter) + conv2 MFMA (+scatter) + conv3 — single-bf16 A -----
__global__ __launch_bounds__(512) void k_enc1(
    const float* __restrict__ x,
    const float* __restrict__ w1, const float* __restrict__ b1,
    const ushort_t* __restrict__ w2fH, const ushort_t* __restrict__ w2fL,
    const float* __restrict__ b2,
    const float* __restrict__ g2, const float* __restrict__ bt2,
    const ushort_t* __restrict__ w3fH, const ushort_t* __restrict__ w3fL,
    const float* __restrict__ b3,
    ushort_t* __restrict__ h3g,        // [4096][25][256] bf16
    float* __restrict__ x2g)           // [4096][32]
{
    int b = blockIdx.x;
    int t = threadIdx.x;
    int w = t >> 6, l = t & 63, lr = l & 15, lg = l >> 4;

    // LDS: xb@0(3136) h1@3136(6272) | im2Hi@9408(13312) | h2@22720(3136) : 25856 B
    //      conv3: imHi@0(9248) overlays dead xb/h1
    __shared__ __align__(16) unsigned char buf[25856];
    __shared__ float x2s[32];
    float* xb = (float*)buf;
    float* h1 = (float*)(buf + 3136);
    ushort_t* im2Hi = (ushort_t*)(buf + 9408);
    float* h2 = (float*)(buf + 22720);
    ushort_t* imHi = (ushort_t*)buf;

    const float bnr = rsqrtf(1.0f + 1e-5f);

    const float* xg = x + (size_t)b * 784;
    for (int i = t; i < 784; i += 512) xb[i] = xg[i];
    for (int i = t; i < 832; i += 512)
        ((float4*)(buf + 9408))[i] = (float4){0.f, 0.f, 0.f, 0.f};
    if (t < 32) x2s[t] = (t < 25) ? 0.f : 1e30f;
    __syncthreads();

    // phase 1: conv1 + scatter into im2col2 (single bf16)
    for (int o = t; o < 1568; o += 512) {
        int c = o / 196, r = o % 196, y = r / 14, xc = r % 14;
        float acc = b1[c];
        for (int sy = 0; sy < 3; sy++) {
            int iy = 2 * y - 1 + sy;
            if ((unsigned)iy >= 28u) continue;
            for (int sx = 0; sx < 3; sx++) {
                int ix = 2 * xc - 1 + sx;
                if ((unsigned)ix >= 28u) continue;
                acc += w1[c * 9 + sy * 3 + sx] * xb[iy * 28 + ix];
            }
        }
        float v = fmaxf(acc, 0.f);
        ushort_t hi = f2bf(v);
        int kb = c * 9;
        int yA, syA, xA, sxA, yB = 0, xB = 0;
        bool hasYB, hasXB;
        if (y & 1) { yA = y >> 1; syA = 2; yB = yA + 1; hasYB = (yB < 7); }
        else       { yA = y >> 1; syA = 1; hasYB = false; }
        if (xc & 1) { xA = xc >> 1; sxA = 2; xB = xA + 1; hasXB = (xB < 7); }
        else        { xA = xc >> 1; sxA = 1; hasXB = false; }
        im2Hi[(yA * 7 + xA) * 104 + kb + syA * 3 + sxA] = hi;
        if (hasXB) im2Hi[(yA * 7 + xB) * 104 + kb + syA * 3] = hi;
        if (hasYB) {
            im2Hi[(yB * 7 + xA) * 104 + kb + sxA] = hi;
            if (hasXB) im2Hi[(yB * 7 + xB) * 104 + kb] = hi;
        }
    }
    __syncthreads();

    // phase 2: conv2 as MFMA (waves 0-3), single-A x hi/lo-B
    if (w < 4) {
        f32x4 cc = {0, 0, 0, 0};
        const s8v* WH = (const s8v*)w2fH;
        const s8v* WL = (const s8v*)w2fL;
#pragma unroll
        for (int k0 = 0; k0 < 3; k0++) {
            s8v a0 = *(const s8v*)&im2Hi[(w * 16 + lr) * 104 + k0 * 32 + lg * 8];
            s8v bh = WH[k0 * 64 + l];
            s8v bl = WL[k0 * 64 + l];
            cc = __builtin_amdgcn_mfma_f32_16x16x32_bf16(a0, bh, cc, 0, 0, 0);
            cc = __builtin_amdgcn_mfma_f32_16x16x32_bf16(a0, bl, cc, 0, 0, 0);
        }
        int ch = lr;
        float s = g2[ch] * bnr, bb = b2[ch], bt = bt2[ch];
#pragma unroll
        for (int r = 0; r < 4; r++) {
            int pos = w * 16 + lg * 4 + r;
            if (pos < 49)
                h2[ch * 49 + pos] = fmaxf((cc[r] + bb) * s + bt, 0.f);
        }
    }
    __syncthreads();

    // phase 3: scatter h2 -> im2col3 (single bf16)
    if (t < 16) imHi[3600 + t] = 0;
    for (int o = t; o < 784; o += 512) {
        float v = h2[o];
        int ci = o / 49, rr = o % 49, iy = rr / 7, ixp = rr % 7;
        ushort_t hi = f2bf(v);
        int kb = ci * 9;
#pragma unroll
        for (int sy = 0; sy < 3; sy++) {
            int py = iy - sy;
            if ((unsigned)py < 5u) {
#pragma unroll
                for (int sx = 0; sx < 3; sx++) {
                    int px = ixp - sx;
                    if ((unsigned)px < 5u)
                        imHi[(py * 5 + px) * 144 + kb + sy * 3 + sx] = hi;
                }
            }
        }
    }
    __syncthreads();

    // phase 4: conv3 as MFMA (single-A x hi/lo-B), bias+relu; bf16 store + x2
    {
        int nt0 = 2 * w;
        f32x4 c00 = {0,0,0,0}, c01 = {0,0,0,0}, c10 = {0,0,0,0}, c11 = {0,0,0,0};
        const s8v* WH = (const s8v*)w3fH;
        const s8v* WL = (const s8v*)w3fL;
#pragma unroll
        for (int k0 = 0; k0 < 5; k0++) {
            s8v ah0 = *(const s8v*)&imHi[lr * 144 + k0 * 32 + lg * 8];
            s8v ah1 = *(const s8v*)&imHi[(16 + lr) * 144 + k0 * 32 + lg * 8];
            s8v bh0 = WH[(nt0 * 5 + k0) * 64 + l];
            s8v bl0 = WL[(nt0 * 5 + k0) * 64 + l];
            s8v bh1 = WH[((nt0 + 1) * 5 + k0) * 64 + l];
            s8v bl1 = WL[((nt0 + 1) * 5 + k0) * 64 + l];
            c00 = __builtin_amdgcn_mfma_f32_16x16x32_bf16(ah0, bh0, c00, 0, 0, 0);
            c10 = __builtin_amdgcn_mfma_f32_16x16x32_bf16(ah1, bh0, c10, 0, 0, 0);
            c00 = __builtin_amdgcn_mfma_f32_16x16x32_bf16(ah0, bl0, c00, 0, 0, 0);
            c10 = __builtin_amdgcn_mfma_f32_16x16x32_bf16(ah1, bl0, c10, 0, 0, 0);
            c01 = __builtin_amdgcn_mfma_f32_16x16x32_bf16(ah0, bh1, c01, 0, 0, 0);
            c11 = __builtin_amdgcn_mfma_f32_16x16x32_bf16(ah1, bh1, c11, 0, 0, 0);
            c01 = __builtin_amdgcn_mfma_f32_16x16x32_bf16(ah0, bl1, c01, 0, 0, 0);
            c11 = __builtin_amdgcn_mfma_f32_16x16x32_bf16(ah1, bl1, c11, 0, 0, 0);
        }
        ushort_t* hg = h3g + (size_t)b * 6400;
#pragma unroll
        for (int q = 0; q < 2; q++) {
            int d = (nt0 + q) * 16 + lr;
            float bb = b3[d];
            f32x4 cm0 = q ? c01 : c00;
            f32x4 cm1 = q ? c11 : c10;
#pragma unroll
            for (int mt = 0; mt < 2; mt++) {
                f32x4 cv = mt ? cm1 : cm0;
#pragma unroll
                for (int r = 0; r < 4; r++) {
                    int pos = mt * 16 + lg * 4 + r;
                    if (pos < 25) {
                        float h = fmaxf(cv[r] + bb, 0.f);
                        ushort_t hi = f2bf(h);
                        float hh = bf16_to_f(hi);
                        hg[pos * 256 + d] = hi;
                        float sq = hh * hh;
                        sq += __shfl_xor(sq, 1);
                        sq += __shfl_xor(sq, 2);
                        sq += __shfl_xor(sq, 4);
                        sq += __shfl_xor(sq, 8);
                        if (lr == 0) atomicAdd(&x2s[pos], sq);
                    }
                }
            }
        }
    }
    __syncthreads();
    if (t < 32) x2g[(size_t)b * 32 + t] = x2s[t];
}

// ---------------- E2: MFMA distances + softmax (2 img/block, single-bf16 A, 2-term) ------
__global__ __launch_bounds__(1024) void k_enc2(
    const ushort_t* __restrict__ h3g,        // [4096][25][256] bf16
    const float* __restrict__ x2g,           // [4096][32]
    const ushort_t* __restrict__ pfragHi, const ushort_t* __restrict__ pfragLo,
    const float* __restrict__ p2,
    float* __restrict__ md_out,
    ushort_t* __restrict__ Wsm)
{
    int t = threadIdx.x;
    int b0 = blockIdx.x * 2;
    int w = t >> 6, l = t & 63, lr = l & 15, lg = l >> 4;

    __shared__ __align__(16) ushort_t h3s[2][32][264];   // 33792 B
    __shared__ float mds[2][512];
    __shared__ float x2sh[2][32];
    __shared__ float wred[2][16];

    for (int i = t; i < 2048; i += 1024) {
        int im = i >> 10, pos = (i >> 5) & 31, c8 = i & 31;
        us8 v = {0, 0, 0, 0, 0, 0, 0, 0};
        if (pos < 25)
            v = *(const us8*)&h3g[(size_t)(b0 + im) * 6400 + pos * 256 + c8 * 8];
        *(us8*)&h3s[im][pos][c8 * 8] = v;
    }
    if (t < 64) x2sh[t >> 5][t & 31] = x2g[(size_t)(b0 + (t >> 5)) * 32 + (t & 31)];
    __syncthreads();

    {
        f32x4 acc[2][2][2];
#pragma unroll
        for (int i = 0; i < 2; i++)
#pragma unroll
            for (int jm = 0; jm < 2; jm++)
#pragma unroll
                for (int mt = 0; mt < 2; mt++) acc[i][jm][mt] = (f32x4){0.f, 0.f, 0.f, 0.f};
        const s8v* BH = (const s8v*)pfragHi;
        const s8v* BL = (const s8v*)pfragLo;
        s8v bhc[2], blc[2], bhn[2], bln[2];
#pragma unroll
        for (int ntq = 0; ntq < 2; ntq++) {
            int nt = w * 2 + ntq;
            bhc[ntq] = BH[(nt * 8 + 0) * 64 + l];
            blc[ntq] = BL[(nt * 8 + 0) * 64 + l];
        }
        for (int k0 = 0; k0 < 8; k0++) {
            if (k0 < 7) {
#pragma unroll
                for (int ntq = 0; ntq < 2; ntq++) {
                    int nt = w * 2 + ntq;
                    bhn[ntq] = BH[(nt * 8 + k0 + 1) * 64 + l];
                    bln[ntq] = BL[(nt * 8 + k0 + 1) * 64 + l];
                }
            }
            s8v ah[2][2];
            ah[0][0] = *(const s8v*)&h3s[0][lr][k0 * 32 + lg * 8];
            ah[0][1] = *(const s8v*)&h3s[0][16 + lr][k0 * 32 + lg * 8];
            ah[1][0] = *(const s8v*)&h3s[1][lr][k0 * 32 + lg * 8];
            ah[1][1] = *(const s8v*)&h3s[1][16 + lr][k0 * 32 + lg * 8];
#pragma unroll
            for (int ntq = 0; ntq < 2; ntq++) {
                s8v bh = bhc[ntq];
                s8v bl = blc[ntq];
#pragma unroll
                for (int im = 0; im < 2; im++) {
                    acc[ntq][im][0] = __builtin_amdgcn_mfma_f32_16x16x32_bf16(ah[im][0], bh, acc[ntq][im][0], 0, 0, 0);
                    acc[ntq][im][1] = __builtin_amdgcn_mfma_f32_16x16x32_bf16(ah[im][1], bh, acc[ntq][im][1], 0, 0, 0);
                    acc[ntq][im][0] = __builtin_amdgcn_mfma_f32_16x16x32_bf16(ah[im][0], bl, acc[ntq][im][0], 0, 0, 0);
                    acc[ntq][im][1] = __builtin_amdgcn_mfma_f32_16x16x32_bf16(ah[im][1], bl, acc[ntq][im][1], 0, 0, 0);
                }
            }
#pragma unroll
            for (int ntq = 0; ntq < 2; ntq++) {
                bhc[ntq] = bhn[ntq];
                blc[ntq] = bln[ntq];
            }
        }
        float x2r[2][8];
#pragma unroll
        for (int im = 0; im < 2; im++)
#pragma unroll
            for (int r = 0; r < 4; r++) {
                x2r[im][r]     = x2sh[im][lg * 4 + r];
                x2r[im][4 + r] = x2sh[im][16 + lg * 4 + r];
            }
#pragma unroll
        for (int ntq = 0; ntq < 2; ntq++) {
            int pcol = (w * 2 + ntq) * 16 + lr;
            float p2v = p2[pcol];
#pragma unroll
            for (int im = 0; im < 2; im++) {
                float mm = 1e30f;
#pragma unroll
                for (int r = 0; r < 4; r++) {
                    float d0 = fmaxf(x2r[im][r]     - 2.f * acc[ntq][im][0][r] + p2v, 0.f);
                    float d1 = fmaxf(x2r[im][4 + r] - 2.f * acc[ntq][im][1][r] + p2v, 0.f);
                    mm = fminf(mm, fminf(d0, d1));
                }
                mm = fminf(mm, __shfl_xor(mm, 16));
                mm = fminf(mm, __shfl_xor(mm, 32));
                if (lg == 0) mds[im][pcol] = mm;
            }
        }
    }
    __syncthreads();

    int img = t >> 9, tt = t & 511;
    float mind = mds[img][tt];
    md_out[(size_t)(b0 + img) * PC + tt] = mind;
    float a = -mind;
    float mx = a;
#pragma unroll
    for (int off = 1; off < 64; off <<= 1) mx = fmaxf(mx, __shfl_xor(mx, off));
    int wv = w & 7;
    if (l == 0) wred[img][wv] = mx;
    __syncthreads();
    float m = wred[img][0];
#pragma unroll
    for (int i = 1; i < 8; i++) m = fmaxf(m, wred[img][i]);
    float e = expf(a - m);
    float sm = e;
#pragma unroll
    for (int off = 1; off < 64; off <<= 1) sm += __shfl_xor(sm, off);
    if (l == 0) wred[img][8 + wv] = sm;
    __syncthreads();
    float ssum = wred[img][8];
#pragma unroll
    for (int i = 9; i < 16; i++) ssum += wred[img][i];
    Wsm[(size_t)(b0 + img) * PC + tt] = f2bf(e / ssum);
}

// ---------------- K2: zupT = Wsm x PW (bf16 MFMA, 2-slab staging), bias+bn+relu ----------
__global__ __launch_bounds__(512) void k_zup2(
    const ushort_t* __restrict__ Wsm,      // [4096][512]
    const ushort_t* __restrict__ PWfrag,   // [400][16][64][8]
    const float* __restrict__ bup, const float* __restrict__ gup,
    const float* __restrict__ btup,
    ushort_t* __restrict__ zupT)           // [4096][6400]
{
    __shared__ __align__(16) ushort_t Bsh[2][8192];
    int t = threadIdx.x;
    int w = t >> 6, l = t & 63;
    int n0 = blockIdx.x * 128;             // 50
    int m0 = blockIdx.y * 128;             // 32
    int row = m0 + w * 16 + (l & 15);
    int krow = (l >> 4) * 8;
    f32x4 acc[8];
#pragma unroll
    for (int i = 0; i < 8; i++) acc[i] = (f32x4){0.f, 0.f, 0.f, 0.f};
    const s8v* B = (const s8v*)PWfrag;
    int base = blockIdx.x * 8 * 16;

    {
        s8v v0 = B[(size_t)(base + (t >> 6) * 16 + 0) * 64 + (t & 63)];
        s8v v1 = B[(size_t)(base + (t >> 6) * 16 + 1) * 64 + (t & 63)];
        *(s8v*)&Bsh[0][t * 8] = v0;
        *(s8v*)&Bsh[0][4096 + t * 8] = v1;
    }
    __syncthreads();
    for (int r = 0; r < 8; r++) {
        int cur = r & 1;
        if (r < 7) {
            s8v v0 = B[(size_t)(base + (t >> 6) * 16 + 2 * r + 2) * 64 + (t & 63)];
            s8v v1 = B[(size_t)(base + (t >> 6) * 16 + 2 * r + 3) * 64 + (t & 63)];
            *(s8v*)&Bsh[cur ^ 1][t * 8] = v0;
            *(s8v*)&Bsh[cur ^ 1][4096 + t * 8] = v1;
        }
#pragma unroll
        for (int kk = 0; kk < 2; kk++) {
            int k0 = 2 * r + kk;
            s8v a = *(const s8v*)&Wsm[(size_t)row * 512 + k0 * 32 + krow];
#pragma unroll
            for (int nt = 0; nt < 8; nt++) {
                s8v bb = *(const s8v*)&Bsh[cur][kk * 4096 + (nt * 64 + l) * 8];
                acc[nt] = __builtin_amdgcn_mfma_f32_16x16x32_bf16(a, bb, acc[nt], 0, 0, 0);
            }
        }
        __syncthreads();
    }

    const float bnr = rsqrtf(1.0f + 1e-5f);
    int rowbase = m0 + w * 16 + (l >> 4) * 4;
#pragma unroll
    for (int nt = 0; nt < 8; nt++) {
        int n = n0 + nt * 16 + (l & 15);
        int ch = n & 255;
        float sc = gup[ch] * bnr, bb = bup[ch], bt = btup[ch];
#pragma unroll
        for (int r = 0; r < 4; r++) {
            float v = (acc[nt][r] + bb) * sc + bt;
            zupT[(size_t)(rowbase + r) * 6400 + n] = f2bf(fmaxf(v, 0.f));
        }
    }
}

// ---------------- K3: fused decoder, 2 img/block, class-per-wave (uniform branches) -------
__global__ __launch_bounds__(512) void k_dtail(
    const ushort_t* __restrict__ zupT,     // [4096][6400]
    const ushort_t* __restrict__ wd1frag,  // [9][8][64][8]
    const float* __restrict__ bd1, const float* __restrict__ gd1, const float* __restrict__ btd1,
    const float* __restrict__ wd2, const float* __restrict__ bd2,
    const float* __restrict__ gd2, const float* __restrict__ btd2,
    const float* __restrict__ wd3, const float* __restrict__ bd3,
    float* __restrict__ out0)
{
    int b0 = blockIdx.x * 2, t = threadIdx.x;
    int w = t >> 6, l = t & 63, lr = l & 15, lg = l >> 4;
    int g = w >> 2, wv = w & 3, tg = t & 255;
    __shared__ __align__(16) unsigned char dbuf[33792];
    __shared__ float hd1p[2][16][64];
    __shared__ float w2sT[9 * 8 * 16];
    __shared__ float w3sT[9 * 8];
    ushort_t* zAb = (ushort_t*)dbuf;
    float* Psb = (float*)dbuf;

    const float bnr = rsqrtf(1.0f + 1e-5f);

    for (int c = t; c < 1600; c += 512) {
        int im = c / 800, cc = c % 800;
        *(us8*)&zAb[im * 8448 + (cc >> 5) * 264 + (cc & 31) * 8] =
            *(const us8*)&zupT[(size_t)(b0 + im) * 6400 + cc * 8];
    }
    for (int i = t; i < 2048; i += 512) ((float*)hd1p)[i] = 0.f;
    for (int i = t; i < 1152; i += 512) {
        int s = i >> 7, rest = i & 127;
        int co = rest >> 4, ci = rest & 15;
        w2sT[i] = wd2[(ci * 8 + co) * 9 + s];
    }
    if (t < 72) {
        int s = t >> 3, ci = t & 7;
        w3sT[t] = wd3[ci * 9 + s];
    }
    __syncthreads();

    {
        f32x4 acc[3][2];
#pragma unroll
        for (int i = 0; i < 3; i++)
#pragma unroll
            for (int mt = 0; mt < 2; mt++) acc[i][mt] = (f32x4){0.f, 0.f, 0.f, 0.f};
        const s8v* B = (const s8v*)wd1frag;
        for (int k0 = 0; k0 < 8; k0++) {
            s8v a0 = *(const s8v*)&zAb[g * 8448 + lr * 264 + k0 * 32 + lg * 8];
            s8v a1 = *(const s8v*)&zAb[g * 8448 + (16 + lr) * 264 + k0 * 32 + lg * 8];
#pragma unroll
            for (int i = 0; i < 3; i++) {
                int nt = wv + 4 * i;
                if (nt < 9) {
                    s8v bb = B[(nt * 8 + k0) * 64 + l];
                    acc[i][0] = __builtin_amdgcn_mfma_f32_16x16x32_bf16(a0, bb, acc[i][0], 0, 0, 0);
                    acc[i][1] = __builtin_amdgcn_mfma_f32_16x16x32_bf16(a1, bb, acc[i][1], 0, 0, 0);
                }
            }
        }
        __syncthreads();
#pragma unroll
        for (int i = 0; i < 3; i++) {
            int nt = wv + 4 * i;
            if (nt < 9) {
                int col = nt * 16 + lr;
#pragma unroll
                for (int mt = 0; mt < 2; mt++)
#pragma unroll
                    for (int r = 0; r < 4; r++) {
                        int pos = mt * 16 + lg * 4 + r;
                        if (pos < 25) Psb[g * 3700 + pos * 148 + col] = acc[i][mt][r];
                    }
            }
        }
    }
    __syncthreads();

    for (int o = tg; o < 784; o += 256) {
        int co = o / 49, rr = o % 49, y = rr / 7, xx = rr % 7;
        float a = bd1[co];
        int sy0 = y - 4 > 0 ? y - 4 : 0, sy1 = y < 2 ? y : 2;
        for (int sy = sy0; sy <= sy1; sy++) {
            int iy = y - sy;
            int sx0 = xx - 4 > 0 ? xx - 4 : 0, sx1 = xx < 2 ? xx : 2;
            for (int sx = sx0; sx <= sx1; sx++) {
                int ix = xx - sx;
                a += Psb[g * 3700 + (iy * 5 + ix) * 148 + co * 9 + sy * 3 + sx];
            }
        }
        float v = a * (gd1[co] * bnr) + btd1[co];
        hd1p[g][co][y * 8 + xx] = fmaxf(v, 0.f);
    }
    __syncthreads();

    {
        if (t < 464) {
            int im = t / 232, rest = t % 232;
            int co = rest / 29, s = rest % 29;
            int yy = (s < 15) ? 14 : (s - 15);
            int xx2 = (s < 15) ? s : 14;
            ((float*)dbuf)[im * 1808 + co * 225 + yy * 15 + xx2] = 0.f;
        }
        int cls = (wv + g) & 3;
        int cy = cls >> 1, cx = cls & 1;
        if (l < 56 && (l & 7) < 7) {
            int r = l >> 3, c = l & 7;
            float acc[8];
#pragma unroll
            for (int co = 0; co < 8; co++) acc[co] = 0.f;
            const float* hb = &hd1p[g][0][0];
            int niy = 1 + cy, nix = 1 + cx;
            for (int ty = 0; ty < niy; ty++) {
                int iy = r + ty;
                int sy = cy ? (ty ? 0 : 2) : 1;
                for (int tx = 0; tx < nix; tx++) {
                    int ix = c + tx;
                    int sx = cx ? (tx ? 0 : 2) : 1;
                    const float* wp = &w2sT[(sy * 3 + sx) * 128];
                    int hoff = iy * 8 + ix;
                    float h[16];
#pragma unroll
                    for (int ci = 0; ci < 16; ci++) h[ci] = hb[ci * 64 + hoff];
#pragma unroll
                    for (int co = 0; co < 8; co++) {
                        const float4* wp4 = (const float4*)&wp[co * 16];
                        float4 wa = wp4[0], wb4 = wp4[1], wc4 = wp4[2], wd4 = wp4[3];
                        float a = acc[co];
                        a = fmaf(h[0], wa.x, a);  a = fmaf(h[1], wa.y, a);
                        a = fmaf(h[2], wa.z, a);  a = fmaf(h[3], wa.w, a);
                        a = fmaf(h[4], wb4.x, a); a = fmaf(h[5], wb4.y, a);
                        a = fmaf(h[6], wb4.z, a); a = fmaf(h[7], wb4.w, a);
                        a = fmaf(h[8], wc4.x, a); a = fmaf(h[9], wc4.y, a);
                        a = fmaf(h[10], wc4.z, a); a = fmaf(h[11], wc4.w, a);
                        a = fmaf(h[12], wd4.x, a); a = fmaf(h[13], wd4.y, a);
                        a = fmaf(h[14], wd4.z, a); a = fmaf(h[15], wd4.w, a);
                        acc[co] = a;
                    }
                }
            }
            int y = 2 * r + cy, x = 2 * c + cx;
            float* hout = (float*)dbuf + g * 1808;
#pragma unroll
            for (int co = 0; co < 8; co++) {
                float v = (acc[co] + bd2[co]) * (gd2[co] * bnr) + btd2[co];
                hout[co * 225 + y * 15 + x] = fmaxf(v, 0.f);
            }
        }
    }
    __syncthreads();

    {
        int cls = (wv + g) & 3;
        int cy = cls >> 1, cx = cls & 1;
        const float* h2b = (const float*)dbuf + g * 1808;
        float* og = out0 + (size_t)(b0 + g) * 784;
        int niy = 1 + cy, nix = 1 + cx;
#pragma unroll
        for (int j = 0; j < 4; j++) {
            int idx = l + 64 * j;
            if (idx < 224) {
                int row = idx >> 4, col = idx & 15;
                if (col < 14) {
                    float a = bd3[0];
                    for (int ty = 0; ty < niy; ty++) {
                        int iy = row + ty;
                        int sy = cy ? (ty ? 0 : 2) : 1;
                        for (int tx = 0; tx < nix; tx++) {
                            int ix = col + tx;
                            int sx = cx ? (tx ? 0 : 2) : 1;
                            const float* wp = &w3sT[(sy * 3 + sx) * 8];
                            int hoff = iy * 15 + ix;
#pragma unroll
                            for (int ci = 0; ci < 8; ci++)
                                a = fmaf(h2b[ci * 225 + hoff], wp[ci], a);
                        }
                    }
                    int y = 2 * row + cy, x = 2 * col + cx;
                    og[y * 28 + x] = 1.f / (1.f + expf(-a));
                }
            }
        }
    }
}

extern "C" void kernel_launch(void* const* d_in, const int* in_sizes, int n_in,
                              void* d_out, int out_size, void* d_ws, size_t ws_size,
                              hipStream_t stream) {
    const float* x    = (const float*)d_in[0];
    const float* w1   = (const float*)d_in[1];
    const float* b1   = (const float*)d_in[2];
    const float* w2   = (const float*)d_in[3];
    const float* b2   = (const float*)d_in[4];
    const float* g2   = (const float*)d_in[5];
    const float* bt2  = (const float*)d_in[6];
    const float* w3   = (const float*)d_in[7];
    const float* b3   = (const float*)d_in[8];
    const float* proto= (const float*)d_in[9];
    const float* wup  = (const float*)d_in[10];
    const float* bup  = (const float*)d_in[11];
    const float* gup  = (const float*)d_in[12];
    const float* btup = (const float*)d_in[13];
    const float* wd1  = (const float*)d_in[14];
    const float* bd1  = (const float*)d_in[15];
    const float* gd1  = (const float*)d_in[16];
    const float* btd1 = (const float*)d_in[17];
    const float* wd2  = (const float*)d_in[18];
    const float* bd2  = (const float*)d_in[19];
    const float* gd2  = (const float*)d_in[20];
    const float* btd2 = (const float*)d_in[21];
    const float* wd3  = (const float*)d_in[22];
    const float* bd3  = (const float*)d_in[23];

    float* out0   = (float*)d_out;                 // [4096][784]
    float* out_md = out0 + (size_t)NB * 784;       // [4096][512]

    // ws layout
    float*    p2      = (float*)d_ws;                          // 512 f
    float*    x2g     = p2 + 512;                              // 131072 f
    ushort_t* pfragHi = (ushort_t*)(x2g + 131072);             // 131072
    ushort_t* pfragLo = pfragHi + 131072;                      // 131072
    ushort_t* w3fH    = pfragLo + 131072;                      // 40960
    ushort_t* w3fL    = w3fH + 40960;                          // 40960
    ushort_t* w2fH    = w3fL + 40960;                          // 1536
    ushort_t* w2fL    = w2fH + 1536;                           // 1536
    ushort_t* wd1frag = w2fL + 1536;                           // 36864
    ushort_t* wupfH   = wd1frag + 36864;                       // 1638400
    ushort_t* wupfL   = wupfH + 1638400;                       // 1638400
    ushort_t* PWfrag  = wupfL + 1638400;                       // 3276800
    ushort_t* Wsm     = PWfrag + 3276800;                      // 2097152
    ushort_t* BIG     = Wsm + 2097152;                         // 52.4 MB region
    ushort_t* h3g     = BIG;                                   // [4096][25][256] bf16
    ushort_t* zupT    = BIG;                                   // [4096][6400] (aliases dead h3g)

    hipLaunchKernelGGL(k_pre, dim3(7734), dim3(256), 0, stream,
                       proto, p2, pfragHi, pfragLo, w3, w3fH, w3fL,
                       w2, w2fH, w2fL, wd1, wd1frag, wup, wupfH, wupfL);
    hipLaunchKernelGGL(k_pw2, dim3(25, 32), dim3(256), 0, stream,
                       pfragHi, pfragLo, wupfH, wupfL, PWfrag);
    hipLaunchKernelGGL(k_enc1, dim3(NB), dim3(512), 0, stream,
                       x, w1, b1, w2fH, w2fL, b2, g2, bt2, w3fH, w3fL, b3, h3g, x2g);
    hipLaunchKernelGGL(k_enc2, dim3(NB / 2), dim3(1024), 0, stream,
                       h3g, x2g, pfragHi, pfragLo, p2, out_md, Wsm);
    hipLaunchKernelGGL(k_zup2, dim3(50, 32), dim3(512), 0, stream,
                       Wsm, PWfrag, bup, gup, btup, zupT);
    hipLaunchKernelGGL(k_dtail, dim3(NB / 2), dim3(512), 0, stream,
                       zupT, wd1frag, bd1, gd1, btd1, wd2, bd2, gd2, btd2, wd3, bd3, out0);
}

// Round 17
// 273.017 us; speedup vs baseline: 1.5713x; 1.0608x over previous
//
#include <hip/hip_runtime.h>
#include <hip/hip_bf16.h>
#include <math.h>

#define NB 4096
#define DC 256
#define PC 512

typedef unsigned short ushort_t;
typedef __attribute__((ext_vector_type(4))) unsigned short us4;
typedef __attribute__((ext_vector_type(8))) unsigned short us8;
typedef __attribute__((ext_vector_type(8))) short s8v;       // bf16x8 for MFMA
typedef __attribute__((ext_vector_type(4))) float f32x4;

__device__ __forceinline__ float bf16_to_f(ushort_t u) {
    union { unsigned int i; float f; } c;
    c.i = ((unsigned int)u) << 16;
    return c.f;
}
__device__ __forceinline__ ushort_t f2bf(float f) {          // RNE
    union { float f; unsigned int u; } c; c.f = f;
    unsigned int r = c.u + 0x7fffu + ((c.u >> 16) & 1u);
    return (ushort_t)(r >> 16);
}

// ---------------- K_pre: all small packing kernels merged (blockIdx-range dispatch) -------
__global__ __launch_bounds__(256) void k_pre(
    const float* __restrict__ proto, float* __restrict__ p2,
    ushort_t* __restrict__ pfragHi, ushort_t* __restrict__ pfragLo,
    const float* __restrict__ w3, ushort_t* __restrict__ w3fH, ushort_t* __restrict__ w3fL,
    const float* __restrict__ w2, ushort_t* __restrict__ w2fH, ushort_t* __restrict__ w2fL,
    const float* __restrict__ wd1, ushort_t* __restrict__ wd1frag,
    const float* __restrict__ wup, ushort_t* __restrict__ wupfH, ushort_t* __restrict__ wupfL)
{
    int b = blockIdx.x, tid = threadIdx.x;
    __shared__ float red[256];
    if (b < 512) {
        int p = b, d = tid;
        float v = proto[p * DC + d];
        red[d] = v * v;
        __syncthreads();
        for (int s = 128; s > 0; s >>= 1) {
            if (d < s) red[d] += red[d + s];
            __syncthreads();
        }
        if (d == 0) p2[p] = red[0];
    } else if (b < 1024) {
        int idx = (b - 512) * 256 + tid;
        int j = idx & 7, l = (idx >> 3) & 63;
        int k0 = (idx >> 9) & 7, nt = idx >> 12;
        int n = nt * 16 + (l & 15);
        int k = k0 * 32 + (l >> 4) * 8 + j;
        float v = proto[n * DC + k];
        ushort_t hi = f2bf(v);
        pfragHi[idx] = hi;
        pfragLo[idx] = f2bf(v - bf16_to_f(hi));
    } else if (b < 1184) {
        int idx = (b - 1024) * 256 + tid;
        int j = idx & 7, l = (idx >> 3) & 63;
        int q = idx >> 9;
        int k0 = q % 5, nt = q / 5;
        int d = nt * 16 + (l & 15);
        int k = k0 * 32 + (l >> 4) * 8 + j;
        float v = (k < 144) ? w3[d * 144 + k] : 0.f;
        ushort_t hi = f2bf(v);
        w3fH[idx] = hi;
        w3fL[idx] = f2bf(v - bf16_to_f(hi));
    } else if (b < 1190) {
        int idx = (b - 1184) * 256 + tid;
        int j = idx & 7, l = (idx >> 3) & 63;
        int k0 = idx >> 9;
        int ch = l & 15;
        int k = k0 * 32 + (l >> 4) * 8 + j;
        float v = (k < 72) ? w2[ch * 72 + k] : 0.f;
        ushort_t hi = f2bf(v);
        w2fH[idx] = hi;
        w2fL[idx] = f2bf(v - bf16_to_f(hi));
    } else if (b < 1334) {
        int idx = (b - 1190) * 256 + tid;
        int j = idx & 7, l = (idx >> 3) & 63;
        int k0 = (idx >> 9) & 7, nt = idx >> 12;
        int n = nt * 16 + (l & 15);
        int k = k0 * 32 + (l >> 4) * 8 + j;
        wd1frag[idx] = f2bf(wd1[k * 144 + n]);
    } else {
        int idx = (b - 1334) * 256 + tid;
        int j = idx & 7, l = (idx >> 3) & 63;
        int k0 = (idx >> 9) & 7, nt = idx >> 12;
        int np = nt * 16 + (l & 15);
        int d = k0 * 32 + (l >> 4) * 8 + j;
        int pos = np >> 8, ch = np & 255;
        float v = wup[d * 6400 + ch * 25 + pos];
        ushort_t hi = f2bf(v);
        wupfH[idx] = hi;
        wupfL[idx] = f2bf(v - bf16_to_f(hi));
    }
}

// ---------------- K0f: PW = proto x wupT via MFMA (hi/lo), -> PWfrag [400][16][64][8] -----
__global__ __launch_bounds__(256) void k_pw2(
    const ushort_t* __restrict__ pfragHi, const ushort_t* __restrict__ pfragLo,
    const ushort_t* __restrict__ wupfH, const ushort_t* __restrict__ wupfL,
    ushort_t* __restrict__ PWfrag)
{
    int t = threadIdx.x;
    int w = t >> 6, l = t & 63, lr = l & 15, lg = l >> 4;
    int my = blockIdx.y;
    int ntb = blockIdx.x * 16 + w * 4;
    const s8v* AH = (const s8v*)pfragHi;
    const s8v* AL = (const s8v*)pfragLo;
    const s8v* BH = (const s8v*)wupfH;
    const s8v* BL = (const s8v*)wupfL;
    f32x4 acc[4];
#pragma unroll
    for (int q = 0; q < 4; q++) acc[q] = (f32x4){0.f, 0.f, 0.f, 0.f};
#pragma unroll
    for (int k0 = 0; k0 < 8; k0++) {
        s8v ah = AH[(my * 8 + k0) * 64 + l];
        s8v al = AL[(my * 8 + k0) * 64 + l];
#pragma unroll
        for (int q = 0; q < 4; q++) {
            s8v bh = BH[(size_t)((ntb + q) * 8 + k0) * 64 + l];
            s8v bl = BL[(size_t)((ntb + q) * 8 + k0) * 64 + l];
            acc[q] = __builtin_amdgcn_mfma_f32_16x16x32_bf16(ah, bh, acc[q], 0, 0, 0);
            acc[q] = __builtin_amdgcn_mfma_f32_16x16x32_bf16(al, bh, acc[q], 0, 0, 0);
            acc[q] = __builtin_amdgcn_mfma_f32_16x16x32_bf16(ah, bl, acc[q], 0, 0, 0);
        }
    }
#pragma unroll
    for (int q = 0; q < 4; q++) {
        int nt = ntb + q;
#pragma unroll
        for (int r = 0; r < 4; r++) {
            int p = my * 16 + lg * 4 + r;
            int k0p = p >> 5;
            int ll = ((p >> 3) & 3) * 16 + lr;
            int jj = p & 7;
            PWfrag[(((size_t)(nt * 16 + k0p) * 64) + ll) * 8 + jj] = f2bf(acc[q][r]);
        }
    }
}

// ---------------- E1: 2 images/block; conv1+scatter | conv2 MFMA (8 waves) | conv3 -------
__global__ __launch_bounds__(512) void k_enc1(
    const float* __restrict__ x,
    const float* __restrict__ w1, const float* __restrict__ b1,
    const ushort_t* __restrict__ w2fH, const ushort_t* __restrict__ w2fL,
    const float* __restrict__ b2,
    const float* __restrict__ g2, const float* __restrict__ bt2,
    const ushort_t* __restrict__ w3fH, const ushort_t* __restrict__ w3fL,
    const float* __restrict__ b3,
    ushort_t* __restrict__ h3g)        // [4096][25][256] bf16
{
    int b0 = blockIdx.x * 2;
    int t = threadIdx.x;
    int w = t >> 6, l = t & 63, lr = l & 15, lg = l >> 4;
    int tim = t >> 8, tt = t & 255;       // thread-half image

    // per-image region (25856 B): xb@0(3136) h1@3136(6272) | im2Hi@9408(13312) | h2@22720(3136)
    //   conv3: imHi@0(9248) overlays dead xb/h1-head
    __shared__ __align__(16) unsigned char buf[51712];
    unsigned char* bufI = buf + tim * 25856;
    float* xb = (float*)bufI;
    float* h1 = (float*)(bufI + 3136);
    ushort_t* im2Hi = (ushort_t*)(bufI + 9408);
    float* h2 = (float*)(bufI + 22720);
    ushort_t* imHi = (ushort_t*)bufI;

    const float bnr = rsqrtf(1.0f + 1e-5f);

    // phase 0: load x, zero im2col2
    const float* xg = x + (size_t)(b0 + tim) * 784;
    for (int i = tt; i < 784; i += 256) xb[i] = xg[i];
    for (int i = tt; i < 832; i += 256)
        ((float4*)(bufI + 9408))[i] = (float4){0.f, 0.f, 0.f, 0.f};
    __syncthreads();

    // phase 1: conv1 + scatter into im2col2 (single bf16)
    for (int o = tt; o < 1568; o += 256) {
        int c = o / 196, r = o % 196, y = r / 14, xc = r % 14;
        float acc = b1[c];
        for (int sy = 0; sy < 3; sy++) {
            int iy = 2 * y - 1 + sy;
            if ((unsigned)iy >= 28u) continue;
            for (int sx = 0; sx < 3; sx++) {
                int ix = 2 * xc - 1 + sx;
                if ((unsigned)ix >= 28u) continue;
                acc += w1[c * 9 + sy * 3 + sx] * xb[iy * 28 + ix];
            }
        }
        float v = fmaxf(acc, 0.f);
        ushort_t hi = f2bf(v);
        int kb = c * 9;
        int yA, syA, xA, sxA, yB = 0, xB = 0;
        bool hasYB, hasXB;
        if (y & 1) { yA = y >> 1; syA = 2; yB = yA + 1; hasYB = (yB < 7); }
        else       { yA = y >> 1; syA = 1; hasYB = false; }
        if (xc & 1) { xA = xc >> 1; sxA = 2; xB = xA + 1; hasXB = (xB < 7); }
        else        { xA = xc >> 1; sxA = 1; hasXB = false; }
        im2Hi[(yA * 7 + xA) * 104 + kb + syA * 3 + sxA] = hi;
        if (hasXB) im2Hi[(yA * 7 + xB) * 104 + kb + syA * 3] = hi;
        if (hasYB) {
            im2Hi[(yB * 7 + xA) * 104 + kb + sxA] = hi;
            if (hasXB) im2Hi[(yB * 7 + xB) * 104 + kb] = hi;
        }
    }
    __syncthreads();

    // phase 2: conv2 as MFMA — all 8 waves (4 per image; waves 0-3 img0, 4-7 img1)
    {
        int w4 = w & 3;
        f32x4 cc = {0, 0, 0, 0};
        const s8v* WH = (const s8v*)w2fH;
        const s8v* WL = (const s8v*)w2fL;
#pragma unroll
        for (int k0 = 0; k0 < 3; k0++) {
            s8v a0 = *(const s8v*)&im2Hi[(w4 * 16 + lr) * 104 + k0 * 32 + lg * 8];
            s8v bh = WH[k0 * 64 + l];
            s8v bl = WL[k0 * 64 + l];
            cc = __builtin_amdgcn_mfma_f32_16x16x32_bf16(a0, bh, cc, 0, 0, 0);
            cc = __builtin_amdgcn_mfma_f32_16x16x32_bf16(a0, bl, cc, 0, 0, 0);
        }
        int ch = lr;
        float s = g2[ch] * bnr, bb = b2[ch], bt = bt2[ch];
#pragma unroll
        for (int r = 0; r < 4; r++) {
            int pos = w4 * 16 + lg * 4 + r;
            if (pos < 49)
                h2[ch * 49 + pos] = fmaxf((cc[r] + bb) * s + bt, 0.f);
        }
    }
    __syncthreads();

    // phase 3: scatter h2 -> im2col3 (single bf16)
    if (tt < 16) imHi[3600 + tt] = 0;
    for (int o = tt; o < 784; o += 256) {
        float v = h2[o];
        int ci = o / 49, rr = o % 49, iy = rr / 7, ixp = rr % 7;
        ushort_t hi = f2bf(v);
        int kb = ci * 9;
#pragma unroll
        for (int sy = 0; sy < 3; sy++) {
            int py = iy - sy;
            if ((unsigned)py < 5u) {
#pragma unroll
                for (int sx = 0; sx < 3; sx++) {
                    int px = ixp - sx;
                    if ((unsigned)px < 5u)
                        imHi[(py * 5 + px) * 144 + kb + sy * 3 + sx] = hi;
                }
            }
        }
    }
    __syncthreads();

    // phase 4: conv3 as MFMA — wave w owns nt-pair {2w,2w+1} for BOTH images (B reg reuse)
    {
        const ushort_t* imHi0 = (const ushort_t*)buf;
        const ushort_t* imHi1 = (const ushort_t*)(buf + 25856);
        int nt0 = 2 * w;
        f32x4 c[2][2][2];   // [im][q][mt]
#pragma unroll
        for (int im = 0; im < 2; im++)
#pragma unroll
            for (int q = 0; q < 2; q++)
#pragma unroll
                for (int mt = 0; mt < 2; mt++) c[im][q][mt] = (f32x4){0.f, 0.f, 0.f, 0.f};
        const s8v* WH = (const s8v*)w3fH;
        const s8v* WL = (const s8v*)w3fL;
#pragma unroll
        for (int k0 = 0; k0 < 5; k0++) {
            s8v a00 = *(const s8v*)&imHi0[lr * 144 + k0 * 32 + lg * 8];
            s8v a01 = *(const s8v*)&imHi0[(16 + lr) * 144 + k0 * 32 + lg * 8];
            s8v a10 = *(const s8v*)&imHi1[lr * 144 + k0 * 32 + lg * 8];
            s8v a11 = *(const s8v*)&imHi1[(16 + lr) * 144 + k0 * 32 + lg * 8];
            s8v bh0 = WH[(nt0 * 5 + k0) * 64 + l];
            s8v bl0 = WL[(nt0 * 5 + k0) * 64 + l];
            s8v bh1 = WH[((nt0 + 1) * 5 + k0) * 64 + l];
            s8v bl1 = WL[((nt0 + 1) * 5 + k0) * 64 + l];
            c[0][0][0] = __builtin_amdgcn_mfma_f32_16x16x32_bf16(a00, bh0, c[0][0][0], 0, 0, 0);
            c[0][0][1] = __builtin_amdgcn_mfma_f32_16x16x32_bf16(a01, bh0, c[0][0][1], 0, 0, 0);
            c[0][0][0] = __builtin_amdgcn_mfma_f32_16x16x32_bf16(a00, bl0, c[0][0][0], 0, 0, 0);
            c[0][0][1] = __builtin_amdgcn_mfma_f32_16x16x32_bf16(a01, bl0, c[0][0][1], 0, 0, 0);
            c[0][1][0] = __builtin_amdgcn_mfma_f32_16x16x32_bf16(a00, bh1, c[0][1][0], 0, 0, 0);
            c[0][1][1] = __builtin_amdgcn_mfma_f32_16x16x32_bf16(a01, bh1, c[0][1][1], 0, 0, 0);
            c[0][1][0] = __builtin_amdgcn_mfma_f32_16x16x32_bf16(a00, bl1, c[0][1][0], 0, 0, 0);
            c[0][1][1] = __builtin_amdgcn_mfma_f32_16x16x32_bf16(a01, bl1, c[0][1][1], 0, 0, 0);
            c[1][0][0] = __builtin_amdgcn_mfma_f32_16x16x32_bf16(a10, bh0, c[1][0][0], 0, 0, 0);
            c[1][0][1] = __builtin_amdgcn_mfma_f32_16x16x32_bf16(a11, bh0, c[1][0][1], 0, 0, 0);
            c[1][0][0] = __builtin_amdgcn_mfma_f32_16x16x32_bf16(a10, bl0, c[1][0][0], 0, 0, 0);
            c[1][0][1] = __builtin_amdgcn_mfma_f32_16x16x32_bf16(a11, bl0, c[1][0][1], 0, 0, 0);
            c[1][1][0] = __builtin_amdgcn_mfma_f32_16x16x32_bf16(a10, bh1, c[1][1][0], 0, 0, 0);
            c[1][1][1] = __builtin_amdgcn_mfma_f32_16x16x32_bf16(a11, bh1, c[1][1][1], 0, 0, 0);
            c[1][1][0] = __builtin_amdgcn_mfma_f32_16x16x32_bf16(a10, bl1, c[1][1][0], 0, 0, 0);
            c[1][1][1] = __builtin_amdgcn_mfma_f32_16x16x32_bf16(a11, bl1, c[1][1][1], 0, 0, 0);
        }
#pragma unroll
        for (int im = 0; im < 2; im++) {
            ushort_t* hg = h3g + (size_t)(b0 + im) * 6400;
#pragma unroll
            for (int q = 0; q < 2; q++) {
                int d = (nt0 + q) * 16 + lr;
                float bb = b3[d];
#pragma unroll
                for (int mt = 0; mt < 2; mt++) {
                    f32x4 cv = c[im][q][mt];
#pragma unroll
                    for (int r = 0; r < 4; r++) {
                        int pos = mt * 16 + lg * 4 + r;
                        if (pos < 25) {
                            float h = fmaxf(cv[r] + bb, 0.f);
                            hg[pos * 256 + d] = f2bf(h);
                        }
                    }
                }
            }
        }
    }
}

// ---------------- E2: MFMA distances + softmax (2 img/block; x2 computed here) -----------
__global__ __launch_bounds__(1024) void k_enc2(
    const ushort_t* __restrict__ h3g,        // [4096][25][256] bf16
    const ushort_t* __restrict__ pfragHi, const ushort_t* __restrict__ pfragLo,
    const float* __restrict__ p2,
    float* __restrict__ md_out,
    ushort_t* __restrict__ Wsm)
{
    int t = threadIdx.x;
    int b0 = blockIdx.x * 2;
    int w = t >> 6, l = t & 63, lr = l & 15, lg = l >> 4;

    __shared__ __align__(16) ushort_t h3s[2][32][264];   // 33792 B
    __shared__ float mds[2][512];
    __shared__ float x2sh[2][32];
    __shared__ float x2part[2][25][8];
    __shared__ float wred[2][16];

    for (int i = t; i < 2048; i += 1024) {
        int im = i >> 10, pos = (i >> 5) & 31, c8 = i & 31;
        us8 v = {0, 0, 0, 0, 0, 0, 0, 0};
        if (pos < 25)
            v = *(const us8*)&h3g[(size_t)(b0 + im) * 6400 + pos * 256 + c8 * 8];
        *(us8*)&h3s[im][pos][c8 * 8] = v;
    }
    __syncthreads();

    // x2 from staged bf16 h3 (numerically identical to enc1's rounded-h computation)
    if (t < 400) {
        int im = t / 200, rest = t % 200;
        int pos = rest >> 3, ch = rest & 7;
        const ushort_t* hp = &h3s[im][pos][ch * 32];
        float s = 0.f;
#pragma unroll
        for (int i = 0; i < 32; i++) {
            float f = bf16_to_f(hp[i]);
            s = fmaf(f, f, s);
        }
        x2part[im][pos][ch] = s;
    }
    __syncthreads();
    if (t < 64) {
        int im = t >> 5, pos = t & 31;
        float s = 1e30f;
        if (pos < 25) {
            s = 0.f;
#pragma unroll
            for (int c = 0; c < 8; c++) s += x2part[im][pos][c];
        }
        x2sh[im][pos] = s;
    }
    __syncthreads();

    {
        f32x4 acc[2][2][2];
#pragma unroll
        for (int i = 0; i < 2; i++)
#pragma unroll
            for (int jm = 0; jm < 2; jm++)
#pragma unroll
                for (int mt = 0; mt < 2; mt++) acc[i][jm][mt] = (f32x4){0.f, 0.f, 0.f, 0.f};
        const s8v* BH = (const s8v*)pfragHi;
        const s8v* BL = (const s8v*)pfragLo;
        s8v bhc[2], blc[2], bhn[2], bln[2];
#pragma unroll
        for (int ntq = 0; ntq < 2; ntq++) {
            int nt = w * 2 + ntq;
            bhc[ntq] = BH[(nt * 8 + 0) * 64 + l];
            blc[ntq] = BL[(nt * 8 + 0) * 64 + l];
        }
        for (int k0 = 0; k0 < 8; k0++) {
            if (k0 < 7) {
#pragma unroll
                for (int ntq = 0; ntq < 2; ntq++) {
                    int nt = w * 2 + ntq;
                    bhn[ntq] = BH[(nt * 8 + k0 + 1) * 64 + l];
                    bln[ntq] = BL[(nt * 8 + k0 + 1) * 64 + l];
                }
            }
            s8v ah[2][2];
            ah[0][0] = *(const s8v*)&h3s[0][lr][k0 * 32 + lg * 8];
            ah[0][1] = *(const s8v*)&h3s[0][16 + lr][k0 * 32 + lg * 8];
            ah[1][0] = *(const s8v*)&h3s[1][lr][k0 * 32 + lg * 8];
            ah[1][1] = *(const s8v*)&h3s[1][16 + lr][k0 * 32 + lg * 8];
#pragma unroll
            for (int ntq = 0; ntq < 2; ntq++) {
                s8v bh = bhc[ntq];
                s8v bl = blc[ntq];
#pragma unroll
                for (int im = 0; im < 2; im++) {
                    acc[ntq][im][0] = __builtin_amdgcn_mfma_f32_16x16x32_bf16(ah[im][0], bh, acc[ntq][im][0], 0, 0, 0);
                    acc[ntq][im][1] = __builtin_amdgcn_mfma_f32_16x16x32_bf16(ah[im][1], bh, acc[ntq][im][1], 0, 0, 0);
                    acc[ntq][im][0] = __builtin_amdgcn_mfma_f32_16x16x32_bf16(ah[im][0], bl, acc[ntq][im][0], 0, 0, 0);
                    acc[ntq][im][1] = __builtin_amdgcn_mfma_f32_16x16x32_bf16(ah[im][1], bl, acc[ntq][im][1], 0, 0, 0);
                }
            }
#pragma unroll
            for (int ntq = 0; ntq < 2; ntq++) {
                bhc[ntq] = bhn[ntq];
                blc[ntq] = bln[ntq];
            }
        }
        float x2r[2][8];
#pragma unroll
        for (int im = 0; im < 2; im++)
#pragma unroll
            for (int r = 0; r < 4; r++) {
                x2r[im][r]     = x2sh[im][lg * 4 + r];
                x2r[im][4 + r] = x2sh[im][16 + lg * 4 + r];
            }
#pragma unroll
        for (int ntq = 0; ntq < 2; ntq++) {
            int pcol = (w * 2 + ntq) * 16 + lr;
            float p2v = p2[pcol];
#pragma unroll
            for (int im = 0; im < 2; im++) {
                float mm = 1e30f;
#pragma unroll
                for (int r = 0; r < 4; r++) {
                    float d0 = fmaxf(x2r[im][r]     - 2.f * acc[ntq][im][0][r] + p2v, 0.f);
                    float d1 = fmaxf(x2r[im][4 + r] - 2.f * acc[ntq][im][1][r] + p2v, 0.f);
                    mm = fminf(mm, fminf(d0, d1));
                }
                mm = fminf(mm, __shfl_xor(mm, 16));
                mm = fminf(mm, __shfl_xor(mm, 32));
                if (lg == 0) mds[im][pcol] = mm;
            }
        }
    }
    __syncthreads();

    int img = t >> 9, tt = t & 511;
    float mind = mds[img][tt];
    md_out[(size_t)(b0 + img) * PC + tt] = mind;
    float a = -mind;
    float mx = a;
#pragma unroll
    for (int off = 1; off < 64; off <<= 1) mx = fmaxf(mx, __shfl_xor(mx, off));
    int wv = w & 7;
    if (l == 0) wred[img][wv] = mx;
    __syncthreads();
    float m = wred[img][0];
#pragma unroll
    for (int i = 1; i < 8; i++) m = fmaxf(m, wred[img][i]);
    float e = expf(a - m);
    float sm = e;
#pragma unroll
    for (int off = 1; off < 64; off <<= 1) sm += __shfl_xor(sm, off);
    if (l == 0) wred[img][8 + wv] = sm;
    __syncthreads();
    float ssum = wred[img][8];
#pragma unroll
    for (int i = 9; i < 16; i++) ssum += wred[img][i];
    Wsm[(size_t)(b0 + img) * PC + tt] = f2bf(e / ssum);
}

// ---------------- K2: zupT = Wsm x PW (bf16 MFMA, 2-slab staging), bias+bn+relu ----------
__global__ __launch_bounds__(512) void k_zup2(
    const ushort_t* __restrict__ Wsm,      // [4096][512]
    const ushort_t* __restrict__ PWfrag,   // [400][16][64][8]
    const float* __restrict__ bup, const float* __restrict__ gup,
    const float* __restrict__ btup,
    ushort_t* __restrict__ zupT)           // [4096][6400]
{
    __shared__ __align__(16) ushort_t Bsh[2][8192];
    int t = threadIdx.x;
    int w = t >> 6, l = t & 63;
    int n0 = blockIdx.x * 128;             // 50
    int m0 = blockIdx.y * 128;             // 32
    int row = m0 + w * 16 + (l & 15);
    int krow = (l >> 4) * 8;
    f32x4 acc[8];
#pragma unroll
    for (int i = 0; i < 8; i++) acc[i] = (f32x4){0.f, 0.f, 0.f, 0.f};
    const s8v* B = (const s8v*)PWfrag;
    int base = blockIdx.x * 8 * 16;

    {
        s8v v0 = B[(size_t)(base + (t >> 6) * 16 + 0) * 64 + (t & 63)];
        s8v v1 = B[(size_t)(base + (t >> 6) * 16 + 1) * 64 + (t & 63)];
        *(s8v*)&Bsh[0][t * 8] = v0;
        *(s8v*)&Bsh[0][4096 + t * 8] = v1;
    }
    __syncthreads();
    for (int r = 0; r < 8; r++) {
        int cur = r & 1;
        if (r < 7) {
            s8v v0 = B[(size_t)(base + (t >> 6) * 16 + 2 * r + 2) * 64 + (t & 63)];
            s8v v1 = B[(size_t)(base + (t >> 6) * 16 + 2 * r + 3) * 64 + (t & 63)];
            *(s8v*)&Bsh[cur ^ 1][t * 8] = v0;
            *(s8v*)&Bsh[cur ^ 1][4096 + t * 8] = v1;
        }
#pragma unroll
        for (int kk = 0; kk < 2; kk++) {
            int k0 = 2 * r + kk;
            s8v a = *(const s8v*)&Wsm[(size_t)row * 512 + k0 * 32 + krow];
#pragma unroll
            for (int nt = 0; nt < 8; nt++) {
                s8v bb = *(const s8v*)&Bsh[cur][kk * 4096 + (nt * 64 + l) * 8];
                acc[nt] = __builtin_amdgcn_mfma_f32_16x16x32_bf16(a, bb, acc[nt], 0, 0, 0);
            }
        }
        __syncthreads();
    }

    const float bnr = rsqrtf(1.0f + 1e-5f);
    int rowbase = m0 + w * 16 + (l >> 4) * 4;
#pragma unroll
    for (int nt = 0; nt < 8; nt++) {
        int n = n0 + nt * 16 + (l & 15);
        int ch = n & 255;
        float sc = gup[ch] * bnr, bb = bup[ch], bt = btup[ch];
#pragma unroll
        for (int r = 0; r < 4; r++) {
            float v = (acc[nt][r] + bb) * sc + bt;
            zupT[(size_t)(rowbase + r) * 6400 + n] = f2bf(fmaxf(v, 0.f));
        }
    }
}

// ---------------- K3: fused decoder, 2 img/block, class-per-wave (uniform branches) -------
__global__ __launch_bounds__(512) void k_dtail(
    const ushort_t* __restrict__ zupT,     // [4096][6400]
    const ushort_t* __restrict__ wd1frag,  // [9][8][64][8]
    const float* __restrict__ bd1, const float* __restrict__ gd1, const float* __restrict__ btd1,
    const float* __restrict__ wd2, const float* __restrict__ bd2,
    const float* __restrict__ gd2, const float* __restrict__ btd2,
    const float* __restrict__ wd3, const float* __restrict__ bd3,
    float* __restrict__ out0)
{
    int b0 = blockIdx.x * 2, t = threadIdx.x;
    int w = t >> 6, l = t & 63, lr = l & 15, lg = l >> 4;
    int g = w >> 2, wv = w & 3, tg = t & 255;
    __shared__ __align__(16) unsigned char dbuf[33792];
    __shared__ float hd1p[2][16][64];
    __shared__ float w2sT[9 * 8 * 16];
    __shared__ float w3sT[9 * 8];
    ushort_t* zAb = (ushort_t*)dbuf;
    float* Psb = (float*)dbuf;

    const float bnr = rsqrtf(1.0f + 1e-5f);

    for (int c = t; c < 1600; c += 512) {
        int im = c / 800, cc = c % 800;
        *(us8*)&zAb[im * 8448 + (cc >> 5) * 264 + (cc & 31) * 8] =
            *(const us8*)&zupT[(size_t)(b0 + im) * 6400 + cc * 8];
    }
    for (int i = t; i < 2048; i += 512) ((float*)hd1p)[i] = 0.f;
    for (int i = t; i < 1152; i += 512) {
        int s = i >> 7, rest = i & 127;
        int co = rest >> 4, ci = rest & 15;
        w2sT[i] = wd2[(ci * 8 + co) * 9 + s];
    }
    if (t < 72) {
        int s = t >> 3, ci = t & 7;
        w3sT[t] = wd3[ci * 9 + s];
    }
    __syncthreads();

    {
        f32x4 acc[3][2];
#pragma unroll
        for (int i = 0; i < 3; i++)
#pragma unroll
            for (int mt = 0; mt < 2; mt++) acc[i][mt] = (f32x4){0.f, 0.f, 0.f, 0.f};
        const s8v* B = (const s8v*)wd1frag;
        for (int k0 = 0; k0 < 8; k0++) {
            s8v a0 = *(const s8v*)&zAb[g * 8448 + lr * 264 + k0 * 32 + lg * 8];
            s8v a1 = *(const s8v*)&zAb[g * 8448 + (16 + lr) * 264 + k0 * 32 + lg * 8];
#pragma unroll
            for (int i = 0; i < 3; i++) {
                int nt = wv + 4 * i;
                if (nt < 9) {
                    s8v bb = B[(nt * 8 + k0) * 64 + l];
                    acc[i][0] = __builtin_amdgcn_mfma_f32_16x16x32_bf16(a0, bb, acc[i][0], 0, 0, 0);
                    acc[i][1] = __builtin_amdgcn_mfma_f32_16x16x32_bf16(a1, bb, acc[i][1], 0, 0, 0);
                }
            }
        }
        __syncthreads();
#pragma unroll
        for (int i = 0; i < 3; i++) {
            int nt = wv + 4 * i;
            if (nt < 9) {
                int col = nt * 16 + lr;
#pragma unroll
                for (int mt = 0; mt < 2; mt++)
#pragma unroll
                    for (int r = 0; r < 4; r++) {
                        int pos = mt * 16 + lg * 4 + r;
                        if (pos < 25) Psb[g * 3700 + pos * 148 + col] = acc[i][mt][r];
                    }
            }
        }
    }
    __syncthreads();

    for (int o = tg; o < 784; o += 256) {
        int co = o / 49, rr = o % 49, y = rr / 7, xx = rr % 7;
        float a = bd1[co];
        int sy0 = y - 4 > 0 ? y - 4 : 0, sy1 = y < 2 ? y : 2;
        for (int sy = sy0; sy <= sy1; sy++) {
            int iy = y - sy;
            int sx0 = xx - 4 > 0 ? xx - 4 : 0, sx1 = xx < 2 ? xx : 2;
            for (int sx = sx0; sx <= sx1; sx++) {
                int ix = xx - sx;
                a += Psb[g * 3700 + (iy * 5 + ix) * 148 + co * 9 + sy * 3 + sx];
            }
        }
        float v = a * (gd1[co] * bnr) + btd1[co];
        hd1p[g][co][y * 8 + xx] = fmaxf(v, 0.f);
    }
    __syncthreads();

    {
        if (t < 464) {
            int im = t / 232, rest = t % 232;
            int co = rest / 29, s = rest % 29;
            int yy = (s < 15) ? 14 : (s - 15);
            int xx2 = (s < 15) ? s : 14;
            ((float*)dbuf)[im * 1808 + co * 225 + yy * 15 + xx2] = 0.f;
        }
        int cls = (wv + g) & 3;
        int cy = cls >> 1, cx = cls & 1;
        if (l < 56 && (l & 7) < 7) {
            int r = l >> 3, c = l & 7;
            float acc[8];
#pragma unroll
            for (int co = 0; co < 8; co++) acc[co] = 0.f;
            const float* hb = &hd1p[g][0][0];
            int niy = 1 + cy, nix = 1 + cx;
            for (int ty = 0; ty < niy; ty++) {
                int iy = r + ty;
                int sy = cy ? (ty ? 0 : 2) : 1;
                for (int tx = 0; tx < nix; tx++) {
                    int ix = c + tx;
                    int sx = cx ? (tx ? 0 : 2) : 1;
                    const float* wp = &w2sT[(sy * 3 + sx) * 128];
                    int hoff = iy * 8 + ix;
                    float h[16];
#pragma unroll
                    for (int ci = 0; ci < 16; ci++) h[ci] = hb[ci * 64 + hoff];
#pragma unroll
                    for (int co = 0; co < 8; co++) {
                        const float4* wp4 = (const float4*)&wp[co * 16];
                        float4 wa = wp4[0], wb4 = wp4[1], wc4 = wp4[2], wd4 = wp4[3];
                        float a = acc[co];
                        a = fmaf(h[0], wa.x, a);  a = fmaf(h[1], wa.y, a);
                        a = fmaf(h[2], wa.z, a);  a = fmaf(h[3], wa.w, a);
                        a = fmaf(h[4], wb4.x, a); a = fmaf(h[5], wb4.y, a);
                        a = fmaf(h[6], wb4.z, a); a = fmaf(h[7], wb4.w, a);
                        a = fmaf(h[8], wc4.x, a); a = fmaf(h[9], wc4.y, a);
                        a = fmaf(h[10], wc4.z, a); a = fmaf(h[11], wc4.w, a);
                        a = fmaf(h[12], wd4.x, a); a = fmaf(h[13], wd4.y, a);
                        a = fmaf(h[14], wd4.z, a); a = fmaf(h[15], wd4.w, a);
                        acc[co] = a;
                    }
                }
            }
            int y = 2 * r + cy, x = 2 * c + cx;
            float* hout = (float*)dbuf + g * 1808;
#pragma unroll
            for (int co = 0; co < 8; co++) {
                float v = (acc[co] + bd2[co]) * (gd2[co] * bnr) + btd2[co];
                hout[co * 225 + y * 15 + x] = fmaxf(v, 0.f);
            }
        }
    }
    __syncthreads();

    {
        int cls = (wv + g) & 3;
        int cy = cls >> 1, cx = cls & 1;
        const float* h2b = (const float*)dbuf + g * 1808;
        float* og = out0 + (size_t)(b0 + g) * 784;
        int niy = 1 + cy, nix = 1 + cx;
#pragma unroll
        for (int j = 0; j < 4; j++) {
            int idx = l + 64 * j;
            if (idx < 224) {
                int row = idx >> 4, col = idx & 15;
                if (col < 14) {
                    float a = bd3[0];
                    for (int ty = 0; ty < niy; ty++) {
                        int iy = row + ty;
                        int sy = cy ? (ty ? 0 : 2) : 1;
                        for (int tx = 0; tx < nix; tx++) {
                            int ix = col + tx;
                            int sx = cx ? (tx ? 0 : 2) : 1;
                            const float* wp = &w3sT[(sy * 3 + sx) * 8];
                            int hoff = iy * 15 + ix;
#pragma unroll
                            for (int ci = 0; ci < 8; ci++)
                                a = fmaf(h2b[ci * 225 + hoff], wp[ci], a);
                        }
                    }
                    int y = 2 * row + cy, x = 2 * col + cx;
                    og[y * 28 + x] = 1.f / (1.f + expf(-a));
                }
            }
        }
    }
}

extern "C" void kernel_launch(void* const* d_in, const int* in_sizes, int n_in,
                              void* d_out, int out_size, void* d_ws, size_t ws_size,
                              hipStream_t stream) {
    const float* x    = (const float*)d_in[0];
    const float* w1   = (const float*)d_in[1];
    const float* b1   = (const float*)d_in[2];
    const float* w2   = (const float*)d_in[3];
    const float* b2   = (const float*)d_in[4];
    const float* g2   = (const float*)d_in[5];
    const float* bt2  = (const float*)d_in[6];
    const float* w3   = (const float*)d_in[7];
    const float* b3   = (const float*)d_in[8];
    const float* proto= (const float*)d_in[9];
    const float* wup  = (const float*)d_in[10];
    const float* bup  = (const float*)d_in[11];
    const float* gup  = (const float*)d_in[12];
    const float* btup = (const float*)d_in[13];
    const float* wd1  = (const float*)d_in[14];
    const float* bd1  = (const float*)d_in[15];
    const float* gd1  = (const float*)d_in[16];
    const float* btd1 = (const float*)d_in[17];
    const float* wd2  = (const float*)d_in[18];
    const float* bd2  = (const float*)d_in[19];
    const float* gd2  = (const float*)d_in[20];
    const float* btd2 = (const float*)d_in[21];
    const float* wd3  = (const float*)d_in[22];
    const float* bd3  = (const float*)d_in[23];

    float* out0   = (float*)d_out;                 // [4096][784]
    float* out_md = out0 + (size_t)NB * 784;       // [4096][512]

    // ws layout
    float*    p2      = (float*)d_ws;                          // 512 f
    float*    x2g     = p2 + 512;                              // (unused, kept for layout)
    ushort_t* pfragHi = (ushort_t*)(x2g + 131072);             // 131072
    ushort_t* pfragLo = pfragHi + 131072;                      // 131072
    ushort_t* w3fH    = pfragLo + 131072;                      // 40960
    ushort_t* w3fL    = w3fH + 40960;                          // 40960
    ushort_t* w2fH    = w3fL + 40960;                          // 1536
    ushort_t* w2fL    = w2fH + 1536;                           // 1536
    ushort_t* wd1frag = w2fL + 1536;                           // 36864
    ushort_t* wupfH   = wd1frag + 36864;                       // 1638400
    ushort_t* wupfL   = wupfH + 1638400;                       // 1638400
    ushort_t* PWfrag  = wupfL + 1638400;                       // 3276800
    ushort_t* Wsm     = PWfrag + 3276800;                      // 2097152
    ushort_t* BIG     = Wsm + 2097152;                         // 52.4 MB region
    ushort_t* h3g     = BIG;                                   // [4096][25][256] bf16
    ushort_t* zupT    = BIG;                                   // [4096][6400] (aliases dead h3g)

    hipLaunchKernelGGL(k_pre, dim3(7734), dim3(256), 0, stream,
                       proto, p2, pfragHi, pfragLo, w3, w3fH, w3fL,
                       w2, w2fH, w2fL, wd1, wd1frag, wup, wupfH, wupfL);
    hipLaunchKernelGGL(k_pw2, dim3(25, 32), dim3(256), 0, stream,
                       pfragHi, pfragLo, wupfH, wupfL, PWfrag);
    hipLaunchKernelGGL(k_enc1, dim3(NB / 2), dim3(512), 0, stream,
                       x, w1, b1, w2fH, w2fL, b2, g2, bt2, w3fH, w3fL, b3, h3g);
    hipLaunchKernelGGL(k_enc2, dim3(NB / 2), dim3(1024), 0, stream,
                       h3g, pfragHi, pfragLo, p2, out_md, Wsm);
    hipLaunchKernelGGL(k_zup2, dim3(50, 32), dim3(512), 0, stream,
                       Wsm, PWfrag, bup, gup, btup, zupT);
    hipLaunchKernelGGL(k_dtail, dim3(NB / 2), dim3(512), 0, stream,
                       zupT, wd1frag, bd1, gd1, btd1, wd2, bd2, gd2, btd2, wd3, bd3, out0);
}